// Round 6
// baseline (494.316 us; speedup 1.0000x reference)
//
#include <hip/hip_runtime.h>
#include <hip/hip_bf16.h>

// Problem constants (fixed by the reference)
constexpr int N_ = 2000;   // nodes
constexpr int E_ = 4096;   // edges
constexpr int H_ = 256;    // hidden
constexpr int KH_ = 128;   // he dim (mlp1 out)
constexpr int NV_ = H_ * KH_; // 32768, V row length — fp8 bytes
constexpr int MPAD_ = 2048;   // padded M for node-side MFMA GEMMs
constexpr int NG_ = 768;      // GRU gate width (3*H)
constexpr float VSCALE = 64.f;     // fp8 scale for V (avoids e4m3 subnormals)
constexpr float VSCALE_INV = 1.f / 64.f;

typedef short bf16x8 __attribute__((ext_vector_type(8)));
typedef float f32x4  __attribute__((ext_vector_type(4)));
typedef float f32x2  __attribute__((ext_vector_type(2)));

__device__ __forceinline__ float bf_lo(unsigned u) { return __uint_as_float(u << 16); }
__device__ __forceinline__ float bf_hi(unsigned u) { return __uint_as_float(u & 0xffff0000u); }
__device__ __forceinline__ short bfbits(float f) {
    __hip_bfloat16 b = __float2bfloat16(f);
    return *(short*)&b;
}

// ---- pipeline sync helpers (T4: counted vmcnt across raw barrier), depth-2 ----
#define PIPE_WAIT_ENTER(N_OUTST)                                   \
    asm volatile("s_waitcnt vmcnt(" #N_OUTST ")" ::: "memory");    \
    __builtin_amdgcn_s_barrier();                                  \
    asm volatile("" ::: "memory");                                 \
    __builtin_amdgcn_sched_barrier(0);

#define PIPE_EXIT()                                                \
    __builtin_amdgcn_sched_barrier(0);                             \
    asm volatile("" ::: "memory");                                 \
    __builtin_amdgcn_s_barrier();

// out = relu([emb[x], pos] @ lin0_W.T + b); also emits Abf (bf16, zero-padded rows).
__global__ void k_lin0(const int* __restrict__ x, const float* __restrict__ pos,
                       const float* __restrict__ emb, const float* __restrict__ W,
                       const float* __restrict__ b, float* __restrict__ out,
                       __hip_bfloat16* __restrict__ Abf) {
    int n = blockIdx.x, t = threadIdx.x;
    if (n >= N_) { Abf[(size_t)n * H_ + t] = __float2bfloat16(0.f); return; }
    __shared__ float in_p[8];
    if (t < 5) in_p[t] = emb[x[n] * 5 + t];
    else if (t < 8) in_p[t] = pos[n * 3 + (t - 5)];
    __syncthreads();
    float acc = b[t];
#pragma unroll
    for (int i = 0; i < 8; i++) acc += in_p[i] * W[t * 8 + i];
    float v = fmaxf(acc, 0.f);
    out[n * H_ + t] = v;
    Abf[(size_t)n * H_ + t] = __float2bfloat16(v);
}

// he = relu(edge_atr @ mlp1_W.T + b)   grid E, block 128
__global__ void k_he(const float* __restrict__ ea, const float* __restrict__ W,
                     const float* __restrict__ b, float* __restrict__ he) {
    int e = blockIdx.x, t = threadIdx.x;
    __shared__ float a[5];
    if (t < 5) a[t] = ea[e * 5 + t];
    __syncthreads();
    float acc = b[t];
#pragma unroll
    for (int i = 0; i < 5; i++) acc += a[i] * W[t * 5 + i];
    he[e * KH_ + t] = fmaxf(acc, 0.f);
}

__global__ void k_counts(const int* __restrict__ ei, float* __restrict__ counts) {
    int e = blockIdx.x * blockDim.x + threadIdx.x;
    if (e < E_) atomicAdd(&counts[ei[E_ + e]], 1.0f);
}

// Bt[nv][h] = mlp2_W[h*32768 + nv] as bf16 (transpose+convert), once per launch.
__global__ void k_trans_bt(const float* __restrict__ W, __hip_bfloat16* __restrict__ Bt) {
    __shared__ float tile[32][68];   // 68: 16B-aligned rows, bank-shifted
    int t = threadIdx.x;
    int n0 = blockIdx.x * 64, k0 = blockIdx.y * 32;
#pragma unroll
    for (int i = 0; i < 2; i++) {
        int idx = t + i * 256;                 // 0..511
        int kk = idx >> 4, nn = (idx & 15) * 4;
        float4 f = *(const float4*)&W[(size_t)(k0 + kk) * NV_ + n0 + nn];
        *(float4*)&tile[kk][nn] = f;
    }
    __syncthreads();
#pragma unroll
    for (int i = 0; i < 2; i++) {
        int idx = t + i * 256;                 // 0..511
        int nn = idx >> 3, k4 = (idx & 7) * 4;
        short4 s;
        s.x = bfbits(tile[k4 + 0][nn]);
        s.y = bfbits(tile[k4 + 1][nn]);
        s.z = bfbits(tile[k4 + 2][nn]);
        s.w = bfbits(tile[k4 + 3][nn]);
        *(short4*)&Bt[(size_t)(n0 + nn) * H_ + k0 + k4] = s;
    }
}

// One-time weight preps (bf16 converts + packed tail B + lin2 pad + mlp2_b transpose).
__global__ void k_prep_w(const float* __restrict__ Wih, const float* __restrict__ Whh,
                         const float* __restrict__ lin1W, const float* __restrict__ l6W1,
                         const float* __restrict__ lin2W, const float* __restrict__ b2,
                         __hip_bfloat16* __restrict__ WihB, __hip_bfloat16* __restrict__ WhhB,
                         __hip_bfloat16* __restrict__ Bpk,
                         __hip_bfloat16* __restrict__ lin2Wb, __hip_bfloat16* __restrict__ BtB) {
    int i = blockIdx.x * 256 + threadIdx.x;     // i < 196608
    if (i < NG_ * H_) {
        WihB[i] = __float2bfloat16(Wih[i]);
        WhhB[i] = __float2bfloat16(Whh[i]);
    }
    Bpk[i] = __float2bfloat16(i < 256 * 512 ? lin1W[i] : l6W1[i - 256 * 512]);
    if (i < 128 * 2 * H_) {
        int r = i >> 8, k = i & 255;
        lin2Wb[i] = __float2bfloat16(r < 242 ? lin2W[r * H_ + k] : 0.f);
        int o = i >> 8, h = i & 255;
        BtB[o * H_ + h] = __float2bfloat16(b2[h * H_ + o]);
    }
}

// Generic MFMA GEMM: C(MxN) = A(MxKD bf16) @ Bt(NxKD bf16)^T [+bias][relu].
// Depth-2 pipeline (counted vmcnt(4) across raw barrier).
template <int KD, bool RELU, bool OUT_BF16>
__global__ __launch_bounds__(256, 3) void k_gemm_nt(const __hip_bfloat16* __restrict__ A,
                                                    const __hip_bfloat16* __restrict__ Bt,
                                                    float* __restrict__ Cf,
                                                    __hip_bfloat16* __restrict__ Cb,
                                                    const float* __restrict__ bias,
                                                    int ldc, int ncols, int mvalid) {
    __shared__ __align__(16) short As[2][4096];
    __shared__ __align__(16) short Bs[2][4096];
    int t = threadIdx.x;
    int lane = t & 63, wave = t >> 6;
    int wm = wave >> 1, wn = wave & 1;
    int quad = lane >> 4, l16 = lane & 15;
    int row0 = blockIdx.y * 128, col0 = blockIdx.x * 128;

    f32x4 acc[4][4] = {};
    int r_ld = (lane >> 2);
    int koff = (((lane & 3) ^ ((lane >> 3) & 3)) * 8);  // swizzled 16B slot
    int swz = (l16 >> 1) & 3;                           // read-side slot XOR
    constexpr int NST = KD / 32;

    auto stage = [&](int buf, int k0) {
#pragma unroll
        for (int c = 0; c < 4; c++) {
            int q = wave * 4 + c;
            int ch = q & 7;
            int r = ch * 16 + r_ld;
            const __hip_bfloat16* gp;
            short* lp;
            if (q < 8) { gp = A  + (size_t)(row0 + r) * KD + k0 + koff; lp = &As[buf][ch * 512]; }
            else       { gp = Bt + (size_t)(col0 + r) * KD + k0 + koff; lp = &Bs[buf][ch * 512]; }
            __builtin_amdgcn_global_load_lds(
                (const __attribute__((address_space(1))) unsigned int*)(uintptr_t)gp,
                (__attribute__((address_space(3))) unsigned int*)(uintptr_t)lp,
                16, 0, 0);
        }
    };

    stage(0, 0);
    for (int kk = 0; kk < NST; kk++) {
        int cur = kk & 1;
        if (kk + 1 < NST) {
            stage(cur ^ 1, (kk + 1) * 32);
            PIPE_WAIT_ENTER(4)
        } else {
            PIPE_WAIT_ENTER(0)
        }
        bf16x8 a[4], b[4];
#pragma unroll
        for (int i = 0; i < 4; i++)
            a[i] = *(const bf16x8*)&As[cur][(wm * 64 + i * 16 + l16) * 32 + ((quad ^ swz) << 3)];
#pragma unroll
        for (int j = 0; j < 4; j++)
            b[j] = *(const bf16x8*)&Bs[cur][(wn * 64 + j * 16 + l16) * 32 + ((quad ^ swz) << 3)];
#pragma unroll
        for (int i = 0; i < 4; i++)
#pragma unroll
            for (int j = 0; j < 4; j++)
                acc[i][j] = __builtin_amdgcn_mfma_f32_16x16x32_bf16(a[i], b[j], acc[i][j], 0, 0, 0);
        PIPE_EXIT()
    }

#pragma unroll
    for (int i = 0; i < 4; i++) {
        int gm0 = row0 + wm * 64 + i * 16 + quad * 4;
#pragma unroll
        for (int r = 0; r < 4; r++) {
            int gm = gm0 + r;
            if (gm < mvalid) {
#pragma unroll
                for (int j = 0; j < 4; j++) {
                    int col = col0 + wn * 64 + l16 + j * 16;
                    if (col < ncols) {
                        float v = acc[i][j][r];
                        if (bias) v += bias[col];
                        if (RELU) v = fmaxf(v, 0.f);
                        if (OUT_BF16) Cb[(size_t)gm * ldc + col] = __float2bfloat16(v);
                        else          Cf[(size_t)gm * ldc + col] = v;
                    }
                }
            }
        }
    }
}

// Fused per-iteration GEMM launch (one grid, block-uniform branch):
//   blocks [0,128):    pair part — gh / outb from Abf
//   blocks [128,4224): V part — V8 = fp8(Abf @ Bt^T), permuted layout
__global__ __launch_bounds__(256, 4) void k_gemm_VP(const __hip_bfloat16* __restrict__ Abf,
                                                    const __hip_bfloat16* __restrict__ Bt,
                                                    const __hip_bfloat16* __restrict__ WhhB,
                                                    const __hip_bfloat16* __restrict__ BtB,
                                                    const float* __restrict__ bhh,
                                                    float* __restrict__ gh,
                                                    float* __restrict__ outb,
                                                    unsigned char* __restrict__ V8) {
    __shared__ __align__(16) short As[2][4096];
    __shared__ __align__(16) short Bs[2][4096];
    int bid = blockIdx.x;
    int t = threadIdx.x;
    int lane = t & 63, wave = t >> 6;
    int wm = wave >> 1, wn = wave & 1;
    int quad = lane >> 4, l16 = lane & 15;
    int r_ld = (lane >> 2);
    int koff = (((lane & 3) ^ ((lane >> 3) & 3)) * 8);
    int swz = (l16 >> 1) & 3;

    if (bid < 128) {
        // ---------------- pair part ----------------
        int pbx = bid & 7, pby = bid >> 3;
        bool ob = (pbx >= 6);
        const __hip_bfloat16* Bp = ob ? BtB : WhhB;
        int col0 = ob ? (pbx - 6) * 128 : pbx * 128;
        int ldc = ob ? H_ : NG_;
        float* C = ob ? outb : gh;
        int row0 = pby * 128;

        f32x4 acc[4][4] = {};
        auto stage = [&](int buf, int k0) {
#pragma unroll
            for (int c = 0; c < 4; c++) {
                int q = wave * 4 + c;
                int ch = q & 7;
                int r = ch * 16 + r_ld;
                const __hip_bfloat16* gp;
                short* lp;
                if (q < 8) { gp = Abf + ((size_t)(row0 + r) << 8) + k0 + koff; lp = &As[buf][ch * 512]; }
                else       { gp = Bp  + ((size_t)(col0 + r) << 8) + k0 + koff; lp = &Bs[buf][ch * 512]; }
                __builtin_amdgcn_global_load_lds(
                    (const __attribute__((address_space(1))) unsigned int*)(uintptr_t)gp,
                    (__attribute__((address_space(3))) unsigned int*)(uintptr_t)lp,
                    16, 0, 0);
            }
        };
        stage(0, 0);
        for (int kk = 0; kk < 8; kk++) {
            int cur = kk & 1;
            if (kk + 1 < 8) {
                stage(cur ^ 1, (kk + 1) * 32);
                PIPE_WAIT_ENTER(4)
            } else {
                PIPE_WAIT_ENTER(0)
            }
            bf16x8 a[4], b[4];
#pragma unroll
            for (int i = 0; i < 4; i++)
                a[i] = *(const bf16x8*)&As[cur][(wm * 64 + i * 16 + l16) * 32 + ((quad ^ swz) << 3)];
#pragma unroll
            for (int j = 0; j < 4; j++)
                b[j] = *(const bf16x8*)&Bs[cur][(wn * 64 + j * 16 + l16) * 32 + ((quad ^ swz) << 3)];
#pragma unroll
            for (int i = 0; i < 4; i++)
#pragma unroll
                for (int j = 0; j < 4; j++)
                    acc[i][j] = __builtin_amdgcn_mfma_f32_16x16x32_bf16(a[i], b[j], acc[i][j], 0, 0, 0);
            PIPE_EXIT()
        }
#pragma unroll
        for (int i = 0; i < 4; i++) {
            int gm0 = row0 + wm * 64 + i * 16 + quad * 4;
#pragma unroll
            for (int r = 0; r < 4; r++) {
                int gm = gm0 + r;
                if (gm < N_) {
#pragma unroll
                    for (int j = 0; j < 4; j++) {
                        int col = col0 + wn * 64 + l16 + j * 16;
                        float v = acc[i][j][r] + (ob ? 0.f : bhh[col]);
                        C[(size_t)gm * ldc + col] = v;
                    }
                }
            }
        }
        return;
    }

    // ---------------- V part ----------------
    int vb = bid - 128;
    int bx = vb & 255, by = vb >> 8;
    int row0 = by * 128, col0 = bx * 128;
    int obase = bx * 8;                    // o = (obase+ch)&255
    int kb = (bx >> 5) * 16;               // k16*16
    short* Ps = &As[0][0];                 // epilogue alias: 32 x 136 shorts

    f32x4 acc[4][4] = {};
    auto stage = [&](int buf, int k0) {
#pragma unroll
        for (int c = 0; c < 4; c++) {
            int q = wave * 4 + c;
            int ch = q & 7;
            const __hip_bfloat16* gp;
            short* lp;
            if (q < 8) {
                gp = Abf + ((size_t)(row0 + ch * 16 + r_ld) << 8) + k0 + koff;
                lp = &As[buf][ch * 512];
            } else {
                int nv = ((obase + ch) & 255) * 128 + kb + r_ld;   // f -> nv remap
                gp = Bt + ((size_t)nv << 8) + k0 + koff;
                lp = &Bs[buf][ch * 512];
            }
            __builtin_amdgcn_global_load_lds(
                (const __attribute__((address_space(1))) unsigned int*)(uintptr_t)gp,
                (__attribute__((address_space(3))) unsigned int*)(uintptr_t)lp,
                16, 0, 0);
        }
    };
    stage(0, 0);
    for (int kk = 0; kk < 8; kk++) {
        int cur = kk & 1;
        if (kk + 1 < 8) {
            stage(cur ^ 1, (kk + 1) * 32);
            PIPE_WAIT_ENTER(4)
        } else {
            PIPE_WAIT_ENTER(0)
        }
        bf16x8 a[4], b[4];
#pragma unroll
        for (int i = 0; i < 4; i++)
            a[i] = *(const bf16x8*)&As[cur][(wm * 64 + i * 16 + l16) * 32 + ((quad ^ swz) << 3)];
#pragma unroll
        for (int j = 0; j < 4; j++)
            b[j] = *(const bf16x8*)&Bs[cur][(wn * 64 + j * 16 + l16) * 32 + ((quad ^ swz) << 3)];
#pragma unroll
        for (int i = 0; i < 4; i++)
#pragma unroll
            for (int j = 0; j < 4; j++)
                acc[i][j] = __builtin_amdgcn_mfma_f32_16x16x32_bf16(a[i], b[j], acc[i][j], 0, 0, 0);
        PIPE_EXIT()
    }

    // 4-pass epilogue: stage 32 scaled-bf16 rows in Ps, convert+store coalesced uint4.
#pragma unroll
    for (int pp = 0; pp < 4; pp++) {
        if (wm == (pp >> 1)) {
#pragma unroll
            for (int ii = 0; ii < 2; ii++) {
                const int i = (pp & 1) * 2 + ii;       // compile-time acc index
                int lr = ii * 16 + quad * 4;           // local row in [0,32)
#pragma unroll
                for (int r = 0; r < 4; r++) {
#pragma unroll
                    for (int j = 0; j < 4; j++) {
                        int col = wn * 64 + j * 16 + l16;
                        Ps[(lr + r) * 136 + col] = bfbits(acc[i][j][r] * VSCALE);
                    }
                }
            }
        }
        __syncthreads();
        {
            int row = t >> 3;            // 0..31
            int col = (t & 7) * 16;      // 0..112 step 16
            int gm = row0 + pp * 32 + row;
            if (gm < N_) {
                uint4 ua = *(const uint4*)&Ps[row * 136 + col];
                uint4 ub = *(const uint4*)&Ps[row * 136 + col + 8];
                unsigned p0 = __builtin_amdgcn_cvt_pk_fp8_f32(bf_lo(ua.x), bf_hi(ua.x), 0, false);
                p0 = __builtin_amdgcn_cvt_pk_fp8_f32(bf_lo(ua.y), bf_hi(ua.y), p0, true);
                unsigned p1 = __builtin_amdgcn_cvt_pk_fp8_f32(bf_lo(ua.z), bf_hi(ua.z), 0, false);
                p1 = __builtin_amdgcn_cvt_pk_fp8_f32(bf_lo(ua.w), bf_hi(ua.w), p1, true);
                unsigned p2 = __builtin_amdgcn_cvt_pk_fp8_f32(bf_lo(ub.x), bf_hi(ub.x), 0, false);
                p2 = __builtin_amdgcn_cvt_pk_fp8_f32(bf_lo(ub.y), bf_hi(ub.y), p2, true);
                unsigned p3 = __builtin_amdgcn_cvt_pk_fp8_f32(bf_lo(ub.z), bf_hi(ub.z), 0, false);
                p3 = __builtin_amdgcn_cvt_pk_fp8_f32(bf_lo(ub.w), bf_hi(ub.w), p3, true);
                uint4 o4;
                o4.x = p0; o4.y = p1; o4.z = p2; o4.w = p3;
                *(uint4*)(V8 + (size_t)gm * NV_ + col0 + col) = o4;
            }
        }
        __syncthreads();
    }
}

// gi = relu(agg/c + conv_b) @ Wih^T + bih  with the m-transform FUSED into
// A-staging (reg-staged: waves 0-1 load agg f32, transform, ds_write; waves
// 2-3 global_load_lds B with counted vmcnt).  grid (6, 16), block 256.
__global__ __launch_bounds__(256, 3) void k_gemm_gi(const float* __restrict__ agg,
                                                    const float* __restrict__ counts,
                                                    const float* __restrict__ conv_b,
                                                    const __hip_bfloat16* __restrict__ WihB,
                                                    const float* __restrict__ bih,
                                                    float* __restrict__ gi) {
    __shared__ __align__(16) short As[2][4096];
    __shared__ __align__(16) short Bs[2][4096];
    __shared__ __align__(16) float conv_lds[256];
    int t = threadIdx.x;
    int lane = t & 63, wave = t >> 6;
    int wm = wave >> 1, wn = wave & 1;
    int quad = lane >> 4, l16 = lane & 15;
    int row0 = blockIdx.y * 128, col0 = blockIdx.x * 128;
    int r_ld = (lane >> 2);
    int koff = (((lane & 3) ^ ((lane >> 3) & 3)) * 8);
    int swz = (l16 >> 1) & 3;
    bool arole = (wave < 2);

    conv_lds[t] = conv_b[t];
    __syncthreads();

    f32x4 acc[4][4] = {};
    float rcv[4];
    const float* asrc[4];
    if (arole) {
#pragma unroll
        for (int c = 0; c < 4; c++) {
            int ch = wave * 4 + c;
            int row = row0 + ch * 16 + r_ld;
            int rowc = row < N_ ? row : N_ - 1;   // clamp padded rows (discarded later)
            rcv[c] = 1.f / fmaxf(counts[rowc], 1.f);
            asrc[c] = agg + (size_t)rowc * 256;
        }
    }
    float4 R[2][4][2];

    auto loadA = [&](int buf, int k0) {
#pragma unroll
        for (int c = 0; c < 4; c++) {
            R[buf][c][0] = *(const float4*)(asrc[c] + k0 + koff);
            R[buf][c][1] = *(const float4*)(asrc[c] + k0 + koff + 4);
        }
    };
    auto stageB = [&](int buf, int k0) {
#pragma unroll
        for (int c = 0; c < 4; c++) {
            int ch = (wave * 4 + c) & 7;
            const __hip_bfloat16* gp = WihB + (size_t)(col0 + ch * 16 + r_ld) * 256 + k0 + koff;
            short* lp = &Bs[buf][ch * 512];
            __builtin_amdgcn_global_load_lds(
                (const __attribute__((address_space(1))) unsigned int*)(uintptr_t)gp,
                (__attribute__((address_space(3))) unsigned int*)(uintptr_t)lp,
                16, 0, 0);
        }
    };
    auto writeA = [&](int buf, int k0) {
        float4 cb0 = *(const float4*)&conv_lds[k0 + koff];
        float4 cb1 = *(const float4*)&conv_lds[k0 + koff + 4];
#pragma unroll
        for (int c = 0; c < 4; c++) {
            int ch = wave * 4 + c;
            float rc = rcv[c];
            float4 a0 = R[buf][c][0], a1 = R[buf][c][1];
            bf16x8 v;
            v[0] = bfbits(fmaxf(a0.x * rc + cb0.x, 0.f));
            v[1] = bfbits(fmaxf(a0.y * rc + cb0.y, 0.f));
            v[2] = bfbits(fmaxf(a0.z * rc + cb0.z, 0.f));
            v[3] = bfbits(fmaxf(a0.w * rc + cb0.w, 0.f));
            v[4] = bfbits(fmaxf(a1.x * rc + cb1.x, 0.f));
            v[5] = bfbits(fmaxf(a1.y * rc + cb1.y, 0.f));
            v[6] = bfbits(fmaxf(a1.z * rc + cb1.z, 0.f));
            v[7] = bfbits(fmaxf(a1.w * rc + cb1.w, 0.f));
            *(bf16x8*)&As[buf][ch * 512 + lane * 8] = v;   // same slotting as gload_lds
        }
    };

    if (arole) loadA(0, 0); else stageB(0, 0);
#pragma unroll
    for (int kk = 0; kk < 8; kk++) {
        const int cur = kk & 1;
        if (kk + 1 < 8) {
            if (arole) loadA(cur ^ 1, (kk + 1) * 32);
            else       stageB(cur ^ 1, (kk + 1) * 32);
        }
        if (arole) {
            writeA(cur, kk * 32);   // compiler auto-waits on R[cur]'s loads
            asm volatile("s_waitcnt lgkmcnt(0)" ::: "memory");
        } else {
            if (kk + 1 < 8) { asm volatile("s_waitcnt vmcnt(4)" ::: "memory"); }
            else            { asm volatile("s_waitcnt vmcnt(0)" ::: "memory"); }
        }
        __builtin_amdgcn_s_barrier();
        asm volatile("" ::: "memory");
        __builtin_amdgcn_sched_barrier(0);
        bf16x8 a[4], b[4];
#pragma unroll
        for (int i = 0; i < 4; i++)
            a[i] = *(const bf16x8*)&As[cur][(wm * 64 + i * 16 + l16) * 32 + ((quad ^ swz) << 3)];
#pragma unroll
        for (int j = 0; j < 4; j++)
            b[j] = *(const bf16x8*)&Bs[cur][(wn * 64 + j * 16 + l16) * 32 + ((quad ^ swz) << 3)];
#pragma unroll
        for (int i = 0; i < 4; i++)
#pragma unroll
            for (int j = 0; j < 4; j++)
                acc[i][j] = __builtin_amdgcn_mfma_f32_16x16x32_bf16(a[i], b[j], acc[i][j], 0, 0, 0);
        PIPE_EXIT()
    }

#pragma unroll
    for (int i = 0; i < 4; i++) {
        int gm0 = row0 + wm * 64 + i * 16 + quad * 4;
#pragma unroll
        for (int r = 0; r < 4; r++) {
            int gm = gm0 + r;
            if (gm < N_) {
#pragma unroll
                for (int j = 0; j < 4; j++) {
                    int col = col0 + wn * 64 + l16 + j * 16;
                    gi[(size_t)gm * NG_ + col] = acc[i][j][r] + bih[col];
                }
            }
        }
    }
}

// Tail GEMM with concat FUSED into A-staging: A row e = [h[row[e]], h[col[e]]]
// gathered+cvt'd in-regs.  B packed (384x512): cols 0..255 -> relu->o1bf;
// cols 256..383 -> h1.  grid (3, 32), block 256.
__global__ __launch_bounds__(256, 3) void k_gemm_tail2(const int* __restrict__ ei,
                                                       const float* __restrict__ h,
                                                       const __hip_bfloat16* __restrict__ Bpk,
                                                       const float* __restrict__ b1,
                                                       const float* __restrict__ b2,
                                                       __hip_bfloat16* __restrict__ o1bf,
                                                       float* __restrict__ h1) {
    __shared__ __align__(16) short As[2][4096];
    __shared__ __align__(16) short Bs[2][4096];
    int t = threadIdx.x;
    int lane = t & 63, wave = t >> 6;
    int wm = wave >> 1, wn = wave & 1;
    int quad = lane >> 4, l16 = lane & 15;
    int row0 = blockIdx.y * 128, col0 = blockIdx.x * 128;
    int r_ld = (lane >> 2);
    int koff = (((lane & 3) ^ ((lane >> 3) & 3)) * 8);
    int swz = (l16 >> 1) & 3;
    bool arole = (wave < 2);

    f32x4 acc[4][4] = {};
    const float* src0[4];
    const float* src1[4];
    if (arole) {
#pragma unroll
        for (int c = 0; c < 4; c++) {
            int ch = wave * 4 + c;
            int e = row0 + ch * 16 + r_ld;          // edge id, always < E_
            src0[c] = h + (size_t)ei[e] * 256;
            src1[c] = h + (size_t)ei[E_ + e] * 256;
        }
    }
    float4 R[2][4][2];

    auto loadA = [&](int buf, int k0) {
        bool hi = (k0 >= 256);
        int kc = (k0 & 255) + koff;
#pragma unroll
        for (int c = 0; c < 4; c++) {
            const float* s = hi ? src1[c] : src0[c];
            R[buf][c][0] = *(const float4*)(s + kc);
            R[buf][c][1] = *(const float4*)(s + kc + 4);
        }
    };
    auto stageB = [&](int buf, int k0) {
#pragma unroll
        for (int c = 0; c < 4; c++) {
            int ch = (wave * 4 + c) & 7;
            const __hip_bfloat16* gp = Bpk + (size_t)(col0 + ch * 16 + r_ld) * 512 + k0 + koff;
            short* lp = &Bs[buf][ch * 512];
            __builtin_amdgcn_global_load_lds(
                (const __attribute__((address_space(1))) unsigned int*)(uintptr_t)gp,
                (__attribute__((address_space(3))) unsigned int*)(uintptr_t)lp,
                16, 0, 0);
        }
    };
    auto writeA = [&](int buf) {
#pragma unroll
        for (int c = 0; c < 4; c++) {
            int ch = wave * 4 + c;
            float4 a0 = R[buf][c][0], a1 = R[buf][c][1];
            bf16x8 v;
            v[0] = bfbits(a0.x); v[1] = bfbits(a0.y); v[2] = bfbits(a0.z); v[3] = bfbits(a0.w);
            v[4] = bfbits(a1.x); v[5] = bfbits(a1.y); v[6] = bfbits(a1.z); v[7] = bfbits(a1.w);
            *(bf16x8*)&As[buf][ch * 512 + lane * 8] = v;
        }
    };

    if (arole) loadA(0, 0); else stageB(0, 0);
#pragma unroll
    for (int kk = 0; kk < 16; kk++) {
        const int cur = kk & 1;
        if (kk + 1 < 16) {
            if (arole) loadA(cur ^ 1, (kk + 1) * 32);
            else       stageB(cur ^ 1, (kk + 1) * 32);
        }
        if (arole) {
            writeA(cur);
            asm volatile("s_waitcnt lgkmcnt(0)" ::: "memory");
        } else {
            if (kk + 1 < 16) { asm volatile("s_waitcnt vmcnt(4)" ::: "memory"); }
            else             { asm volatile("s_waitcnt vmcnt(0)" ::: "memory"); }
        }
        __builtin_amdgcn_s_barrier();
        asm volatile("" ::: "memory");
        __builtin_amdgcn_sched_barrier(0);
        bf16x8 a[4], b[4];
#pragma unroll
        for (int i = 0; i < 4; i++)
            a[i] = *(const bf16x8*)&As[cur][(wm * 64 + i * 16 + l16) * 32 + ((quad ^ swz) << 3)];
#pragma unroll
        for (int j = 0; j < 4; j++)
            b[j] = *(const bf16x8*)&Bs[cur][(wn * 64 + j * 16 + l16) * 32 + ((quad ^ swz) << 3)];
#pragma unroll
        for (int i = 0; i < 4; i++)
#pragma unroll
            for (int j = 0; j < 4; j++)
                acc[i][j] = __builtin_amdgcn_mfma_f32_16x16x32_bf16(a[i], b[j], acc[i][j], 0, 0, 0);
        PIPE_EXIT()
    }

#pragma unroll
    for (int i = 0; i < 4; i++) {
        int gm0 = row0 + wm * 64 + i * 16 + quad * 4;
#pragma unroll
        for (int r = 0; r < 4; r++) {
            int gm = gm0 + r;
#pragma unroll
            for (int j = 0; j < 4; j++) {
                int col = col0 + wn * 64 + l16 + j * 16;
                float v = acc[i][j][r];
                if (col < 256) {
                    v = fmaxf(v + b1[col], 0.f);
                    o1bf[(size_t)gm * H_ + col] = __float2bfloat16(v);
                } else {
                    h1[(size_t)gm * 128 + (col - 256)] = v + b2[col - 256];
                }
            }
        }
    }
}

// msg[e,o] = (he[e,:]/64).(fp8 V[row[e],o,:]) + outb[row[e],o]; atomicAdd into agg[col[e],o]
__global__ void k_msg(const int* __restrict__ ei, const float* __restrict__ he,
                      const unsigned char* __restrict__ V8, const float* __restrict__ outb,
                      float* __restrict__ agg) {
    int e = blockIdx.x, o = threadIdx.x;
    __shared__ float hs[KH_];
    if (o < KH_) hs[o] = he[e * KH_ + o] * VSCALE_INV;
    __syncthreads();
    int r = ei[e], c = ei[E_ + e];
    float acc = outb[(size_t)r * H_ + o];
    const unsigned char* vbase = V8 + (size_t)r * NV_ + o * 16;
#pragma unroll
    for (int q = 0; q < 8; q++) {       // 8 x 16B chunks, stride 4096
        uint4 u = *(const uint4*)(vbase + (size_t)q * 4096);
        const float* hp = hs + q * 16;
        f32x2 f;
        f = __builtin_amdgcn_cvt_pk_f32_fp8(u.x, false); acc += hp[0]  * f.x + hp[1]  * f.y;
        f = __builtin_amdgcn_cvt_pk_f32_fp8(u.x, true);  acc += hp[2]  * f.x + hp[3]  * f.y;
        f = __builtin_amdgcn_cvt_pk_f32_fp8(u.y, false); acc += hp[4]  * f.x + hp[5]  * f.y;
        f = __builtin_amdgcn_cvt_pk_f32_fp8(u.y, true);  acc += hp[6]  * f.x + hp[7]  * f.y;
        f = __builtin_amdgcn_cvt_pk_f32_fp8(u.z, false); acc += hp[8]  * f.x + hp[9]  * f.y;
        f = __builtin_amdgcn_cvt_pk_f32_fp8(u.z, true);  acc += hp[10] * f.x + hp[11] * f.y;
        f = __builtin_amdgcn_cvt_pk_f32_fp8(u.w, false); acc += hp[12] * f.x + hp[13] * f.y;
        f = __builtin_amdgcn_cvt_pk_f32_fp8(u.w, true);  acc += hp[14] * f.x + hp[15] * f.y;
    }
    atomicAdd(&agg[(size_t)c * H_ + o], acc);
}

// GRU pointwise; refreshes Abf = bf16(h); zeroes agg for the next iteration.
__global__ void k_gru_update(const float* __restrict__ gi, const float* __restrict__ gh,
                             float* __restrict__ h, __hip_bfloat16* __restrict__ Abf,
                             float* __restrict__ agg) {
    int i = blockIdx.x * blockDim.x + threadIdx.x;
    if (i >= N_ * H_) return;
    int n = i >> 8, j = i & 255;
    const float* gip = gi + (size_t)n * NG_;
    const float* ghp = gh + (size_t)n * NG_;
    float r = 1.f / (1.f + expf(-(gip[j] + ghp[j])));
    float z = 1.f / (1.f + expf(-(gip[H_ + j] + ghp[H_ + j])));
    float nn = tanhf(gip[2 * H_ + j] + r * ghp[2 * H_ + j]);
    float hv = (1.f - z) * nn + z * h[i];
    h[i] = hv;
    Abf[i] = __float2bfloat16(hv);
    agg[i] = 0.f;
}

// batchnorm stats over E rows, per column j   grid 128, block 256
__global__ void k_bnstats(const float* __restrict__ h1, float* __restrict__ mu,
                          float* __restrict__ rsig) {
    int j = blockIdx.x, t = threadIdx.x;
    float s = 0.f, ss = 0.f;
    for (int e = t; e < E_; e += 256) {
        float v = h1[(size_t)e * 128 + j];
        s += v;
        ss += v * v;
    }
    __shared__ float rs[256], rss[256];
    rs[t] = s; rss[t] = ss;
    __syncthreads();
    for (int off = 128; off > 0; off >>= 1) {
        if (t < off) { rs[t] += rs[t + off]; rss[t] += rss[t + off]; }
        __syncthreads();
    }
    if (t == 0) {
        float m_ = rs[0] / E_;
        float v_ = rss[0] / E_ - m_ * m_;
        mu[j] = m_;
        rsig[j] = rsqrtf(v_ + 1e-5f);
    }
}

// precs[e] = relu(bn(h1[e])) . l6_W2 + b
__global__ void k_precs(const float* __restrict__ h1, const float* __restrict__ mu,
                        const float* __restrict__ rsig, const float* __restrict__ g,
                        const float* __restrict__ bb, const float* __restrict__ W2,
                        const float* __restrict__ b2, float* __restrict__ out) {
    int e = blockIdx.x * blockDim.x + threadIdx.x;
    if (e >= E_) return;
    float acc = b2[0];
#pragma unroll 4
    for (int j = 0; j < 128; j++) {
        float v = (h1[(size_t)e * 128 + j] - mu[j]) * rsig[j] * g[j] + bb[j];
        acc += fmaxf(v, 0.f) * W2[j];
    }
    out[(size_t)E_ * 242 + e] = acc;
}

extern "C" void kernel_launch(void* const* d_in, const int* in_sizes, int n_in,
                              void* d_out, int out_size, void* d_ws, size_t ws_size,
                              hipStream_t stream) {
    const int*   x        = (const int*)  d_in[0];
    const float* pos      = (const float*)d_in[1];
    const int*   ei       = (const int*)  d_in[2];
    const float* edge_atr = (const float*)d_in[3];
    const float* emb      = (const float*)d_in[4];
    const float* lin0_W   = (const float*)d_in[5];
    const float* lin0_b   = (const float*)d_in[6];
    const float* mlp1_W   = (const float*)d_in[7];
    const float* mlp1_b   = (const float*)d_in[8];
    const float* mlp2_W   = (const float*)d_in[9];
    const float* mlp2_b   = (const float*)d_in[10];
    const float* conv_b   = (const float*)d_in[11];
    const float* gru_Wih  = (const float*)d_in[12];
    const float* gru_Whh  = (const float*)d_in[13];
    const float* gru_bih  = (const float*)d_in[14];
    const float* gru_bhh  = (const float*)d_in[15];
    const float* lin1_W   = (const float*)d_in[16];
    const float* lin1_b   = (const float*)d_in[17];
    const float* lin2_W   = (const float*)d_in[18];
    const float* lin2_b   = (const float*)d_in[19];
    const float* l6_W1    = (const float*)d_in[20];
    const float* l6_b1    = (const float*)d_in[21];
    const float* bn_g     = (const float*)d_in[22];
    const float* bn_b     = (const float*)d_in[23];
    const float* l6_W2    = (const float*)d_in[24];
    const float* l6_b2    = (const float*)d_in[25];
    float* out = (float*)d_out;

    // workspace layout
    char* w = (char*)d_ws;
    size_t off = 0;
    auto alloc = [&](size_t bytes) -> void* {
        void* p = w + off;
        off = (off + bytes + 255) & ~(size_t)255;
        return p;
    };
    float* hbuf   = (float*)alloc((size_t)N_ * H_ * 4);
    float* aggm   = (float*)alloc((size_t)N_ * H_ * 4);
    float* outb   = (float*)alloc((size_t)N_ * H_ * 4);
    float* he     = (float*)alloc((size_t)E_ * KH_ * 4);
    float* gi     = (float*)alloc((size_t)N_ * NG_ * 4);
    float* gh     = (float*)alloc((size_t)N_ * NG_ * 4);
    float* h1     = (float*)alloc((size_t)E_ * 128 * 4);
    float* counts = (float*)alloc((size_t)N_ * 4);
    float* mu     = (float*)alloc(128 * 4);
    float* rsig   = (float*)alloc(128 * 4);
    unsigned char* V8      = (unsigned char*)alloc((size_t)N_ * NV_);          // 65.5 MB fp8
    __hip_bfloat16* Abf    = (__hip_bfloat16*)alloc((size_t)MPAD_ * H_ * 2);
    __hip_bfloat16* Bt     = (__hip_bfloat16*)alloc((size_t)NV_ * H_ * 2);     // 16.8 MB
    __hip_bfloat16* WihB   = (__hip_bfloat16*)alloc((size_t)NG_ * H_ * 2);
    __hip_bfloat16* WhhB   = (__hip_bfloat16*)alloc((size_t)NG_ * H_ * 2);
    __hip_bfloat16* Bpk    = (__hip_bfloat16*)alloc((size_t)384 * 512 * 2);
    __hip_bfloat16* lin2Wb = (__hip_bfloat16*)alloc((size_t)H_ * H_ * 2);
    __hip_bfloat16* BtB    = (__hip_bfloat16*)alloc((size_t)H_ * H_ * 2);
    __hip_bfloat16* o1bf   = (__hip_bfloat16*)alloc((size_t)E_ * H_ * 2);

    k_lin0<<<MPAD_, 256, 0, stream>>>(x, pos, emb, lin0_W, lin0_b, hbuf, Abf);
    k_he<<<E_, 128, 0, stream>>>(edge_atr, mlp1_W, mlp1_b, he);
    hipMemsetAsync(counts, 0, (size_t)N_ * 4, stream);
    hipMemsetAsync(aggm, 0, (size_t)N_ * H_ * 4, stream);
    k_counts<<<(E_ + 255) / 256, 256, 0, stream>>>(ei, counts);
    k_trans_bt<<<dim3(NV_ / 64, H_ / 32), 256, 0, stream>>>(mlp2_W, Bt);
    k_prep_w<<<768, 256, 0, stream>>>(gru_Wih, gru_Whh, lin1_W, l6_W1, lin2_W, mlp2_b,
                                      WihB, WhhB, Bpk, lin2Wb, BtB);

    for (int it = 0; it < 3; it++) {
        // fused: gh = Abf@Whh^T + bhh, outb = Abf@BtB^T, V8 = fp8(Abf@Bt^T)
        k_gemm_VP<<<128 + (NV_ / 128) * (MPAD_ / 128), 256, 0, stream>>>(
            Abf, Bt, WhhB, BtB, gru_bhh, gh, outb, V8);
        k_msg<<<E_, 256, 0, stream>>>(ei, he, V8, outb, aggm);
        // gi = relu(agg/c + conv_b) @ Wih^T + bih   (m-transform fused in staging)
        k_gemm_gi<<<dim3(6, MPAD_ / 128), 256, 0, stream>>>(
            aggm, counts, conv_b, WihB, gru_bih, gi);
        k_gru_update<<<(N_ * H_ + 255) / 256, 256, 0, stream>>>(gi, gh, hbuf, Abf, aggm);
    }

    k_gemm_tail2<<<dim3(3, E_ / 128), 256, 0, stream>>>(ei, hbuf, Bpk, lin1_b, l6_b1,
                                                        o1bf, h1);
    k_gemm_nt<256, false, false><<<dim3(2, E_ / 128), 256, 0, stream>>>(
        o1bf, lin2Wb, out, nullptr, lin2_b, 242, 242, E_);
    k_bnstats<<<128, 256, 0, stream>>>(h1, mu, rsig);
    k_precs<<<(E_ + 255) / 256, 256, 0, stream>>>(h1, mu, rsig, bn_g, bn_b, l6_W2, l6_b2, out);
}

// Round 7
// 446.657 us; speedup vs baseline: 1.1067x; 1.1067x over previous
//
#include <hip/hip_runtime.h>
#include <hip/hip_bf16.h>

// Problem constants (fixed by the reference)
constexpr int N_ = 2000;   // nodes
constexpr int E_ = 4096;   // edges
constexpr int H_ = 256;    // hidden
constexpr int KH_ = 128;   // he dim (mlp1 out)
constexpr int NV_ = H_ * KH_; // 32768, V row length — fp8 bytes
constexpr int MPAD_ = 2048;   // padded M for node-side MFMA GEMMs
constexpr int NG_ = 768;      // GRU gate width (3*H)
constexpr float VSCALE = 64.f;     // fp8 scale for V (avoids e4m3 subnormals)
constexpr float VSCALE_INV = 1.f / 64.f;

typedef short bf16x8 __attribute__((ext_vector_type(8)));
typedef float f32x4  __attribute__((ext_vector_type(4)));
typedef float f32x2  __attribute__((ext_vector_type(2)));

__device__ __forceinline__ float bf_lo(unsigned u) { return __uint_as_float(u << 16); }
__device__ __forceinline__ float bf_hi(unsigned u) { return __uint_as_float(u & 0xffff0000u); }
__device__ __forceinline__ short bfbits(float f) {
    __hip_bfloat16 b = __float2bfloat16(f);
    return *(short*)&b;
}

// ---- pipeline sync helpers (T4: counted vmcnt across raw barrier), depth-2 ----
#define PIPE_WAIT_ENTER(N_OUTST)                                   \
    asm volatile("s_waitcnt vmcnt(" #N_OUTST ")" ::: "memory");    \
    __builtin_amdgcn_s_barrier();                                  \
    asm volatile("" ::: "memory");                                 \
    __builtin_amdgcn_sched_barrier(0);

#define PIPE_EXIT()                                                \
    __builtin_amdgcn_sched_barrier(0);                             \
    asm volatile("" ::: "memory");                                 \
    __builtin_amdgcn_s_barrier();

// out = relu([emb[x], pos] @ lin0_W.T + b); also emits Abf (bf16, zero-padded rows).
__global__ void k_lin0(const int* __restrict__ x, const float* __restrict__ pos,
                       const float* __restrict__ emb, const float* __restrict__ W,
                       const float* __restrict__ b, float* __restrict__ out,
                       __hip_bfloat16* __restrict__ Abf) {
    int n = blockIdx.x, t = threadIdx.x;
    if (n >= N_) { Abf[(size_t)n * H_ + t] = __float2bfloat16(0.f); return; }
    __shared__ float in_p[8];
    if (t < 5) in_p[t] = emb[x[n] * 5 + t];
    else if (t < 8) in_p[t] = pos[n * 3 + (t - 5)];
    __syncthreads();
    float acc = b[t];
#pragma unroll
    for (int i = 0; i < 8; i++) acc += in_p[i] * W[t * 8 + i];
    float v = fmaxf(acc, 0.f);
    out[n * H_ + t] = v;
    Abf[(size_t)n * H_ + t] = __float2bfloat16(v);
}

// he = relu(edge_atr @ mlp1_W.T + b)   grid E, block 128
__global__ void k_he(const float* __restrict__ ea, const float* __restrict__ W,
                     const float* __restrict__ b, float* __restrict__ he) {
    int e = blockIdx.x, t = threadIdx.x;
    __shared__ float a[5];
    if (t < 5) a[t] = ea[e * 5 + t];
    __syncthreads();
    float acc = b[t];
#pragma unroll
    for (int i = 0; i < 5; i++) acc += a[i] * W[t * 5 + i];
    he[e * KH_ + t] = fmaxf(acc, 0.f);
}

__global__ void k_counts(const int* __restrict__ ei, float* __restrict__ counts) {
    int e = blockIdx.x * blockDim.x + threadIdx.x;
    if (e < E_) atomicAdd(&counts[ei[E_ + e]], 1.0f);
}

// Bt[nv][h] = mlp2_W[h*32768 + nv] as bf16 (transpose+convert), once per launch.
__global__ void k_trans_bt(const float* __restrict__ W, __hip_bfloat16* __restrict__ Bt) {
    __shared__ float tile[32][68];   // 68: 16B-aligned rows, bank-shifted
    int t = threadIdx.x;
    int n0 = blockIdx.x * 64, k0 = blockIdx.y * 32;
#pragma unroll
    for (int i = 0; i < 2; i++) {
        int idx = t + i * 256;                 // 0..511
        int kk = idx >> 4, nn = (idx & 15) * 4;
        float4 f = *(const float4*)&W[(size_t)(k0 + kk) * NV_ + n0 + nn];
        *(float4*)&tile[kk][nn] = f;
    }
    __syncthreads();
#pragma unroll
    for (int i = 0; i < 2; i++) {
        int idx = t + i * 256;                 // 0..511
        int nn = idx >> 3, k4 = (idx & 7) * 4;
        short4 s;
        s.x = bfbits(tile[k4 + 0][nn]);
        s.y = bfbits(tile[k4 + 1][nn]);
        s.z = bfbits(tile[k4 + 2][nn]);
        s.w = bfbits(tile[k4 + 3][nn]);
        *(short4*)&Bt[(size_t)(n0 + nn) * H_ + k0 + k4] = s;
    }
}

// One-time weight preps (bf16 converts + packed tail B + lin2 pad + mlp2_b transpose).
__global__ void k_prep_w(const float* __restrict__ Wih, const float* __restrict__ Whh,
                         const float* __restrict__ lin1W, const float* __restrict__ l6W1,
                         const float* __restrict__ lin2W, const float* __restrict__ b2,
                         __hip_bfloat16* __restrict__ WihB, __hip_bfloat16* __restrict__ WhhB,
                         __hip_bfloat16* __restrict__ Bpk,
                         __hip_bfloat16* __restrict__ lin2Wb, __hip_bfloat16* __restrict__ BtB) {
    int i = blockIdx.x * 256 + threadIdx.x;     // i < 196608
    if (i < NG_ * H_) {
        WihB[i] = __float2bfloat16(Wih[i]);
        WhhB[i] = __float2bfloat16(Whh[i]);
    }
    Bpk[i] = __float2bfloat16(i < 256 * 512 ? lin1W[i] : l6W1[i - 256 * 512]);
    if (i < 128 * 2 * H_) {
        int r = i >> 8, k = i & 255;
        lin2Wb[i] = __float2bfloat16(r < 242 ? lin2W[r * H_ + k] : 0.f);
        int o = i >> 8, h = i & 255;
        BtB[o * H_ + h] = __float2bfloat16(b2[h * H_ + o]);
    }
}

// Cbf[e] = bf16([h[row[e]], h[col[e]]])   grid E, block 256
__global__ void k_concat(const int* __restrict__ ei, const float* __restrict__ h,
                         __hip_bfloat16* __restrict__ Cbf) {
    int e = blockIdx.x, t = threadIdx.x;
    int r = ei[e], c = ei[E_ + e];
    Cbf[(size_t)e * 512 + t]       = __float2bfloat16(h[(size_t)r * H_ + t]);
    Cbf[(size_t)e * 512 + 256 + t] = __float2bfloat16(h[(size_t)c * H_ + t]);
}

// Generic MFMA GEMM: C(MxN) = A(MxKD bf16) @ Bt(NxKD bf16)^T [+bias][relu].
// Depth-2 pipeline (counted vmcnt(4) across raw barrier).
template <int KD, bool RELU, bool OUT_BF16>
__global__ __launch_bounds__(256, 3) void k_gemm_nt(const __hip_bfloat16* __restrict__ A,
                                                    const __hip_bfloat16* __restrict__ Bt,
                                                    float* __restrict__ Cf,
                                                    __hip_bfloat16* __restrict__ Cb,
                                                    const float* __restrict__ bias,
                                                    int ldc, int ncols, int mvalid) {
    __shared__ __align__(16) short As[2][4096];
    __shared__ __align__(16) short Bs[2][4096];
    int t = threadIdx.x;
    int lane = t & 63, wave = t >> 6;
    int wm = wave >> 1, wn = wave & 1;
    int quad = lane >> 4, l16 = lane & 15;
    int row0 = blockIdx.y * 128, col0 = blockIdx.x * 128;

    f32x4 acc[4][4] = {};
    int r_ld = (lane >> 2);
    int koff = (((lane & 3) ^ ((lane >> 3) & 3)) * 8);  // swizzled 16B slot
    int swz = (l16 >> 1) & 3;                           // read-side slot XOR
    constexpr int NST = KD / 32;

    auto stage = [&](int buf, int k0) {
#pragma unroll
        for (int c = 0; c < 4; c++) {
            int q = wave * 4 + c;
            int ch = q & 7;
            int r = ch * 16 + r_ld;
            const __hip_bfloat16* gp;
            short* lp;
            if (q < 8) { gp = A  + (size_t)(row0 + r) * KD + k0 + koff; lp = &As[buf][ch * 512]; }
            else       { gp = Bt + (size_t)(col0 + r) * KD + k0 + koff; lp = &Bs[buf][ch * 512]; }
            __builtin_amdgcn_global_load_lds(
                (const __attribute__((address_space(1))) unsigned int*)(uintptr_t)gp,
                (__attribute__((address_space(3))) unsigned int*)(uintptr_t)lp,
                16, 0, 0);
        }
    };

    stage(0, 0);
    for (int kk = 0; kk < NST; kk++) {
        int cur = kk & 1;
        if (kk + 1 < NST) {
            stage(cur ^ 1, (kk + 1) * 32);
            PIPE_WAIT_ENTER(4)
        } else {
            PIPE_WAIT_ENTER(0)
        }
        bf16x8 a[4], b[4];
#pragma unroll
        for (int i = 0; i < 4; i++)
            a[i] = *(const bf16x8*)&As[cur][(wm * 64 + i * 16 + l16) * 32 + ((quad ^ swz) << 3)];
#pragma unroll
        for (int j = 0; j < 4; j++)
            b[j] = *(const bf16x8*)&Bs[cur][(wn * 64 + j * 16 + l16) * 32 + ((quad ^ swz) << 3)];
#pragma unroll
        for (int i = 0; i < 4; i++)
#pragma unroll
            for (int j = 0; j < 4; j++)
                acc[i][j] = __builtin_amdgcn_mfma_f32_16x16x32_bf16(a[i], b[j], acc[i][j], 0, 0, 0);
        PIPE_EXIT()
    }

#pragma unroll
    for (int i = 0; i < 4; i++) {
        int gm0 = row0 + wm * 64 + i * 16 + quad * 4;
#pragma unroll
        for (int r = 0; r < 4; r++) {
            int gm = gm0 + r;
            if (gm < mvalid) {
#pragma unroll
                for (int j = 0; j < 4; j++) {
                    int col = col0 + wn * 64 + l16 + j * 16;
                    if (col < ncols) {
                        float v = acc[i][j][r];
                        if (bias) v += bias[col];
                        if (RELU) v = fmaxf(v, 0.f);
                        if (OUT_BF16) Cb[(size_t)gm * ldc + col] = __float2bfloat16(v);
                        else          Cf[(size_t)gm * ldc + col] = v;
                    }
                }
            }
        }
    }
}

// Fused per-iteration GEMM launch (one grid, block-uniform branch):
//   blocks [0,128):    pair part — gh / outb from Abf
//   blocks [128,4224): V part — V8 = fp8(Abf @ Bt^T), permuted layout
__global__ __launch_bounds__(256, 4) void k_gemm_VP(const __hip_bfloat16* __restrict__ Abf,
                                                    const __hip_bfloat16* __restrict__ Bt,
                                                    const __hip_bfloat16* __restrict__ WhhB,
                                                    const __hip_bfloat16* __restrict__ BtB,
                                                    const float* __restrict__ bhh,
                                                    float* __restrict__ gh,
                                                    float* __restrict__ outb,
                                                    unsigned char* __restrict__ V8) {
    __shared__ __align__(16) short As[2][4096];
    __shared__ __align__(16) short Bs[2][4096];
    int bid = blockIdx.x;
    int t = threadIdx.x;
    int lane = t & 63, wave = t >> 6;
    int wm = wave >> 1, wn = wave & 1;
    int quad = lane >> 4, l16 = lane & 15;
    int r_ld = (lane >> 2);
    int koff = (((lane & 3) ^ ((lane >> 3) & 3)) * 8);
    int swz = (l16 >> 1) & 3;

    if (bid < 128) {
        // ---------------- pair part ----------------
        int pbx = bid & 7, pby = bid >> 3;
        bool ob = (pbx >= 6);
        const __hip_bfloat16* Bp = ob ? BtB : WhhB;
        int col0 = ob ? (pbx - 6) * 128 : pbx * 128;
        int ldc = ob ? H_ : NG_;
        float* C = ob ? outb : gh;
        int row0 = pby * 128;

        f32x4 acc[4][4] = {};
        auto stage = [&](int buf, int k0) {
#pragma unroll
            for (int c = 0; c < 4; c++) {
                int q = wave * 4 + c;
                int ch = q & 7;
                int r = ch * 16 + r_ld;
                const __hip_bfloat16* gp;
                short* lp;
                if (q < 8) { gp = Abf + ((size_t)(row0 + r) << 8) + k0 + koff; lp = &As[buf][ch * 512]; }
                else       { gp = Bp  + ((size_t)(col0 + r) << 8) + k0 + koff; lp = &Bs[buf][ch * 512]; }
                __builtin_amdgcn_global_load_lds(
                    (const __attribute__((address_space(1))) unsigned int*)(uintptr_t)gp,
                    (__attribute__((address_space(3))) unsigned int*)(uintptr_t)lp,
                    16, 0, 0);
            }
        };
        stage(0, 0);
        for (int kk = 0; kk < 8; kk++) {
            int cur = kk & 1;
            if (kk + 1 < 8) {
                stage(cur ^ 1, (kk + 1) * 32);
                PIPE_WAIT_ENTER(4)
            } else {
                PIPE_WAIT_ENTER(0)
            }
            bf16x8 a[4], b[4];
#pragma unroll
            for (int i = 0; i < 4; i++)
                a[i] = *(const bf16x8*)&As[cur][(wm * 64 + i * 16 + l16) * 32 + ((quad ^ swz) << 3)];
#pragma unroll
            for (int j = 0; j < 4; j++)
                b[j] = *(const bf16x8*)&Bs[cur][(wn * 64 + j * 16 + l16) * 32 + ((quad ^ swz) << 3)];
#pragma unroll
            for (int i = 0; i < 4; i++)
#pragma unroll
                for (int j = 0; j < 4; j++)
                    acc[i][j] = __builtin_amdgcn_mfma_f32_16x16x32_bf16(a[i], b[j], acc[i][j], 0, 0, 0);
            PIPE_EXIT()
        }
#pragma unroll
        for (int i = 0; i < 4; i++) {
            int gm0 = row0 + wm * 64 + i * 16 + quad * 4;
#pragma unroll
            for (int r = 0; r < 4; r++) {
                int gm = gm0 + r;
                if (gm < N_) {
#pragma unroll
                    for (int j = 0; j < 4; j++) {
                        int col = col0 + wn * 64 + l16 + j * 16;
                        float v = acc[i][j][r] + (ob ? 0.f : bhh[col]);
                        C[(size_t)gm * ldc + col] = v;
                    }
                }
            }
        }
        return;
    }

    // ---------------- V part ----------------
    int vb = bid - 128;
    int bx = vb & 255, by = vb >> 8;
    int row0 = by * 128, col0 = bx * 128;
    int obase = bx * 8;                    // o = (obase+ch)&255
    int kb = (bx >> 5) * 16;               // k16*16
    short* Ps = &As[0][0];                 // epilogue alias: 32 x 136 shorts

    f32x4 acc[4][4] = {};
    auto stage = [&](int buf, int k0) {
#pragma unroll
        for (int c = 0; c < 4; c++) {
            int q = wave * 4 + c;
            int ch = q & 7;
            const __hip_bfloat16* gp;
            short* lp;
            if (q < 8) {
                gp = Abf + ((size_t)(row0 + ch * 16 + r_ld) << 8) + k0 + koff;
                lp = &As[buf][ch * 512];
            } else {
                int nv = ((obase + ch) & 255) * 128 + kb + r_ld;   // f -> nv remap
                gp = Bt + ((size_t)nv << 8) + k0 + koff;
                lp = &Bs[buf][ch * 512];
            }
            __builtin_amdgcn_global_load_lds(
                (const __attribute__((address_space(1))) unsigned int*)(uintptr_t)gp,
                (__attribute__((address_space(3))) unsigned int*)(uintptr_t)lp,
                16, 0, 0);
        }
    };
    stage(0, 0);
    for (int kk = 0; kk < 8; kk++) {
        int cur = kk & 1;
        if (kk + 1 < 8) {
            stage(cur ^ 1, (kk + 1) * 32);
            PIPE_WAIT_ENTER(4)
        } else {
            PIPE_WAIT_ENTER(0)
        }
        bf16x8 a[4], b[4];
#pragma unroll
        for (int i = 0; i < 4; i++)
            a[i] = *(const bf16x8*)&As[cur][(wm * 64 + i * 16 + l16) * 32 + ((quad ^ swz) << 3)];
#pragma unroll
        for (int j = 0; j < 4; j++)
            b[j] = *(const bf16x8*)&Bs[cur][(wn * 64 + j * 16 + l16) * 32 + ((quad ^ swz) << 3)];
#pragma unroll
        for (int i = 0; i < 4; i++)
#pragma unroll
            for (int j = 0; j < 4; j++)
                acc[i][j] = __builtin_amdgcn_mfma_f32_16x16x32_bf16(a[i], b[j], acc[i][j], 0, 0, 0);
        PIPE_EXIT()
    }

    // 4-pass epilogue: stage 32 scaled-bf16 rows in Ps, convert+store coalesced uint4.
#pragma unroll
    for (int pp = 0; pp < 4; pp++) {
        if (wm == (pp >> 1)) {
#pragma unroll
            for (int ii = 0; ii < 2; ii++) {
                const int i = (pp & 1) * 2 + ii;       // compile-time acc index
                int lr = ii * 16 + quad * 4;           // local row in [0,32)
#pragma unroll
                for (int r = 0; r < 4; r++) {
#pragma unroll
                    for (int j = 0; j < 4; j++) {
                        int col = wn * 64 + j * 16 + l16;
                        Ps[(lr + r) * 136 + col] = bfbits(acc[i][j][r] * VSCALE);
                    }
                }
            }
        }
        __syncthreads();
        {
            int row = t >> 3;            // 0..31
            int col = (t & 7) * 16;      // 0..112 step 16
            int gm = row0 + pp * 32 + row;
            if (gm < N_) {
                uint4 ua = *(const uint4*)&Ps[row * 136 + col];
                uint4 ub = *(const uint4*)&Ps[row * 136 + col + 8];
                unsigned p0 = __builtin_amdgcn_cvt_pk_fp8_f32(bf_lo(ua.x), bf_hi(ua.x), 0, false);
                p0 = __builtin_amdgcn_cvt_pk_fp8_f32(bf_lo(ua.y), bf_hi(ua.y), p0, true);
                unsigned p1 = __builtin_amdgcn_cvt_pk_fp8_f32(bf_lo(ua.z), bf_hi(ua.z), 0, false);
                p1 = __builtin_amdgcn_cvt_pk_fp8_f32(bf_lo(ua.w), bf_hi(ua.w), p1, true);
                unsigned p2 = __builtin_amdgcn_cvt_pk_fp8_f32(bf_lo(ub.x), bf_hi(ub.x), 0, false);
                p2 = __builtin_amdgcn_cvt_pk_fp8_f32(bf_lo(ub.y), bf_hi(ub.y), p2, true);
                unsigned p3 = __builtin_amdgcn_cvt_pk_fp8_f32(bf_lo(ub.z), bf_hi(ub.z), 0, false);
                p3 = __builtin_amdgcn_cvt_pk_fp8_f32(bf_lo(ub.w), bf_hi(ub.w), p3, true);
                uint4 o4;
                o4.x = p0; o4.y = p1; o4.z = p2; o4.w = p3;
                *(uint4*)(V8 + (size_t)gm * NV_ + col0 + col) = o4;
            }
        }
        __syncthreads();
    }
}

// gi = relu(agg/c + conv_b) @ Wih^T + bih, m-transform fused into A-staging.
// BALANCED roles: every wave stages 2 A-channels (f32 load+transform+ds_write)
// AND 2 B-channels (global_load_lds). Explicit vmcnt(6) drains A_cur+B_cur
// while leaving next-stage's 6 ops in flight.  grid (6, 16), block 256.
__global__ __launch_bounds__(256, 3) void k_gemm_gi(const float* __restrict__ agg,
                                                    const float* __restrict__ counts,
                                                    const float* __restrict__ conv_b,
                                                    const __hip_bfloat16* __restrict__ WihB,
                                                    const float* __restrict__ bih,
                                                    float* __restrict__ gi) {
    __shared__ __align__(16) short As[2][4096];
    __shared__ __align__(16) short Bs[2][4096];
    __shared__ __align__(16) float conv_lds[256];
    int t = threadIdx.x;
    int lane = t & 63, wave = t >> 6;
    int wm = wave >> 1, wn = wave & 1;
    int quad = lane >> 4, l16 = lane & 15;
    int row0 = blockIdx.y * 128, col0 = blockIdx.x * 128;
    int r_ld = (lane >> 2);
    int koff = (((lane & 3) ^ ((lane >> 3) & 3)) * 8);
    int swz = (l16 >> 1) & 3;

    conv_lds[t] = conv_b[t];
    __syncthreads();

    f32x4 acc[4][4] = {};
    float rcv[2];
    const float* asrc[2];
#pragma unroll
    for (int c = 0; c < 2; c++) {
        int ch = wave * 2 + c;
        int row = row0 + ch * 16 + r_ld;
        int rowc = row < N_ ? row : N_ - 1;   // clamp padded rows (results discarded)
        rcv[c] = 1.f / fmaxf(counts[rowc], 1.f);
        asrc[c] = agg + (size_t)rowc * 256;
    }
    float4 R[2][2][2];

    auto loadA = [&](int buf, int k0) {
#pragma unroll
        for (int c = 0; c < 2; c++) {
            R[buf][c][0] = *(const float4*)(asrc[c] + k0 + koff);
            R[buf][c][1] = *(const float4*)(asrc[c] + k0 + koff + 4);
        }
    };
    auto stageB = [&](int buf, int k0) {
#pragma unroll
        for (int c = 0; c < 2; c++) {
            int ch = wave * 2 + c;
            const __hip_bfloat16* gp = WihB + (size_t)(col0 + ch * 16 + r_ld) * 256 + k0 + koff;
            short* lp = &Bs[buf][ch * 512];
            __builtin_amdgcn_global_load_lds(
                (const __attribute__((address_space(1))) unsigned int*)(uintptr_t)gp,
                (__attribute__((address_space(3))) unsigned int*)(uintptr_t)lp,
                16, 0, 0);
        }
    };
    auto writeA = [&](int buf, int k0) {
        float4 cb0 = *(const float4*)&conv_lds[k0 + koff];
        float4 cb1 = *(const float4*)&conv_lds[k0 + koff + 4];
#pragma unroll
        for (int c = 0; c < 2; c++) {
            int ch = wave * 2 + c;
            float rc = rcv[c];
            float4 a0 = R[buf][c][0], a1 = R[buf][c][1];
            bf16x8 v;
            v[0] = bfbits(fmaxf(a0.x * rc + cb0.x, 0.f));
            v[1] = bfbits(fmaxf(a0.y * rc + cb0.y, 0.f));
            v[2] = bfbits(fmaxf(a0.z * rc + cb0.z, 0.f));
            v[3] = bfbits(fmaxf(a0.w * rc + cb0.w, 0.f));
            v[4] = bfbits(fmaxf(a1.x * rc + cb1.x, 0.f));
            v[5] = bfbits(fmaxf(a1.y * rc + cb1.y, 0.f));
            v[6] = bfbits(fmaxf(a1.z * rc + cb1.z, 0.f));
            v[7] = bfbits(fmaxf(a1.w * rc + cb1.w, 0.f));
            *(bf16x8*)&As[buf][ch * 512 + lane * 8] = v;   // same slotting as gload_lds
        }
    };

    loadA(0, 0);
    stageB(0, 0);
#pragma unroll
    for (int kk = 0; kk < 8; kk++) {
        const int cur = kk & 1;
        if (kk + 1 < 8) {
            loadA(cur ^ 1, (kk + 1) * 32);
            stageB(cur ^ 1, (kk + 1) * 32);
        }
        writeA(cur, kk * 32);   // compiler auto-waits on R[cur]'s loads
        if (kk + 1 < 8) { asm volatile("s_waitcnt vmcnt(6)" ::: "memory"); }
        else            { asm volatile("s_waitcnt vmcnt(0)" ::: "memory"); }
        asm volatile("s_waitcnt lgkmcnt(0)" ::: "memory");
        __builtin_amdgcn_s_barrier();
        asm volatile("" ::: "memory");
        __builtin_amdgcn_sched_barrier(0);
        bf16x8 a[4], b[4];
#pragma unroll
        for (int i = 0; i < 4; i++)
            a[i] = *(const bf16x8*)&As[cur][(wm * 64 + i * 16 + l16) * 32 + ((quad ^ swz) << 3)];
#pragma unroll
        for (int j = 0; j < 4; j++)
            b[j] = *(const bf16x8*)&Bs[cur][(wn * 64 + j * 16 + l16) * 32 + ((quad ^ swz) << 3)];
#pragma unroll
        for (int i = 0; i < 4; i++)
#pragma unroll
            for (int j = 0; j < 4; j++)
                acc[i][j] = __builtin_amdgcn_mfma_f32_16x16x32_bf16(a[i], b[j], acc[i][j], 0, 0, 0);
        PIPE_EXIT()
    }

#pragma unroll
    for (int i = 0; i < 4; i++) {
        int gm0 = row0 + wm * 64 + i * 16 + quad * 4;
#pragma unroll
        for (int r = 0; r < 4; r++) {
            int gm = gm0 + r;
            if (gm < N_) {
#pragma unroll
                for (int j = 0; j < 4; j++) {
                    int col = col0 + wn * 64 + l16 + j * 16;
                    gi[(size_t)gm * NG_ + col] = acc[i][j][r] + bih[col];
                }
            }
        }
    }
}

// Tail GEMM with packed B (384x512): cols 0..255 -> relu->o1bf; cols 256..383 -> h1.
__global__ __launch_bounds__(256, 3) void k_gemm_tail(const __hip_bfloat16* __restrict__ A,
                                                      const __hip_bfloat16* __restrict__ Bpk,
                                                      const float* __restrict__ b1,
                                                      const float* __restrict__ b2,
                                                      __hip_bfloat16* __restrict__ o1bf,
                                                      float* __restrict__ h1) {
    __shared__ __align__(16) short As[2][4096];
    __shared__ __align__(16) short Bs[2][4096];
    int t = threadIdx.x;
    int lane = t & 63, wave = t >> 6;
    int wm = wave >> 1, wn = wave & 1;
    int quad = lane >> 4, l16 = lane & 15;
    int row0 = blockIdx.y * 128, col0 = blockIdx.x * 128;

    f32x4 acc[4][4] = {};
    int r_ld = (lane >> 2);
    int koff = (((lane & 3) ^ ((lane >> 3) & 3)) * 8);
    int swz = (l16 >> 1) & 3;

    auto stage = [&](int buf, int k0) {
#pragma unroll
        for (int c = 0; c < 4; c++) {
            int q = wave * 4 + c;
            int ch = q & 7;
            int r = ch * 16 + r_ld;
            const __hip_bfloat16* gp;
            short* lp;
            if (q < 8) { gp = A   + (size_t)(row0 + r) * 512 + k0 + koff; lp = &As[buf][ch * 512]; }
            else       { gp = Bpk + (size_t)(col0 + r) * 512 + k0 + koff; lp = &Bs[buf][ch * 512]; }
            __builtin_amdgcn_global_load_lds(
                (const __attribute__((address_space(1))) unsigned int*)(uintptr_t)gp,
                (__attribute__((address_space(3))) unsigned int*)(uintptr_t)lp,
                16, 0, 0);
        }
    };

    stage(0, 0);
    for (int kk = 0; kk < 16; kk++) {
        int cur = kk & 1;
        if (kk + 1 < 16) {
            stage(cur ^ 1, (kk + 1) * 32);
            PIPE_WAIT_ENTER(4)
        } else {
            PIPE_WAIT_ENTER(0)
        }
        bf16x8 a[4], b[4];
#pragma unroll
        for (int i = 0; i < 4; i++)
            a[i] = *(const bf16x8*)&As[cur][(wm * 64 + i * 16 + l16) * 32 + ((quad ^ swz) << 3)];
#pragma unroll
        for (int j = 0; j < 4; j++)
            b[j] = *(const bf16x8*)&Bs[cur][(wn * 64 + j * 16 + l16) * 32 + ((quad ^ swz) << 3)];
#pragma unroll
        for (int i = 0; i < 4; i++)
#pragma unroll
            for (int j = 0; j < 4; j++)
                acc[i][j] = __builtin_amdgcn_mfma_f32_16x16x32_bf16(a[i], b[j], acc[i][j], 0, 0, 0);
        PIPE_EXIT()
    }

#pragma unroll
    for (int i = 0; i < 4; i++) {
        int gm0 = row0 + wm * 64 + i * 16 + quad * 4;
#pragma unroll
        for (int r = 0; r < 4; r++) {
            int gm = gm0 + r;
#pragma unroll
            for (int j = 0; j < 4; j++) {
                int col = col0 + wn * 64 + l16 + j * 16;
                float v = acc[i][j][r];
                if (col < 256) {
                    v = fmaxf(v + b1[col], 0.f);
                    o1bf[(size_t)gm * H_ + col] = __float2bfloat16(v);
                } else {
                    h1[(size_t)gm * 128 + (col - 256)] = v + b2[col - 256];
                }
            }
        }
    }
}

// msg[e,o] = (he[e,:]/64).(fp8 V[row[e],o,:]) + outb[row[e],o]; atomicAdd into agg[col[e],o]
__global__ void k_msg(const int* __restrict__ ei, const float* __restrict__ he,
                      const unsigned char* __restrict__ V8, const float* __restrict__ outb,
                      float* __restrict__ agg) {
    int e = blockIdx.x, o = threadIdx.x;
    __shared__ float hs[KH_];
    if (o < KH_) hs[o] = he[e * KH_ + o] * VSCALE_INV;
    __syncthreads();
    int r = ei[e], c = ei[E_ + e];
    float acc = outb[(size_t)r * H_ + o];
    const unsigned char* vbase = V8 + (size_t)r * NV_ + o * 16;
#pragma unroll
    for (int q = 0; q < 8; q++) {       // 8 x 16B chunks, stride 4096
        uint4 u = *(const uint4*)(vbase + (size_t)q * 4096);
        const float* hp = hs + q * 16;
        f32x2 f;
        f = __builtin_amdgcn_cvt_pk_f32_fp8(u.x, false); acc += hp[0]  * f.x + hp[1]  * f.y;
        f = __builtin_amdgcn_cvt_pk_f32_fp8(u.x, true);  acc += hp[2]  * f.x + hp[3]  * f.y;
        f = __builtin_amdgcn_cvt_pk_f32_fp8(u.y, false); acc += hp[4]  * f.x + hp[5]  * f.y;
        f = __builtin_amdgcn_cvt_pk_f32_fp8(u.y, true);  acc += hp[6]  * f.x + hp[7]  * f.y;
        f = __builtin_amdgcn_cvt_pk_f32_fp8(u.z, false); acc += hp[8]  * f.x + hp[9]  * f.y;
        f = __builtin_amdgcn_cvt_pk_f32_fp8(u.z, true);  acc += hp[10] * f.x + hp[11] * f.y;
        f = __builtin_amdgcn_cvt_pk_f32_fp8(u.w, false); acc += hp[12] * f.x + hp[13] * f.y;
        f = __builtin_amdgcn_cvt_pk_f32_fp8(u.w, true);  acc += hp[14] * f.x + hp[15] * f.y;
    }
    atomicAdd(&agg[(size_t)c * H_ + o], acc);
}

// GRU pointwise; refreshes Abf = bf16(h); zeroes agg for the next iteration.
__global__ void k_gru_update(const float* __restrict__ gi, const float* __restrict__ gh,
                             float* __restrict__ h, __hip_bfloat16* __restrict__ Abf,
                             float* __restrict__ agg) {
    int i = blockIdx.x * blockDim.x + threadIdx.x;
    if (i >= N_ * H_) return;
    int n = i >> 8, j = i & 255;
    const float* gip = gi + (size_t)n * NG_;
    const float* ghp = gh + (size_t)n * NG_;
    float r = 1.f / (1.f + expf(-(gip[j] + ghp[j])));
    float z = 1.f / (1.f + expf(-(gip[H_ + j] + ghp[H_ + j])));
    float nn = tanhf(gip[2 * H_ + j] + r * ghp[2 * H_ + j]);
    float hv = (1.f - z) * nn + z * h[i];
    h[i] = hv;
    Abf[i] = __float2bfloat16(hv);
    agg[i] = 0.f;
}

// batchnorm stats over E rows, per column j   grid 128, block 256
__global__ void k_bnstats(const float* __restrict__ h1, float* __restrict__ mu,
                          float* __restrict__ rsig) {
    int j = blockIdx.x, t = threadIdx.x;
    float s = 0.f, ss = 0.f;
    for (int e = t; e < E_; e += 256) {
        float v = h1[(size_t)e * 128 + j];
        s += v;
        ss += v * v;
    }
    __shared__ float rs[256], rss[256];
    rs[t] = s; rss[t] = ss;
    __syncthreads();
    for (int off = 128; off > 0; off >>= 1) {
        if (t < off) { rs[t] += rs[t + off]; rss[t] += rss[t + off]; }
        __syncthreads();
    }
    if (t == 0) {
        float m_ = rs[0] / E_;
        float v_ = rss[0] / E_ - m_ * m_;
        mu[j] = m_;
        rsig[j] = rsqrtf(v_ + 1e-5f);
    }
}

// precs[e] = relu(bn(h1[e])) . l6_W2 + b
__global__ void k_precs(const float* __restrict__ h1, const float* __restrict__ mu,
                        const float* __restrict__ rsig, const float* __restrict__ g,
                        const float* __restrict__ bb, const float* __restrict__ W2,
                        const float* __restrict__ b2, float* __restrict__ out) {
    int e = blockIdx.x * blockDim.x + threadIdx.x;
    if (e >= E_) return;
    float acc = b2[0];
#pragma unroll 4
    for (int j = 0; j < 128; j++) {
        float v = (h1[(size_t)e * 128 + j] - mu[j]) * rsig[j] * g[j] + bb[j];
        acc += fmaxf(v, 0.f) * W2[j];
    }
    out[(size_t)E_ * 242 + e] = acc;
}

extern "C" void kernel_launch(void* const* d_in, const int* in_sizes, int n_in,
                              void* d_out, int out_size, void* d_ws, size_t ws_size,
                              hipStream_t stream) {
    const int*   x        = (const int*)  d_in[0];
    const float* pos      = (const float*)d_in[1];
    const int*   ei       = (const int*)  d_in[2];
    const float* edge_atr = (const float*)d_in[3];
    const float* emb      = (const float*)d_in[4];
    const float* lin0_W   = (const float*)d_in[5];
    const float* lin0_b   = (const float*)d_in[6];
    const float* mlp1_W   = (const float*)d_in[7];
    const float* mlp1_b   = (const float*)d_in[8];
    const float* mlp2_W   = (const float*)d_in[9];
    const float* mlp2_b   = (const float*)d_in[10];
    const float* conv_b   = (const float*)d_in[11];
    const float* gru_Wih  = (const float*)d_in[12];
    const float* gru_Whh  = (const float*)d_in[13];
    const float* gru_bih  = (const float*)d_in[14];
    const float* gru_bhh  = (const float*)d_in[15];
    const float* lin1_W   = (const float*)d_in[16];
    const float* lin1_b   = (const float*)d_in[17];
    const float* lin2_W   = (const float*)d_in[18];
    const float* lin2_b   = (const float*)d_in[19];
    const float* l6_W1    = (const float*)d_in[20];
    const float* l6_b1    = (const float*)d_in[21];
    const float* bn_g     = (const float*)d_in[22];
    const float* bn_b     = (const float*)d_in[23];
    const float* l6_W2    = (const float*)d_in[24];
    const float* l6_b2    = (const float*)d_in[25];
    float* out = (float*)d_out;

    // workspace layout
    char* w = (char*)d_ws;
    size_t off = 0;
    auto alloc = [&](size_t bytes) -> void* {
        void* p = w + off;
        off = (off + bytes + 255) & ~(size_t)255;
        return p;
    };
    float* hbuf   = (float*)alloc((size_t)N_ * H_ * 4);
    float* aggm   = (float*)alloc((size_t)N_ * H_ * 4);
    float* outb   = (float*)alloc((size_t)N_ * H_ * 4);
    float* he     = (float*)alloc((size_t)E_ * KH_ * 4);
    float* gi     = (float*)alloc((size_t)N_ * NG_ * 4);
    float* gh     = (float*)alloc((size_t)N_ * NG_ * 4);
    float* h1     = (float*)alloc((size_t)E_ * 128 * 4);
    float* counts = (float*)alloc((size_t)N_ * 4);
    float* mu     = (float*)alloc(128 * 4);
    float* rsig   = (float*)alloc(128 * 4);
    unsigned char* V8      = (unsigned char*)alloc((size_t)N_ * NV_);          // 65.5 MB fp8
    __hip_bfloat16* Abf    = (__hip_bfloat16*)alloc((size_t)MPAD_ * H_ * 2);
    __hip_bfloat16* Bt     = (__hip_bfloat16*)alloc((size_t)NV_ * H_ * 2);     // 16.8 MB
    __hip_bfloat16* WihB   = (__hip_bfloat16*)alloc((size_t)NG_ * H_ * 2);
    __hip_bfloat16* WhhB   = (__hip_bfloat16*)alloc((size_t)NG_ * H_ * 2);
    __hip_bfloat16* Bpk    = (__hip_bfloat16*)alloc((size_t)384 * 512 * 2);
    __hip_bfloat16* lin2Wb = (__hip_bfloat16*)alloc((size_t)H_ * H_ * 2);
    __hip_bfloat16* BtB    = (__hip_bfloat16*)alloc((size_t)H_ * H_ * 2);
    __hip_bfloat16* Cbf    = (__hip_bfloat16*)alloc((size_t)E_ * 2 * H_ * 2);
    __hip_bfloat16* o1bf   = (__hip_bfloat16*)alloc((size_t)E_ * H_ * 2);

    k_lin0<<<MPAD_, 256, 0, stream>>>(x, pos, emb, lin0_W, lin0_b, hbuf, Abf);
    k_he<<<E_, 128, 0, stream>>>(edge_atr, mlp1_W, mlp1_b, he);
    hipMemsetAsync(counts, 0, (size_t)N_ * 4, stream);
    hipMemsetAsync(aggm, 0, (size_t)N_ * H_ * 4, stream);
    k_counts<<<(E_ + 255) / 256, 256, 0, stream>>>(ei, counts);
    k_trans_bt<<<dim3(NV_ / 64, H_ / 32), 256, 0, stream>>>(mlp2_W, Bt);
    k_prep_w<<<768, 256, 0, stream>>>(gru_Wih, gru_Whh, lin1_W, l6_W1, lin2_W, mlp2_b,
                                      WihB, WhhB, Bpk, lin2Wb, BtB);

    for (int it = 0; it < 3; it++) {
        // fused: gh = Abf@Whh^T + bhh, outb = Abf@BtB^T, V8 = fp8(Abf@Bt^T)
        k_gemm_VP<<<128 + (NV_ / 128) * (MPAD_ / 128), 256, 0, stream>>>(
            Abf, Bt, WhhB, BtB, gru_bhh, gh, outb, V8);
        k_msg<<<E_, 256, 0, stream>>>(ei, he, V8, outb, aggm);
        // gi = relu(agg/c + conv_b) @ Wih^T + bih   (m-transform fused, balanced waves)
        k_gemm_gi<<<dim3(6, MPAD_ / 128), 256, 0, stream>>>(
            aggm, counts, conv_b, WihB, gru_bih, gi);
        k_gru_update<<<(N_ * H_ + 255) / 256, 256, 0, stream>>>(gi, gh, hbuf, Abf, aggm);
    }

    k_concat<<<E_, 256, 0, stream>>>(ei, hbuf, Cbf);
    k_gemm_tail<<<dim3(3, E_ / 128), 256, 0, stream>>>(Cbf, Bpk, lin1_b, l6_b1, o1bf, h1);
    k_gemm_nt<256, false, false><<<dim3(2, E_ / 128), 256, 0, stream>>>(
        o1bf, lin2Wb, out, nullptr, lin2_b, 242, 242, E_);
    k_bnstats<<<128, 256, 0, stream>>>(h1, mu, rsig);
    k_precs<<<(E_ + 255) / 256, 256, 0, stream>>>(h1, mu, rsig, bn_g, bn_b, l6_W2, l6_b2, out);
}

// Round 9
// 422.432 us; speedup vs baseline: 1.1702x; 1.0573x over previous
//
#include <hip/hip_runtime.h>
#include <hip/hip_bf16.h>

// Problem constants (fixed by the reference)
constexpr int N_ = 2000;   // nodes
constexpr int E_ = 4096;   // edges
constexpr int H_ = 256;    // hidden
constexpr int KH_ = 128;   // he dim (mlp1 out)
constexpr int NV_ = H_ * KH_; // 32768, V row length — fp8 bytes
constexpr int MPAD_ = 2048;   // padded M for node-side MFMA GEMMs
constexpr int NG_ = 768;      // GRU gate width (3*H)
constexpr float VSCALE = 64.f;     // fp8 scale for V (avoids e4m3 subnormals)
constexpr float VSCALE_INV = 1.f / 64.f;

typedef short bf16x8 __attribute__((ext_vector_type(8)));
typedef float f32x4  __attribute__((ext_vector_type(4)));
typedef float f32x2  __attribute__((ext_vector_type(2)));

__device__ __forceinline__ float bf_lo(unsigned u) { return __uint_as_float(u << 16); }
__device__ __forceinline__ float bf_hi(unsigned u) { return __uint_as_float(u & 0xffff0000u); }
__device__ __forceinline__ short bfbits(float f) {
    __hip_bfloat16 b = __float2bfloat16(f);
    return *(short*)&b;
}

// ---- pipeline sync helpers (T4: counted vmcnt across raw barrier), depth-2 ----
#define PIPE_WAIT_ENTER(N_OUTST)                                   \
    asm volatile("s_waitcnt vmcnt(" #N_OUTST ")" ::: "memory");    \
    __builtin_amdgcn_s_barrier();                                  \
    asm volatile("" ::: "memory");                                 \
    __builtin_amdgcn_sched_barrier(0);

#define PIPE_EXIT()                                                \
    __builtin_amdgcn_sched_barrier(0);                             \
    asm volatile("" ::: "memory");                                 \
    __builtin_amdgcn_s_barrier();

// out = relu([emb[x], pos] @ lin0_W.T + b); emits Abf (bf16, zero-padded rows).
// Also zero-inits counts/deg/wcur/aggm (replaces memsets).
__global__ void k_lin0(const int* __restrict__ x, const float* __restrict__ pos,
                       const float* __restrict__ emb, const float* __restrict__ W,
                       const float* __restrict__ b, float* __restrict__ out,
                       __hip_bfloat16* __restrict__ Abf,
                       float* __restrict__ counts, float* __restrict__ aggm,
                       int* __restrict__ deg, int* __restrict__ wcur) {
    int n = blockIdx.x, t = threadIdx.x;
    if (n >= N_) { Abf[(size_t)n * H_ + t] = __float2bfloat16(0.f); return; }
    if (t == 0) counts[n] = 0.f;
    if (t == 1) deg[n] = 0;
    if (t == 2) wcur[n] = 0;
    aggm[(size_t)n * H_ + t] = 0.f;
    __shared__ float in_p[8];
    if (t < 5) in_p[t] = emb[x[n] * 5 + t];
    else if (t < 8) in_p[t] = pos[n * 3 + (t - 5)];
    __syncthreads();
    float acc = b[t];
#pragma unroll
    for (int i = 0; i < 8; i++) acc += in_p[i] * W[t * 8 + i];
    float v = fmaxf(acc, 0.f);
    out[n * H_ + t] = v;
    Abf[(size_t)n * H_ + t] = __float2bfloat16(v);
}

// he = relu(edge_atr @ mlp1_W.T + b); also tallies col in-degree + row out-degree.
// grid E, block 128
__global__ void k_he(const float* __restrict__ ea, const float* __restrict__ W,
                     const float* __restrict__ b, float* __restrict__ he,
                     const int* __restrict__ ei, float* __restrict__ counts,
                     int* __restrict__ deg) {
    int e = blockIdx.x, t = threadIdx.x;
    __shared__ float a[5];
    if (t < 5) a[t] = ea[e * 5 + t];
    if (t == 8) atomicAdd(&counts[ei[E_ + e]], 1.0f);
    if (t == 9) atomicAdd(&deg[ei[e]], 1);
    __syncthreads();
    float acc = b[t];
#pragma unroll
    for (int i = 0; i < 5; i++) acc += a[i] * W[t * 5 + i];
    he[e * KH_ + t] = fmaxf(acc, 0.f);
}

// exclusive prefix over deg[0..N_-1] -> rowptr[0..N_]   (1 block, 256 threads)
__global__ void k_scan(const int* __restrict__ deg, int* __restrict__ rowptr) {
    __shared__ int ws[256];
    int t = threadIdx.x;
    int base = t * 8;
    int loc[8];
    int s = 0;
#pragma unroll
    for (int j = 0; j < 8; j++) {
        int idx = base + j;
        int d = (idx < N_) ? deg[idx] : 0;
        loc[j] = s;
        s += d;
    }
    ws[t] = s;
    __syncthreads();
    for (int off2 = 1; off2 < 256; off2 <<= 1) {
        int v = (t >= off2) ? ws[t - off2] : 0;
        __syncthreads();
        ws[t] += v;
        __syncthreads();
    }
    int excl = ws[t] - s;
#pragma unroll
    for (int j = 0; j < 8; j++) {
        int idx = base + j;
        if (idx <= N_) rowptr[idx] = excl + loc[j];
    }
}

// scatter edge ids into row-sorted order
__global__ void k_fill(const int* __restrict__ ei, const int* __restrict__ rowptr,
                       int* __restrict__ wcur, int* __restrict__ eord) {
    int e = blockIdx.x * blockDim.x + threadIdx.x;
    if (e < E_) {
        int r = ei[e];
        int p = atomicAdd(&wcur[r], 1);
        eord[rowptr[r] + p] = e;
    }
}

// Bt[nv][h] = mlp2_W[h*32768 + nv] as bf16 (transpose+convert), once per launch.
__global__ void k_trans_bt(const float* __restrict__ W, __hip_bfloat16* __restrict__ Bt) {
    __shared__ float tile[32][68];   // 68: 16B-aligned rows, bank-shifted
    int t = threadIdx.x;
    int n0 = blockIdx.x * 64, k0 = blockIdx.y * 32;
#pragma unroll
    for (int i = 0; i < 2; i++) {
        int idx = t + i * 256;                 // 0..511
        int kk = idx >> 4, nn = (idx & 15) * 4;
        float4 f = *(const float4*)&W[(size_t)(k0 + kk) * NV_ + n0 + nn];
        *(float4*)&tile[kk][nn] = f;
    }
    __syncthreads();
#pragma unroll
    for (int i = 0; i < 2; i++) {
        int idx = t + i * 256;                 // 0..511
        int nn = idx >> 3, k4 = (idx & 7) * 4;
        short4 s;
        s.x = bfbits(tile[k4 + 0][nn]);
        s.y = bfbits(tile[k4 + 1][nn]);
        s.z = bfbits(tile[k4 + 2][nn]);
        s.w = bfbits(tile[k4 + 3][nn]);
        *(short4*)&Bt[(size_t)(n0 + nn) * H_ + k0 + k4] = s;
    }
}

// One-time weight preps (bf16 converts + packed tail B + lin2 pad + mlp2_b transpose).
__global__ void k_prep_w(const float* __restrict__ Wih, const float* __restrict__ Whh,
                         const float* __restrict__ lin1W, const float* __restrict__ l6W1,
                         const float* __restrict__ lin2W, const float* __restrict__ b2,
                         __hip_bfloat16* __restrict__ WihB, __hip_bfloat16* __restrict__ WhhB,
                         __hip_bfloat16* __restrict__ Bpk,
                         __hip_bfloat16* __restrict__ lin2Wb, __hip_bfloat16* __restrict__ BtB) {
    int i = blockIdx.x * 256 + threadIdx.x;     // i < 196608
    if (i < NG_ * H_) {
        WihB[i] = __float2bfloat16(Wih[i]);
        WhhB[i] = __float2bfloat16(Whh[i]);
    }
    Bpk[i] = __float2bfloat16(i < 256 * 512 ? lin1W[i] : l6W1[i - 256 * 512]);
    if (i < 128 * 2 * H_) {
        int r = i >> 8, k = i & 255;
        lin2Wb[i] = __float2bfloat16(r < 242 ? lin2W[r * H_ + k] : 0.f);
        int o = i >> 8, h = i & 255;
        BtB[o * H_ + h] = __float2bfloat16(b2[h * H_ + o]);
    }
}

// Cbf[e] = bf16([h[row[e]], h[col[e]]]); block 0 zero-inits bnsum.  grid E, block 256
__global__ void k_concat(const int* __restrict__ ei, const float* __restrict__ h,
                         __hip_bfloat16* __restrict__ Cbf, float* __restrict__ bnsum) {
    int e = blockIdx.x, t = threadIdx.x;
    if (e == 0) bnsum[t] = 0.f;
    int r = ei[e], c = ei[E_ + e];
    Cbf[(size_t)e * 512 + t]       = __float2bfloat16(h[(size_t)r * H_ + t]);
    Cbf[(size_t)e * 512 + 256 + t] = __float2bfloat16(h[(size_t)c * H_ + t]);
}

// Generic MFMA GEMM: C(MxN) = A(MxKD bf16) @ Bt(NxKD bf16)^T [+bias][relu].
// Depth-2 pipeline (counted vmcnt(4) across raw barrier).
template <int KD, bool RELU, bool OUT_BF16>
__global__ __launch_bounds__(256, 3) void k_gemm_nt(const __hip_bfloat16* __restrict__ A,
                                                    const __hip_bfloat16* __restrict__ Bt,
                                                    float* __restrict__ Cf,
                                                    __hip_bfloat16* __restrict__ Cb,
                                                    const float* __restrict__ bias,
                                                    int ldc, int ncols, int mvalid) {
    __shared__ __align__(16) short As[2][4096];
    __shared__ __align__(16) short Bs[2][4096];
    int t = threadIdx.x;
    int lane = t & 63, wave = t >> 6;
    int wm = wave >> 1, wn = wave & 1;
    int quad = lane >> 4, l16 = lane & 15;
    int row0 = blockIdx.y * 128, col0 = blockIdx.x * 128;

    f32x4 acc[4][4] = {};
    int r_ld = (lane >> 2);
    int koff = (((lane & 3) ^ ((lane >> 3) & 3)) * 8);  // swizzled 16B slot
    int swz = (l16 >> 1) & 3;                           // read-side slot XOR
    constexpr int NST = KD / 32;

    auto stage = [&](int buf, int k0) {
#pragma unroll
        for (int c = 0; c < 4; c++) {
            int q = wave * 4 + c;
            int ch = q & 7;
            int r = ch * 16 + r_ld;
            const __hip_bfloat16* gp;
            short* lp;
            if (q < 8) { gp = A  + (size_t)(row0 + r) * KD + k0 + koff; lp = &As[buf][ch * 512]; }
            else       { gp = Bt + (size_t)(col0 + r) * KD + k0 + koff; lp = &Bs[buf][ch * 512]; }
            __builtin_amdgcn_global_load_lds(
                (const __attribute__((address_space(1))) unsigned int*)(uintptr_t)gp,
                (__attribute__((address_space(3))) unsigned int*)(uintptr_t)lp,
                16, 0, 0);
        }
    };

    stage(0, 0);
    for (int kk = 0; kk < NST; kk++) {
        int cur = kk & 1;
        if (kk + 1 < NST) {
            stage(cur ^ 1, (kk + 1) * 32);
            PIPE_WAIT_ENTER(4)
        } else {
            PIPE_WAIT_ENTER(0)
        }
        bf16x8 a[4], b[4];
#pragma unroll
        for (int i = 0; i < 4; i++)
            a[i] = *(const bf16x8*)&As[cur][(wm * 64 + i * 16 + l16) * 32 + ((quad ^ swz) << 3)];
#pragma unroll
        for (int j = 0; j < 4; j++)
            b[j] = *(const bf16x8*)&Bs[cur][(wn * 64 + j * 16 + l16) * 32 + ((quad ^ swz) << 3)];
#pragma unroll
        for (int i = 0; i < 4; i++)
#pragma unroll
            for (int j = 0; j < 4; j++)
                acc[i][j] = __builtin_amdgcn_mfma_f32_16x16x32_bf16(a[i], b[j], acc[i][j], 0, 0, 0);
        PIPE_EXIT()
    }

#pragma unroll
    for (int i = 0; i < 4; i++) {
        int gm0 = row0 + wm * 64 + i * 16 + quad * 4;
#pragma unroll
        for (int r = 0; r < 4; r++) {
            int gm = gm0 + r;
            if (gm < mvalid) {
#pragma unroll
                for (int j = 0; j < 4; j++) {
                    int col = col0 + wn * 64 + l16 + j * 16;
                    if (col < ncols) {
                        float v = acc[i][j][r];
                        if (bias) v += bias[col];
                        if (RELU) v = fmaxf(v, 0.f);
                        if (OUT_BF16) Cb[(size_t)gm * ldc + col] = __float2bfloat16(v);
                        else          Cf[(size_t)gm * ldc + col] = v;
                    }
                }
            }
        }
    }
}

// Fused per-iteration GEMM launch (one grid, block-uniform branch):
//   blocks [0,128):    pair part — gh / outb from Abf
//   blocks [128,4224): V part — V8 = fp8(Abf @ Bt^T), permuted layout
__global__ __launch_bounds__(256, 4) void k_gemm_VP(const __hip_bfloat16* __restrict__ Abf,
                                                    const __hip_bfloat16* __restrict__ Bt,
                                                    const __hip_bfloat16* __restrict__ WhhB,
                                                    const __hip_bfloat16* __restrict__ BtB,
                                                    const float* __restrict__ bhh,
                                                    float* __restrict__ gh,
                                                    float* __restrict__ outb,
                                                    unsigned char* __restrict__ V8) {
    __shared__ __align__(16) short As[2][4096];
    __shared__ __align__(16) short Bs[2][4096];
    int bid = blockIdx.x;
    int t = threadIdx.x;
    int lane = t & 63, wave = t >> 6;
    int wm = wave >> 1, wn = wave & 1;
    int quad = lane >> 4, l16 = lane & 15;
    int r_ld = (lane >> 2);
    int koff = (((lane & 3) ^ ((lane >> 3) & 3)) * 8);
    int swz = (l16 >> 1) & 3;

    if (bid < 128) {
        // ---------------- pair part ----------------
        int pbx = bid & 7, pby = bid >> 3;
        bool ob = (pbx >= 6);
        const __hip_bfloat16* Bp = ob ? BtB : WhhB;
        int col0 = ob ? (pbx - 6) * 128 : pbx * 128;
        int ldc = ob ? H_ : NG_;
        float* C = ob ? outb : gh;
        int row0 = pby * 128;

        f32x4 acc[4][4] = {};
        auto stage = [&](int buf, int k0) {
#pragma unroll
            for (int c = 0; c < 4; c++) {
                int q = wave * 4 + c;
                int ch = q & 7;
                int r = ch * 16 + r_ld;
                const __hip_bfloat16* gp;
                short* lp;
                if (q < 8) { gp = Abf + ((size_t)(row0 + r) << 8) + k0 + koff; lp = &As[buf][ch * 512]; }
                else       { gp = Bp  + ((size_t)(col0 + r) << 8) + k0 + koff; lp = &Bs[buf][ch * 512]; }
                __builtin_amdgcn_global_load_lds(
                    (const __attribute__((address_space(1))) unsigned int*)(uintptr_t)gp,
                    (__attribute__((address_space(3))) unsigned int*)(uintptr_t)lp,
                    16, 0, 0);
            }
        };
        stage(0, 0);
        for (int kk = 0; kk < 8; kk++) {
            int cur = kk & 1;
            if (kk + 1 < 8) {
                stage(cur ^ 1, (kk + 1) * 32);
                PIPE_WAIT_ENTER(4)
            } else {
                PIPE_WAIT_ENTER(0)
            }
            bf16x8 a[4], b[4];
#pragma unroll
            for (int i = 0; i < 4; i++)
                a[i] = *(const bf16x8*)&As[cur][(wm * 64 + i * 16 + l16) * 32 + ((quad ^ swz) << 3)];
#pragma unroll
            for (int j = 0; j < 4; j++)
                b[j] = *(const bf16x8*)&Bs[cur][(wn * 64 + j * 16 + l16) * 32 + ((quad ^ swz) << 3)];
#pragma unroll
            for (int i = 0; i < 4; i++)
#pragma unroll
                for (int j = 0; j < 4; j++)
                    acc[i][j] = __builtin_amdgcn_mfma_f32_16x16x32_bf16(a[i], b[j], acc[i][j], 0, 0, 0);
            PIPE_EXIT()
        }
#pragma unroll
        for (int i = 0; i < 4; i++) {
            int gm0 = row0 + wm * 64 + i * 16 + quad * 4;
#pragma unroll
            for (int r = 0; r < 4; r++) {
                int gm = gm0 + r;
                if (gm < N_) {
#pragma unroll
                    for (int j = 0; j < 4; j++) {
                        int col = col0 + wn * 64 + l16 + j * 16;
                        float v = acc[i][j][r] + (ob ? 0.f : bhh[col]);
                        C[(size_t)gm * ldc + col] = v;
                    }
                }
            }
        }
        return;
    }

    // ---------------- V part ----------------
    int vb = bid - 128;
    int bx = vb & 255, by = vb >> 8;
    int row0 = by * 128, col0 = bx * 128;
    int obase = bx * 8;                    // o = (obase+ch)&255
    int kb = (bx >> 5) * 16;               // k16*16
    short* Ps = &As[0][0];                 // epilogue alias: 32 x 136 shorts

    f32x4 acc[4][4] = {};
    auto stage = [&](int buf, int k0) {
#pragma unroll
        for (int c = 0; c < 4; c++) {
            int q = wave * 4 + c;
            int ch = q & 7;
            const __hip_bfloat16* gp;
            short* lp;
            if (q < 8) {
                gp = Abf + ((size_t)(row0 + ch * 16 + r_ld) << 8) + k0 + koff;
                lp = &As[buf][ch * 512];
            } else {
                int nv = ((obase + ch) & 255) * 128 + kb + r_ld;   // f -> nv remap
                gp = Bt + ((size_t)nv << 8) + k0 + koff;
                lp = &Bs[buf][ch * 512];
            }
            __builtin_amdgcn_global_load_lds(
                (const __attribute__((address_space(1))) unsigned int*)(uintptr_t)gp,
                (__attribute__((address_space(3))) unsigned int*)(uintptr_t)lp,
                16, 0, 0);
        }
    };
    stage(0, 0);
    for (int kk = 0; kk < 8; kk++) {
        int cur = kk & 1;
        if (kk + 1 < 8) {
            stage(cur ^ 1, (kk + 1) * 32);
            PIPE_WAIT_ENTER(4)
        } else {
            PIPE_WAIT_ENTER(0)
        }
        bf16x8 a[4], b[4];
#pragma unroll
        for (int i = 0; i < 4; i++)
            a[i] = *(const bf16x8*)&As[cur][(wm * 64 + i * 16 + l16) * 32 + ((quad ^ swz) << 3)];
#pragma unroll
        for (int j = 0; j < 4; j++)
            b[j] = *(const bf16x8*)&Bs[cur][(wn * 64 + j * 16 + l16) * 32 + ((quad ^ swz) << 3)];
#pragma unroll
        for (int i = 0; i < 4; i++)
#pragma unroll
            for (int j = 0; j < 4; j++)
                acc[i][j] = __builtin_amdgcn_mfma_f32_16x16x32_bf16(a[i], b[j], acc[i][j], 0, 0, 0);
        PIPE_EXIT()
    }

    // 4-pass epilogue: stage 32 scaled-bf16 rows in Ps, convert+store coalesced uint4.
#pragma unroll
    for (int pp = 0; pp < 4; pp++) {
        if (wm == (pp >> 1)) {
#pragma unroll
            for (int ii = 0; ii < 2; ii++) {
                const int i = (pp & 1) * 2 + ii;       // compile-time acc index
                int lr = ii * 16 + quad * 4;           // local row in [0,32)
#pragma unroll
                for (int r = 0; r < 4; r++) {
#pragma unroll
                    for (int j = 0; j < 4; j++) {
                        int col = wn * 64 + j * 16 + l16;
                        Ps[(lr + r) * 136 + col] = bfbits(acc[i][j][r] * VSCALE);
                    }
                }
            }
        }
        __syncthreads();
        {
            int row = t >> 3;            // 0..31
            int col = (t & 7) * 16;      // 0..112 step 16
            int gm = row0 + pp * 32 + row;
            if (gm < N_) {
                uint4 ua = *(const uint4*)&Ps[row * 136 + col];
                uint4 ub = *(const uint4*)&Ps[row * 136 + col + 8];
                unsigned p0 = __builtin_amdgcn_cvt_pk_fp8_f32(bf_lo(ua.x), bf_hi(ua.x), 0, false);
                p0 = __builtin_amdgcn_cvt_pk_fp8_f32(bf_lo(ua.y), bf_hi(ua.y), p0, true);
                unsigned p1 = __builtin_amdgcn_cvt_pk_fp8_f32(bf_lo(ua.z), bf_hi(ua.z), 0, false);
                p1 = __builtin_amdgcn_cvt_pk_fp8_f32(bf_lo(ua.w), bf_hi(ua.w), p1, true);
                unsigned p2 = __builtin_amdgcn_cvt_pk_fp8_f32(bf_lo(ub.x), bf_hi(ub.x), 0, false);
                p2 = __builtin_amdgcn_cvt_pk_fp8_f32(bf_lo(ub.y), bf_hi(ub.y), p2, true);
                unsigned p3 = __builtin_amdgcn_cvt_pk_fp8_f32(bf_lo(ub.z), bf_hi(ub.z), 0, false);
                p3 = __builtin_amdgcn_cvt_pk_fp8_f32(bf_lo(ub.w), bf_hi(ub.w), p3, true);
                uint4 o4;
                o4.x = p0; o4.y = p1; o4.z = p2; o4.w = p3;
                *(uint4*)(V8 + (size_t)gm * NV_ + col0 + col) = o4;
            }
        }
        __syncthreads();
    }
}

// gi = relu(agg/c + conv_b) @ Wih^T + bih, m-transform fused into A-staging.
// BALANCED roles: every wave stages 2 A-channels and 2 B-channels.
__global__ __launch_bounds__(256, 3) void k_gemm_gi(const float* __restrict__ agg,
                                                    const float* __restrict__ counts,
                                                    const float* __restrict__ conv_b,
                                                    const __hip_bfloat16* __restrict__ WihB,
                                                    const float* __restrict__ bih,
                                                    float* __restrict__ gi) {
    __shared__ __align__(16) short As[2][4096];
    __shared__ __align__(16) short Bs[2][4096];
    __shared__ __align__(16) float conv_lds[256];
    int t = threadIdx.x;
    int lane = t & 63, wave = t >> 6;
    int wm = wave >> 1, wn = wave & 1;
    int quad = lane >> 4, l16 = lane & 15;
    int row0 = blockIdx.y * 128, col0 = blockIdx.x * 128;
    int r_ld = (lane >> 2);
    int koff = (((lane & 3) ^ ((lane >> 3) & 3)) * 8);
    int swz = (l16 >> 1) & 3;

    conv_lds[t] = conv_b[t];
    __syncthreads();

    f32x4 acc[4][4] = {};
    float rcv[2];
    const float* asrc[2];
#pragma unroll
    for (int c = 0; c < 2; c++) {
        int ch = wave * 2 + c;
        int row = row0 + ch * 16 + r_ld;
        int rowc = row < N_ ? row : N_ - 1;   // clamp padded rows (results discarded)
        rcv[c] = 1.f / fmaxf(counts[rowc], 1.f);
        asrc[c] = agg + (size_t)rowc * 256;
    }
    float4 R[2][2][2];

    auto loadA = [&](int buf, int k0) {
#pragma unroll
        for (int c = 0; c < 2; c++) {
            R[buf][c][0] = *(const float4*)(asrc[c] + k0 + koff);
            R[buf][c][1] = *(const float4*)(asrc[c] + k0 + koff + 4);
        }
    };
    auto stageB = [&](int buf, int k0) {
#pragma unroll
        for (int c = 0; c < 2; c++) {
            int ch = wave * 2 + c;
            const __hip_bfloat16* gp = WihB + (size_t)(col0 + ch * 16 + r_ld) * 256 + k0 + koff;
            short* lp = &Bs[buf][ch * 512];
            __builtin_amdgcn_global_load_lds(
                (const __attribute__((address_space(1))) unsigned int*)(uintptr_t)gp,
                (__attribute__((address_space(3))) unsigned int*)(uintptr_t)lp,
                16, 0, 0);
        }
    };
    auto writeA = [&](int buf, int k0) {
        float4 cb0 = *(const float4*)&conv_lds[k0 + koff];
        float4 cb1 = *(const float4*)&conv_lds[k0 + koff + 4];
#pragma unroll
        for (int c = 0; c < 2; c++) {
            int ch = wave * 2 + c;
            float rc = rcv[c];
            float4 a0 = R[buf][c][0], a1 = R[buf][c][1];
            bf16x8 v;
            v[0] = bfbits(fmaxf(a0.x * rc + cb0.x, 0.f));
            v[1] = bfbits(fmaxf(a0.y * rc + cb0.y, 0.f));
            v[2] = bfbits(fmaxf(a0.z * rc + cb0.z, 0.f));
            v[3] = bfbits(fmaxf(a0.w * rc + cb0.w, 0.f));
            v[4] = bfbits(fmaxf(a1.x * rc + cb1.x, 0.f));
            v[5] = bfbits(fmaxf(a1.y * rc + cb1.y, 0.f));
            v[6] = bfbits(fmaxf(a1.z * rc + cb1.z, 0.f));
            v[7] = bfbits(fmaxf(a1.w * rc + cb1.w, 0.f));
            *(bf16x8*)&As[buf][ch * 512 + lane * 8] = v;   // same slotting as gload_lds
        }
    };

    loadA(0, 0);
    stageB(0, 0);
#pragma unroll
    for (int kk = 0; kk < 8; kk++) {
        const int cur = kk & 1;
        if (kk + 1 < 8) {
            loadA(cur ^ 1, (kk + 1) * 32);
            stageB(cur ^ 1, (kk + 1) * 32);
        }
        writeA(cur, kk * 32);   // compiler auto-waits on R[cur]'s loads
        if (kk + 1 < 8) { asm volatile("s_waitcnt vmcnt(6)" ::: "memory"); }
        else            { asm volatile("s_waitcnt vmcnt(0)" ::: "memory"); }
        asm volatile("s_waitcnt lgkmcnt(0)" ::: "memory");
        __builtin_amdgcn_s_barrier();
        asm volatile("" ::: "memory");
        __builtin_amdgcn_sched_barrier(0);
        bf16x8 a[4], b[4];
#pragma unroll
        for (int i = 0; i < 4; i++)
            a[i] = *(const bf16x8*)&As[cur][(wm * 64 + i * 16 + l16) * 32 + ((quad ^ swz) << 3)];
#pragma unroll
        for (int j = 0; j < 4; j++)
            b[j] = *(const bf16x8*)&Bs[cur][(wn * 64 + j * 16 + l16) * 32 + ((quad ^ swz) << 3)];
#pragma unroll
        for (int i = 0; i < 4; i++)
#pragma unroll
            for (int j = 0; j < 4; j++)
                acc[i][j] = __builtin_amdgcn_mfma_f32_16x16x32_bf16(a[i], b[j], acc[i][j], 0, 0, 0);
        PIPE_EXIT()
    }

#pragma unroll
    for (int i = 0; i < 4; i++) {
        int gm0 = row0 + wm * 64 + i * 16 + quad * 4;
#pragma unroll
        for (int r = 0; r < 4; r++) {
            int gm = gm0 + r;
            if (gm < N_) {
#pragma unroll
                for (int j = 0; j < 4; j++) {
                    int col = col0 + wn * 64 + l16 + j * 16;
                    gi[(size_t)gm * NG_ + col] = acc[i][j][r] + bih[col];
                }
            }
        }
    }
}

// Tail GEMM with packed B (384x512): cols 0..255 -> relu->o1bf; cols 256..383 -> h1.
// Block x==2 additionally emits BN column partial sums (shfl-reduced, 2 atomics/col/wave).
__global__ __launch_bounds__(256, 3) void k_gemm_tail(const __hip_bfloat16* __restrict__ A,
                                                      const __hip_bfloat16* __restrict__ Bpk,
                                                      const float* __restrict__ b1,
                                                      const float* __restrict__ b2,
                                                      __hip_bfloat16* __restrict__ o1bf,
                                                      float* __restrict__ h1,
                                                      float* __restrict__ bnsum) {
    __shared__ __align__(16) short As[2][4096];
    __shared__ __align__(16) short Bs[2][4096];
    int t = threadIdx.x;
    int lane = t & 63, wave = t >> 6;
    int wm = wave >> 1, wn = wave & 1;
    int quad = lane >> 4, l16 = lane & 15;
    int row0 = blockIdx.y * 128, col0 = blockIdx.x * 128;

    f32x4 acc[4][4] = {};
    int r_ld = (lane >> 2);
    int koff = (((lane & 3) ^ ((lane >> 3) & 3)) * 8);
    int swz = (l16 >> 1) & 3;

    auto stage = [&](int buf, int k0) {
#pragma unroll
        for (int c = 0; c < 4; c++) {
            int q = wave * 4 + c;
            int ch = q & 7;
            int r = ch * 16 + r_ld;
            const __hip_bfloat16* gp;
            short* lp;
            if (q < 8) { gp = A   + (size_t)(row0 + r) * 512 + k0 + koff; lp = &As[buf][ch * 512]; }
            else       { gp = Bpk + (size_t)(col0 + r) * 512 + k0 + koff; lp = &Bs[buf][ch * 512]; }
            __builtin_amdgcn_global_load_lds(
                (const __attribute__((address_space(1))) unsigned int*)(uintptr_t)gp,
                (__attribute__((address_space(3))) unsigned int*)(uintptr_t)lp,
                16, 0, 0);
        }
    };

    stage(0, 0);
    for (int kk = 0; kk < 16; kk++) {
        int cur = kk & 1;
        if (kk + 1 < 16) {
            stage(cur ^ 1, (kk + 1) * 32);
            PIPE_WAIT_ENTER(4)
        } else {
            PIPE_WAIT_ENTER(0)
        }
        bf16x8 a[4], b[4];
#pragma unroll
        for (int i = 0; i < 4; i++)
            a[i] = *(const bf16x8*)&As[cur][(wm * 64 + i * 16 + l16) * 32 + ((quad ^ swz) << 3)];
#pragma unroll
        for (int j = 0; j < 4; j++)
            b[j] = *(const bf16x8*)&Bs[cur][(wn * 64 + j * 16 + l16) * 32 + ((quad ^ swz) << 3)];
#pragma unroll
        for (int i = 0; i < 4; i++)
#pragma unroll
            for (int j = 0; j < 4; j++)
                acc[i][j] = __builtin_amdgcn_mfma_f32_16x16x32_bf16(a[i], b[j], acc[i][j], 0, 0, 0);
        PIPE_EXIT()
    }

#pragma unroll
    for (int i = 0; i < 4; i++) {
        int gm0 = row0 + wm * 64 + i * 16 + quad * 4;
#pragma unroll
        for (int r = 0; r < 4; r++) {
            int gm = gm0 + r;
#pragma unroll
            for (int j = 0; j < 4; j++) {
                int col = col0 + wn * 64 + l16 + j * 16;
                float v = acc[i][j][r];
                if (col < 256) {
                    v = fmaxf(v + b1[col], 0.f);
                    o1bf[(size_t)gm * H_ + col] = __float2bfloat16(v);
                } else {
                    h1[(size_t)gm * 128 + (col - 256)] = v + b2[col - 256];
                }
            }
        }
    }

    if (col0 == 256) {
        // BN partial sums over this block's 128 rows, per h1 column.
#pragma unroll
        for (int j = 0; j < 4; j++) {
            int cj = wn * 64 + j * 16 + l16;      // h1 col 0..127
            float bj = b2[cj];
            float s = 0.f, ss = 0.f;
#pragma unroll
            for (int i = 0; i < 4; i++)
#pragma unroll
                for (int r = 0; r < 4; r++) {
                    float v = acc[i][j][r] + bj;
                    s += v;
                    ss += v * v;
                }
            s  += __shfl_xor(s, 16);  s  += __shfl_xor(s, 32);   // reduce across quads
            ss += __shfl_xor(ss, 16); ss += __shfl_xor(ss, 32);
            if (quad == 0) {
                atomicAdd(&bnsum[cj], s);
                atomicAdd(&bnsum[128 + cj], ss);
            }
        }
    }
}

// msg[e,o] = (he[e,:]/64).(fp8 V[row[e],o,:]) + outb[row[e],o]; atomicAdd into agg[col[e],o]
// Edges processed in row-sorted order, XCD-chunked: block b on XCD b%8 handles
// eord[(b%8)*512 + b/8] -> same-row edges run back-to-back on one XCD -> V8 L2 hits.
// 4 independent partial accumulators break the serial FMA chain.
__global__ void k_msg(const int* __restrict__ ei, const int* __restrict__ eord,
                      const float* __restrict__ he,
                      const unsigned char* __restrict__ V8, const float* __restrict__ outb,
                      float* __restrict__ agg) {
    int bid = blockIdx.x;
    int e = eord[((bid & 7) << 9) | (bid >> 3)];
    int o = threadIdx.x;
    __shared__ float hs[KH_];
    if (o < KH_) hs[o] = he[e * KH_ + o] * VSCALE_INV;
    __syncthreads();
    int r = ei[e], c = ei[E_ + e];
    const unsigned char* vbase = V8 + (size_t)r * NV_ + o * 16;

    auto dot16 = [&](uint4 u, const float* hp) -> float {
        f32x2 f;
        float s;
        f = __builtin_amdgcn_cvt_pk_f32_fp8(u.x, false); s  = hp[0]  * f.x + hp[1]  * f.y;
        f = __builtin_amdgcn_cvt_pk_f32_fp8(u.x, true);  s += hp[2]  * f.x + hp[3]  * f.y;
        f = __builtin_amdgcn_cvt_pk_f32_fp8(u.y, false); s += hp[4]  * f.x + hp[5]  * f.y;
        f = __builtin_amdgcn_cvt_pk_f32_fp8(u.y, true);  s += hp[6]  * f.x + hp[7]  * f.y;
        f = __builtin_amdgcn_cvt_pk_f32_fp8(u.z, false); s += hp[8]  * f.x + hp[9]  * f.y;
        f = __builtin_amdgcn_cvt_pk_f32_fp8(u.z, true);  s += hp[10] * f.x + hp[11] * f.y;
        f = __builtin_amdgcn_cvt_pk_f32_fp8(u.w, false); s += hp[12] * f.x + hp[13] * f.y;
        f = __builtin_amdgcn_cvt_pk_f32_fp8(u.w, true);  s += hp[14] * f.x + hp[15] * f.y;
        return s;
    };

    float p0, p1, p2, p3;
    {
        uint4 u0 = *(const uint4*)(vbase);
        uint4 u1 = *(const uint4*)(vbase + 4096);
        uint4 u2 = *(const uint4*)(vbase + 2 * 4096);
        uint4 u3 = *(const uint4*)(vbase + 3 * 4096);
        p0 = dot16(u0, hs);
        p1 = dot16(u1, hs + 16);
        p2 = dot16(u2, hs + 32);
        p3 = dot16(u3, hs + 48);
    }
    {
        uint4 u0 = *(const uint4*)(vbase + 4 * 4096);
        uint4 u1 = *(const uint4*)(vbase + 5 * 4096);
        uint4 u2 = *(const uint4*)(vbase + 6 * 4096);
        uint4 u3 = *(const uint4*)(vbase + 7 * 4096);
        p0 += dot16(u0, hs + 64);
        p1 += dot16(u1, hs + 80);
        p2 += dot16(u2, hs + 96);
        p3 += dot16(u3, hs + 112);
    }
    float acc = outb[(size_t)r * H_ + o] + ((p0 + p1) + (p2 + p3));
    atomicAdd(&agg[(size_t)c * H_ + o], acc);
}

// GRU pointwise; refreshes Abf = bf16(h); zeroes agg for the next iteration.
__global__ void k_gru_update(const float* __restrict__ gi, const float* __restrict__ gh,
                             float* __restrict__ h, __hip_bfloat16* __restrict__ Abf,
                             float* __restrict__ agg) {
    int i = blockIdx.x * blockDim.x + threadIdx.x;
    if (i >= N_ * H_) return;
    int n = i >> 8, j = i & 255;
    const float* gip = gi + (size_t)n * NG_;
    const float* ghp = gh + (size_t)n * NG_;
    float r = 1.f / (1.f + expf(-(gip[j] + ghp[j])));
    float z = 1.f / (1.f + expf(-(gip[H_ + j] + ghp[H_ + j])));
    float nn = tanhf(gip[2 * H_ + j] + r * ghp[2 * H_ + j]);
    float hv = (1.f - z) * nn + z * h[i];
    h[i] = hv;
    Abf[i] = __float2bfloat16(hv);
    agg[i] = 0.f;
}

// precs[e] = relu(bn(h1[e])) . l6_W2 + b   (mu/rsig computed inline from bnsum)
__global__ void k_precs(const float* __restrict__ h1, const float* __restrict__ bnsum,
                        const float* __restrict__ g, const float* __restrict__ bb,
                        const float* __restrict__ W2, const float* __restrict__ b2,
                        float* __restrict__ out) {
    __shared__ float smu[128], srs[128];
    int t = threadIdx.x;
    if (t < 128) {
        float mu = bnsum[t] * (1.f / E_);
        float var = bnsum[128 + t] * (1.f / E_) - mu * mu;
        smu[t] = mu;
        srs[t] = rsqrtf(var + 1e-5f);
    }
    __syncthreads();
    int e = blockIdx.x * blockDim.x + t;
    if (e >= E_) return;
    float acc = b2[0];
#pragma unroll 4
    for (int j = 0; j < 128; j++) {
        float v = (h1[(size_t)e * 128 + j] - smu[j]) * srs[j] * g[j] + bb[j];
        acc += fmaxf(v, 0.f) * W2[j];
    }
    out[(size_t)E_ * 242 + e] = acc;
}

extern "C" void kernel_launch(void* const* d_in, const int* in_sizes, int n_in,
                              void* d_out, int out_size, void* d_ws, size_t ws_size,
                              hipStream_t stream) {
    const int*   x        = (const int*)  d_in[0];
    const float* pos      = (const float*)d_in[1];
    const int*   ei       = (const int*)  d_in[2];
    const float* edge_atr = (const float*)d_in[3];
    const float* emb      = (const float*)d_in[4];
    const float* lin0_W   = (const float*)d_in[5];
    const float* lin0_b   = (const float*)d_in[6];
    const float* mlp1_W   = (const float*)d_in[7];
    const float* mlp1_b   = (const float*)d_in[8];
    const float* mlp2_W   = (const float*)d_in[9];
    const float* mlp2_b   = (const float*)d_in[10];
    const float* conv_b   = (const float*)d_in[11];
    const float* gru_Wih  = (const float*)d_in[12];
    const float* gru_Whh  = (const float*)d_in[13];
    const float* gru_bih  = (const float*)d_in[14];
    const float* gru_bhh  = (const float*)d_in[15];
    const float* lin1_W   = (const float*)d_in[16];
    const float* lin1_b   = (const float*)d_in[17];
    const float* lin2_W   = (const float*)d_in[18];
    const float* lin2_b   = (const float*)d_in[19];
    const float* l6_W1    = (const float*)d_in[20];
    const float* l6_b1    = (const float*)d_in[21];
    const float* bn_g     = (const float*)d_in[22];
    const float* bn_b     = (const float*)d_in[23];
    const float* l6_W2    = (const float*)d_in[24];
    const float* l6_b2    = (const float*)d_in[25];
    float* out = (float*)d_out;

    // workspace layout
    char* w = (char*)d_ws;
    size_t off = 0;
    auto alloc = [&](size_t bytes) -> void* {
        void* p = w + off;
        off = (off + bytes + 255) & ~(size_t)255;
        return p;
    };
    float* hbuf   = (float*)alloc((size_t)N_ * H_ * 4);
    float* aggm   = (float*)alloc((size_t)N_ * H_ * 4);
    float* outb   = (float*)alloc((size_t)N_ * H_ * 4);
    float* he     = (float*)alloc((size_t)E_ * KH_ * 4);
    float* gi     = (float*)alloc((size_t)N_ * NG_ * 4);
    float* gh     = (float*)alloc((size_t)N_ * NG_ * 4);
    float* h1     = (float*)alloc((size_t)E_ * 128 * 4);
    float* counts = (float*)alloc((size_t)N_ * 4);
    float* bnsum  = (float*)alloc(256 * 4);
    int*   deg    = (int*)  alloc((size_t)N_ * 4);
    int*   wcur   = (int*)  alloc((size_t)N_ * 4);
    int*   rowptr = (int*)  alloc((size_t)(N_ + 1) * 4);
    int*   eord   = (int*)  alloc((size_t)E_ * 4);
    unsigned char* V8      = (unsigned char*)alloc((size_t)N_ * NV_);          // 65.5 MB fp8
    __hip_bfloat16* Abf    = (__hip_bfloat16*)alloc((size_t)MPAD_ * H_ * 2);
    __hip_bfloat16* Bt     = (__hip_bfloat16*)alloc((size_t)NV_ * H_ * 2);     // 16.8 MB
    __hip_bfloat16* WihB   = (__hip_bfloat16*)alloc((size_t)NG_ * H_ * 2);
    __hip_bfloat16* WhhB   = (__hip_bfloat16*)alloc((size_t)NG_ * H_ * 2);
    __hip_bfloat16* Bpk    = (__hip_bfloat16*)alloc((size_t)384 * 512 * 2);
    __hip_bfloat16* lin2Wb = (__hip_bfloat16*)alloc((size_t)H_ * H_ * 2);
    __hip_bfloat16* BtB    = (__hip_bfloat16*)alloc((size_t)H_ * H_ * 2);
    __hip_bfloat16* Cbf    = (__hip_bfloat16*)alloc((size_t)E_ * 2 * H_ * 2);
    __hip_bfloat16* o1bf   = (__hip_bfloat16*)alloc((size_t)E_ * H_ * 2);

    k_lin0<<<MPAD_, 256, 0, stream>>>(x, pos, emb, lin0_W, lin0_b, hbuf, Abf,
                                      counts, aggm, deg, wcur);
    k_he<<<E_, 128, 0, stream>>>(edge_atr, mlp1_W, mlp1_b, he, ei, counts, deg);
    k_scan<<<1, 256, 0, stream>>>(deg, rowptr);
    k_fill<<<(E_ + 255) / 256, 256, 0, stream>>>(ei, rowptr, wcur, eord);
    k_trans_bt<<<dim3(NV_ / 64, H_ / 32), 256, 0, stream>>>(mlp2_W, Bt);
    k_prep_w<<<768, 256, 0, stream>>>(gru_Wih, gru_Whh, lin1_W, l6_W1, lin2_W, mlp2_b,
                                      WihB, WhhB, Bpk, lin2Wb, BtB);

    for (int it = 0; it < 3; it++) {
        // fused: gh = Abf@Whh^T + bhh, outb = Abf@BtB^T, V8 = fp8(Abf@Bt^T)
        k_gemm_VP<<<128 + (NV_ / 128) * (MPAD_ / 128), 256, 0, stream>>>(
            Abf, Bt, WhhB, BtB, gru_bhh, gh, outb, V8);
        k_msg<<<E_, 256, 0, stream>>>(ei, eord, he, V8, outb, aggm);
        // gi = relu(agg/c + conv_b) @ Wih^T + bih   (m-transform fused, balanced waves)
        k_gemm_gi<<<dim3(6, MPAD_ / 128), 256, 0, stream>>>(
            aggm, counts, conv_b, WihB, gru_bih, gi);
        k_gru_update<<<(N_ * H_ + 255) / 256, 256, 0, stream>>>(gi, gh, hbuf, Abf, aggm);
    }

    k_concat<<<E_, 256, 0, stream>>>(ei, hbuf, Cbf, bnsum);
    k_gemm_tail<<<dim3(3, E_ / 128), 256, 0, stream>>>(Cbf, Bpk, lin1_b, l6_b1,
                                                       o1bf, h1, bnsum);
    k_gemm_nt<256, false, false><<<dim3(2, E_ / 128), 256, 0, stream>>>(
        o1bf, lin2Wb, out, nullptr, lin2_b, 242, 242, E_);
    k_precs<<<(E_ + 255) / 256, 256, 0, stream>>>(h1, bnsum, bn_g, bn_b, l6_W2, l6_b2, out);
}

// Round 10
// 404.892 us; speedup vs baseline: 1.2209x; 1.0433x over previous
//
#include <hip/hip_runtime.h>
#include <hip/hip_bf16.h>

// Problem constants (fixed by the reference)
constexpr int N_ = 2000;   // nodes
constexpr int E_ = 4096;   // edges
constexpr int H_ = 256;    // hidden
constexpr int KH_ = 128;   // he dim (mlp1 out)
constexpr int NV_ = H_ * KH_; // 32768, V row length — fp8 bytes
constexpr int MPAD_ = 2048;   // padded M for node-side MFMA GEMMs
constexpr int NG_ = 768;      // GRU gate width (3*H)
constexpr float VSCALE = 64.f;     // fp8 scale for V (avoids e4m3 subnormals)
constexpr float VSCALE_INV = 1.f / 64.f;

typedef short bf16x8 __attribute__((ext_vector_type(8)));
typedef float f32x4  __attribute__((ext_vector_type(4)));
typedef float f32x2  __attribute__((ext_vector_type(2)));

__device__ __forceinline__ float bf_lo(unsigned u) { return __uint_as_float(u << 16); }
__device__ __forceinline__ float bf_hi(unsigned u) { return __uint_as_float(u & 0xffff0000u); }
__device__ __forceinline__ short bfbits(float f) {
    __hip_bfloat16 b = __float2bfloat16(f);
    return *(short*)&b;
}

// ---- pipeline sync helpers (T4: counted vmcnt across raw barrier) ----
#define PIPE_WAIT_ENTER(N_OUTST)                                   \
    asm volatile("s_waitcnt vmcnt(" #N_OUTST ")" ::: "memory");    \
    __builtin_amdgcn_s_barrier();                                  \
    asm volatile("" ::: "memory");                                 \
    __builtin_amdgcn_sched_barrier(0);

#define PIPE_EXIT()                                                \
    __builtin_amdgcn_sched_barrier(0);                             \
    asm volatile("" ::: "memory");                                 \
    __builtin_amdgcn_s_barrier();

// out = relu([emb[x], pos] @ lin0_W.T + b); emits Abf (bf16, zero-padded rows).
// Also zero-inits counts/deg/aggm (replaces memsets).
__global__ void k_lin0(const int* __restrict__ x, const float* __restrict__ pos,
                       const float* __restrict__ emb, const float* __restrict__ W,
                       const float* __restrict__ b, float* __restrict__ out,
                       __hip_bfloat16* __restrict__ Abf,
                       float* __restrict__ counts, float* __restrict__ aggm,
                       int* __restrict__ deg) {
    int n = blockIdx.x, t = threadIdx.x;
    if (n >= N_) { Abf[(size_t)n * H_ + t] = __float2bfloat16(0.f); return; }
    if (t == 0) counts[n] = 0.f;
    if (t == 1) deg[n] = 0;
    aggm[(size_t)n * H_ + t] = 0.f;
    __shared__ float in_p[8];
    if (t < 5) in_p[t] = emb[x[n] * 5 + t];
    else if (t < 8) in_p[t] = pos[n * 3 + (t - 5)];
    __syncthreads();
    float acc = b[t];
#pragma unroll
    for (int i = 0; i < 8; i++) acc += in_p[i] * W[t * 8 + i];
    float v = fmaxf(acc, 0.f);
    out[n * H_ + t] = v;
    Abf[(size_t)n * H_ + t] = __float2bfloat16(v);
}

// he = relu(edge_atr @ mlp1_W.T + b); also tallies col in-degree + row out-degree.
// grid E, block 128
__global__ void k_he(const float* __restrict__ ea, const float* __restrict__ W,
                     const float* __restrict__ b, float* __restrict__ he,
                     const int* __restrict__ ei, float* __restrict__ counts,
                     int* __restrict__ deg) {
    int e = blockIdx.x, t = threadIdx.x;
    __shared__ float a[5];
    if (t < 5) a[t] = ea[e * 5 + t];
    if (t == 8) atomicAdd(&counts[ei[E_ + e]], 1.0f);
    if (t == 9) atomicAdd(&deg[ei[e]], 1);
    __syncthreads();
    float acc = b[t];
#pragma unroll
    for (int i = 0; i < 5; i++) acc += a[i] * W[t * 5 + i];
    he[e * KH_ + t] = fmaxf(acc, 0.f);
}

// Fused scan+fill: exclusive prefix over deg -> LDS rowptr, then scatter edge ids
// into row-sorted eord (LDS write-cursors).  1 block, 256 threads.
__global__ void k_scanfill(const int* __restrict__ ei, const int* __restrict__ deg,
                           int* __restrict__ eord) {
    __shared__ int rp[N_];
    __shared__ int wc[N_];
    __shared__ int ws[256];
    int t = threadIdx.x;
    int base = t * 8;
    int loc[8];
    int s = 0;
#pragma unroll
    for (int j = 0; j < 8; j++) {
        int idx = base + j;
        int d = (idx < N_) ? deg[idx] : 0;
        loc[j] = s;
        s += d;
    }
    ws[t] = s;
    __syncthreads();
    for (int off2 = 1; off2 < 256; off2 <<= 1) {
        int v = (t >= off2) ? ws[t - off2] : 0;
        __syncthreads();
        ws[t] += v;
        __syncthreads();
    }
    int excl = ws[t] - s;
#pragma unroll
    for (int j = 0; j < 8; j++) {
        int idx = base + j;
        if (idx < N_) { rp[idx] = excl + loc[j]; wc[idx] = 0; }
    }
    __syncthreads();
    for (int e = t; e < E_; e += 256) {
        int r = ei[e];
        int p = atomicAdd(&wc[r], 1);
        eord[rp[r] + p] = e;
    }
}

// Bt[nv][h] = mlp2_W[h*32768 + nv] as bf16 (transpose+convert), once per launch.
__global__ void k_trans_bt(const float* __restrict__ W, __hip_bfloat16* __restrict__ Bt) {
    __shared__ float tile[32][68];   // 68: 16B-aligned rows, bank-shifted
    int t = threadIdx.x;
    int n0 = blockIdx.x * 64, k0 = blockIdx.y * 32;
#pragma unroll
    for (int i = 0; i < 2; i++) {
        int idx = t + i * 256;                 // 0..511
        int kk = idx >> 4, nn = (idx & 15) * 4;
        float4 f = *(const float4*)&W[(size_t)(k0 + kk) * NV_ + n0 + nn];
        *(float4*)&tile[kk][nn] = f;
    }
    __syncthreads();
#pragma unroll
    for (int i = 0; i < 2; i++) {
        int idx = t + i * 256;                 // 0..511
        int nn = idx >> 3, k4 = (idx & 7) * 4;
        short4 s;
        s.x = bfbits(tile[k4 + 0][nn]);
        s.y = bfbits(tile[k4 + 1][nn]);
        s.z = bfbits(tile[k4 + 2][nn]);
        s.w = bfbits(tile[k4 + 3][nn]);
        *(short4*)&Bt[(size_t)(n0 + nn) * H_ + k0 + k4] = s;
    }
}

// One-time weight preps (bf16 converts + packed tail B + lin2 pad + mlp2_b transpose).
__global__ void k_prep_w(const float* __restrict__ Wih, const float* __restrict__ Whh,
                         const float* __restrict__ lin1W, const float* __restrict__ l6W1,
                         const float* __restrict__ lin2W, const float* __restrict__ b2,
                         __hip_bfloat16* __restrict__ WihB, __hip_bfloat16* __restrict__ WhhB,
                         __hip_bfloat16* __restrict__ Bpk,
                         __hip_bfloat16* __restrict__ lin2Wb, __hip_bfloat16* __restrict__ BtB) {
    int i = blockIdx.x * 256 + threadIdx.x;     // i < 196608
    if (i < NG_ * H_) {
        WihB[i] = __float2bfloat16(Wih[i]);
        WhhB[i] = __float2bfloat16(Whh[i]);
    }
    Bpk[i] = __float2bfloat16(i < 256 * 512 ? lin1W[i] : l6W1[i - 256 * 512]);
    if (i < 128 * 2 * H_) {
        int r = i >> 8, k = i & 255;
        lin2Wb[i] = __float2bfloat16(r < 242 ? lin2W[r * H_ + k] : 0.f);
        int o = i >> 8, h = i & 255;
        BtB[o * H_ + h] = __float2bfloat16(b2[h * H_ + o]);
    }
}

// Cbf[e] = bf16([h[row[e]], h[col[e]]]); block 0 zero-inits bnsum.  grid E, block 256
__global__ void k_concat(const int* __restrict__ ei, const float* __restrict__ h,
                         __hip_bfloat16* __restrict__ Cbf, float* __restrict__ bnsum) {
    int e = blockIdx.x, t = threadIdx.x;
    if (e == 0) bnsum[t] = 0.f;
    int r = ei[e], c = ei[E_ + e];
    Cbf[(size_t)e * 512 + t]       = __float2bfloat16(h[(size_t)r * H_ + t]);
    Cbf[(size_t)e * 512 + 256 + t] = __float2bfloat16(h[(size_t)c * H_ + t]);
}

// Fused per-iteration GEMM launch (one grid, block-uniform branch):
//   blocks [0,128):    pair part — gh / outb from Abf (depth-2, buffers 0/1)
//   blocks [128,4224): V part — V8 = fp8(Abf @ Bt^T), permuted layout (depth-3)
// Depth-3 on the V part: with K=256 (8 steps) the 2-deep pipeline exposes one
// full L3 latency per stage; 3 buffers keep 2 stages in flight (vmcnt(8)).
// LDS 48KB -> 3 blocks/CU (12 waves/CU, still overlap regime per m114).
__global__ __launch_bounds__(256, 3) void k_gemm_VP(const __hip_bfloat16* __restrict__ Abf,
                                                    const __hip_bfloat16* __restrict__ Bt,
                                                    const __hip_bfloat16* __restrict__ WhhB,
                                                    const __hip_bfloat16* __restrict__ BtB,
                                                    const float* __restrict__ bhh,
                                                    float* __restrict__ gh,
                                                    float* __restrict__ outb,
                                                    unsigned char* __restrict__ V8) {
    __shared__ __align__(16) short As[3][4096];
    __shared__ __align__(16) short Bs[3][4096];
    int bid = blockIdx.x;
    int t = threadIdx.x;
    int lane = t & 63, wave = t >> 6;
    int wm = wave >> 1, wn = wave & 1;
    int quad = lane >> 4, l16 = lane & 15;
    int r_ld = (lane >> 2);
    int koff = (((lane & 3) ^ ((lane >> 3) & 3)) * 8);
    int swz = (l16 >> 1) & 3;

    if (bid < 128) {
        // ---------------- pair part (depth-2) ----------------
        int pbx = bid & 7, pby = bid >> 3;
        bool ob = (pbx >= 6);
        const __hip_bfloat16* Bp = ob ? BtB : WhhB;
        int col0 = ob ? (pbx - 6) * 128 : pbx * 128;
        int ldc = ob ? H_ : NG_;
        float* C = ob ? outb : gh;
        int row0 = pby * 128;

        f32x4 acc[4][4] = {};
        auto stage = [&](int buf, int k0) {
#pragma unroll
            for (int c = 0; c < 4; c++) {
                int q = wave * 4 + c;
                int ch = q & 7;
                int r = ch * 16 + r_ld;
                const __hip_bfloat16* gp;
                short* lp;
                if (q < 8) { gp = Abf + ((size_t)(row0 + r) << 8) + k0 + koff; lp = &As[buf][ch * 512]; }
                else       { gp = Bp  + ((size_t)(col0 + r) << 8) + k0 + koff; lp = &Bs[buf][ch * 512]; }
                __builtin_amdgcn_global_load_lds(
                    (const __attribute__((address_space(1))) unsigned int*)(uintptr_t)gp,
                    (__attribute__((address_space(3))) unsigned int*)(uintptr_t)lp,
                    16, 0, 0);
            }
        };
        stage(0, 0);
        for (int kk = 0; kk < 8; kk++) {
            int cur = kk & 1;
            if (kk + 1 < 8) {
                stage(cur ^ 1, (kk + 1) * 32);
                PIPE_WAIT_ENTER(4)
            } else {
                PIPE_WAIT_ENTER(0)
            }
            bf16x8 a[4], b[4];
#pragma unroll
            for (int i = 0; i < 4; i++)
                a[i] = *(const bf16x8*)&As[cur][(wm * 64 + i * 16 + l16) * 32 + ((quad ^ swz) << 3)];
#pragma unroll
            for (int j = 0; j < 4; j++)
                b[j] = *(const bf16x8*)&Bs[cur][(wn * 64 + j * 16 + l16) * 32 + ((quad ^ swz) << 3)];
#pragma unroll
            for (int i = 0; i < 4; i++)
#pragma unroll
                for (int j = 0; j < 4; j++)
                    acc[i][j] = __builtin_amdgcn_mfma_f32_16x16x32_bf16(a[i], b[j], acc[i][j], 0, 0, 0);
            PIPE_EXIT()
        }
#pragma unroll
        for (int i = 0; i < 4; i++) {
            int gm0 = row0 + wm * 64 + i * 16 + quad * 4;
#pragma unroll
            for (int r = 0; r < 4; r++) {
                int gm = gm0 + r;
                if (gm < N_) {
#pragma unroll
                    for (int j = 0; j < 4; j++) {
                        int col = col0 + wn * 64 + l16 + j * 16;
                        float v = acc[i][j][r] + (ob ? 0.f : bhh[col]);
                        C[(size_t)gm * ldc + col] = v;
                    }
                }
            }
        }
        return;
    }

    // ---------------- V part (depth-3) ----------------
    int vb = bid - 128;
    int bx = vb & 255, by = vb >> 8;
    int row0 = by * 128, col0 = bx * 128;
    int obase = bx * 8;                    // o = (obase+ch)&255
    int kb = (bx >> 5) * 16;               // k16*16
    short* Ps = &As[0][0];                 // epilogue alias: 32 x 136 shorts

    f32x4 acc[4][4] = {};
    auto stage = [&](int buf, int k0) {
#pragma unroll
        for (int c = 0; c < 4; c++) {
            int q = wave * 4 + c;
            int ch = q & 7;
            const __hip_bfloat16* gp;
            short* lp;
            if (q < 8) {
                gp = Abf + ((size_t)(row0 + ch * 16 + r_ld) << 8) + k0 + koff;
                lp = &As[buf][ch * 512];
            } else {
                int nv = ((obase + ch) & 255) * 128 + kb + r_ld;   // f -> nv remap
                gp = Bt + ((size_t)nv << 8) + k0 + koff;
                lp = &Bs[buf][ch * 512];
            }
            __builtin_amdgcn_global_load_lds(
                (const __attribute__((address_space(1))) unsigned int*)(uintptr_t)gp,
                (__attribute__((address_space(3))) unsigned int*)(uintptr_t)lp,
                16, 0, 0);
        }
    };
    stage(0, 0);
    stage(1, 32);
    for (int kk = 0; kk < 8; kk++) {
        int cur = kk % 3;
        if (kk + 2 < 8) {
            stage((kk + 2) % 3, (kk + 2) * 32);
            PIPE_WAIT_ENTER(8)
        } else if (kk + 1 < 8) {
            PIPE_WAIT_ENTER(4)
        } else {
            PIPE_WAIT_ENTER(0)
        }
        bf16x8 a[4], b[4];
#pragma unroll
        for (int i = 0; i < 4; i++)
            a[i] = *(const bf16x8*)&As[cur][(wm * 64 + i * 16 + l16) * 32 + ((quad ^ swz) << 3)];
#pragma unroll
        for (int j = 0; j < 4; j++)
            b[j] = *(const bf16x8*)&Bs[cur][(wn * 64 + j * 16 + l16) * 32 + ((quad ^ swz) << 3)];
#pragma unroll
        for (int i = 0; i < 4; i++)
#pragma unroll
            for (int j = 0; j < 4; j++)
                acc[i][j] = __builtin_amdgcn_mfma_f32_16x16x32_bf16(a[i], b[j], acc[i][j], 0, 0, 0);
        PIPE_EXIT()
    }

    // 4-pass epilogue: stage 32 scaled-bf16 rows in Ps, convert+store coalesced uint4.
#pragma unroll
    for (int pp = 0; pp < 4; pp++) {
        if (wm == (pp >> 1)) {
#pragma unroll
            for (int ii = 0; ii < 2; ii++) {
                const int i = (pp & 1) * 2 + ii;       // compile-time acc index
                int lr = ii * 16 + quad * 4;           // local row in [0,32)
#pragma unroll
                for (int r = 0; r < 4; r++) {
#pragma unroll
                    for (int j = 0; j < 4; j++) {
                        int col = wn * 64 + j * 16 + l16;
                        Ps[(lr + r) * 136 + col] = bfbits(acc[i][j][r] * VSCALE);
                    }
                }
            }
        }
        __syncthreads();
        {
            int row = t >> 3;            // 0..31
            int col = (t & 7) * 16;      // 0..112 step 16
            int gm = row0 + pp * 32 + row;
            if (gm < N_) {
                uint4 ua = *(const uint4*)&Ps[row * 136 + col];
                uint4 ub = *(const uint4*)&Ps[row * 136 + col + 8];
                unsigned p0 = __builtin_amdgcn_cvt_pk_fp8_f32(bf_lo(ua.x), bf_hi(ua.x), 0, false);
                p0 = __builtin_amdgcn_cvt_pk_fp8_f32(bf_lo(ua.y), bf_hi(ua.y), p0, true);
                unsigned p1 = __builtin_amdgcn_cvt_pk_fp8_f32(bf_lo(ua.z), bf_hi(ua.z), 0, false);
                p1 = __builtin_amdgcn_cvt_pk_fp8_f32(bf_lo(ua.w), bf_hi(ua.w), p1, true);
                unsigned p2 = __builtin_amdgcn_cvt_pk_fp8_f32(bf_lo(ub.x), bf_hi(ub.x), 0, false);
                p2 = __builtin_amdgcn_cvt_pk_fp8_f32(bf_lo(ub.y), bf_hi(ub.y), p2, true);
                unsigned p3 = __builtin_amdgcn_cvt_pk_fp8_f32(bf_lo(ub.z), bf_hi(ub.z), 0, false);
                p3 = __builtin_amdgcn_cvt_pk_fp8_f32(bf_lo(ub.w), bf_hi(ub.w), p3, true);
                uint4 o4;
                o4.x = p0; o4.y = p1; o4.z = p2; o4.w = p3;
                *(uint4*)(V8 + (size_t)gm * NV_ + col0 + col) = o4;
            }
        }
        __syncthreads();
    }
}

// gi = relu(agg/c + conv_b) @ Wih^T + bih, m-transform fused into A-staging.
// BALANCED roles: every wave stages 2 A-channels and 2 B-channels.
__global__ __launch_bounds__(256, 3) void k_gemm_gi(const float* __restrict__ agg,
                                                    const float* __restrict__ counts,
                                                    const float* __restrict__ conv_b,
                                                    const __hip_bfloat16* __restrict__ WihB,
                                                    const float* __restrict__ bih,
                                                    float* __restrict__ gi) {
    __shared__ __align__(16) short As[2][4096];
    __shared__ __align__(16) short Bs[2][4096];
    __shared__ __align__(16) float conv_lds[256];
    int t = threadIdx.x;
    int lane = t & 63, wave = t >> 6;
    int wm = wave >> 1, wn = wave & 1;
    int quad = lane >> 4, l16 = lane & 15;
    int row0 = blockIdx.y * 128, col0 = blockIdx.x * 128;
    int r_ld = (lane >> 2);
    int koff = (((lane & 3) ^ ((lane >> 3) & 3)) * 8);
    int swz = (l16 >> 1) & 3;

    conv_lds[t] = conv_b[t];
    __syncthreads();

    f32x4 acc[4][4] = {};
    float rcv[2];
    const float* asrc[2];
#pragma unroll
    for (int c = 0; c < 2; c++) {
        int ch = wave * 2 + c;
        int row = row0 + ch * 16 + r_ld;
        int rowc = row < N_ ? row : N_ - 1;   // clamp padded rows (results discarded)
        rcv[c] = 1.f / fmaxf(counts[rowc], 1.f);
        asrc[c] = agg + (size_t)rowc * 256;
    }
    float4 R[2][2][2];

    auto loadA = [&](int buf, int k0) {
#pragma unroll
        for (int c = 0; c < 2; c++) {
            R[buf][c][0] = *(const float4*)(asrc[c] + k0 + koff);
            R[buf][c][1] = *(const float4*)(asrc[c] + k0 + koff + 4);
        }
    };
    auto stageB = [&](int buf, int k0) {
#pragma unroll
        for (int c = 0; c < 2; c++) {
            int ch = wave * 2 + c;
            const __hip_bfloat16* gp = WihB + (size_t)(col0 + ch * 16 + r_ld) * 256 + k0 + koff;
            short* lp = &Bs[buf][ch * 512];
            __builtin_amdgcn_global_load_lds(
                (const __attribute__((address_space(1))) unsigned int*)(uintptr_t)gp,
                (__attribute__((address_space(3))) unsigned int*)(uintptr_t)lp,
                16, 0, 0);
        }
    };
    auto writeA = [&](int buf, int k0) {
        float4 cb0 = *(const float4*)&conv_lds[k0 + koff];
        float4 cb1 = *(const float4*)&conv_lds[k0 + koff + 4];
#pragma unroll
        for (int c = 0; c < 2; c++) {
            int ch = wave * 2 + c;
            float rc = rcv[c];
            float4 a0 = R[buf][c][0], a1 = R[buf][c][1];
            bf16x8 v;
            v[0] = bfbits(fmaxf(a0.x * rc + cb0.x, 0.f));
            v[1] = bfbits(fmaxf(a0.y * rc + cb0.y, 0.f));
            v[2] = bfbits(fmaxf(a0.z * rc + cb0.z, 0.f));
            v[3] = bfbits(fmaxf(a0.w * rc + cb0.w, 0.f));
            v[4] = bfbits(fmaxf(a1.x * rc + cb1.x, 0.f));
            v[5] = bfbits(fmaxf(a1.y * rc + cb1.y, 0.f));
            v[6] = bfbits(fmaxf(a1.z * rc + cb1.z, 0.f));
            v[7] = bfbits(fmaxf(a1.w * rc + cb1.w, 0.f));
            *(bf16x8*)&As[buf][ch * 512 + lane * 8] = v;   // same slotting as gload_lds
        }
    };

    loadA(0, 0);
    stageB(0, 0);
#pragma unroll
    for (int kk = 0; kk < 8; kk++) {
        const int cur = kk & 1;
        if (kk + 1 < 8) {
            loadA(cur ^ 1, (kk + 1) * 32);
            stageB(cur ^ 1, (kk + 1) * 32);
        }
        writeA(cur, kk * 32);   // compiler auto-waits on R[cur]'s loads
        if (kk + 1 < 8) { asm volatile("s_waitcnt vmcnt(6)" ::: "memory"); }
        else            { asm volatile("s_waitcnt vmcnt(0)" ::: "memory"); }
        asm volatile("s_waitcnt lgkmcnt(0)" ::: "memory");
        __builtin_amdgcn_s_barrier();
        asm volatile("" ::: "memory");
        __builtin_amdgcn_sched_barrier(0);
        bf16x8 a[4], b[4];
#pragma unroll
        for (int i = 0; i < 4; i++)
            a[i] = *(const bf16x8*)&As[cur][(wm * 64 + i * 16 + l16) * 32 + ((quad ^ swz) << 3)];
#pragma unroll
        for (int j = 0; j < 4; j++)
            b[j] = *(const bf16x8*)&Bs[cur][(wn * 64 + j * 16 + l16) * 32 + ((quad ^ swz) << 3)];
#pragma unroll
        for (int i = 0; i < 4; i++)
#pragma unroll
            for (int j = 0; j < 4; j++)
                acc[i][j] = __builtin_amdgcn_mfma_f32_16x16x32_bf16(a[i], b[j], acc[i][j], 0, 0, 0);
        PIPE_EXIT()
    }

#pragma unroll
    for (int i = 0; i < 4; i++) {
        int gm0 = row0 + wm * 64 + i * 16 + quad * 4;
#pragma unroll
        for (int r = 0; r < 4; r++) {
            int gm = gm0 + r;
            if (gm < N_) {
#pragma unroll
                for (int j = 0; j < 4; j++) {
                    int col = col0 + wn * 64 + l16 + j * 16;
                    gi[(size_t)gm * NG_ + col] = acc[i][j][r] + bih[col];
                }
            }
        }
    }
}

// Tail GEMM with packed B (384x512): cols 0..255 -> relu->o1bf; cols 256..383 -> h1.
// Block x==2 additionally emits BN column partial sums (shfl-reduced, 2 atomics/col/wave).
__global__ __launch_bounds__(256, 3) void k_gemm_tail(const __hip_bfloat16* __restrict__ A,
                                                      const __hip_bfloat16* __restrict__ Bpk,
                                                      const float* __restrict__ b1,
                                                      const float* __restrict__ b2,
                                                      __hip_bfloat16* __restrict__ o1bf,
                                                      float* __restrict__ h1,
                                                      float* __restrict__ bnsum) {
    __shared__ __align__(16) short As[2][4096];
    __shared__ __align__(16) short Bs[2][4096];
    int t = threadIdx.x;
    int lane = t & 63, wave = t >> 6;
    int wm = wave >> 1, wn = wave & 1;
    int quad = lane >> 4, l16 = lane & 15;
    int row0 = blockIdx.y * 128, col0 = blockIdx.x * 128;

    f32x4 acc[4][4] = {};
    int r_ld = (lane >> 2);
    int koff = (((lane & 3) ^ ((lane >> 3) & 3)) * 8);
    int swz = (l16 >> 1) & 3;

    auto stage = [&](int buf, int k0) {
#pragma unroll
        for (int c = 0; c < 4; c++) {
            int q = wave * 4 + c;
            int ch = q & 7;
            int r = ch * 16 + r_ld;
            const __hip_bfloat16* gp;
            short* lp;
            if (q < 8) { gp = A   + (size_t)(row0 + r) * 512 + k0 + koff; lp = &As[buf][ch * 512]; }
            else       { gp = Bpk + (size_t)(col0 + r) * 512 + k0 + koff; lp = &Bs[buf][ch * 512]; }
            __builtin_amdgcn_global_load_lds(
                (const __attribute__((address_space(1))) unsigned int*)(uintptr_t)gp,
                (__attribute__((address_space(3))) unsigned int*)(uintptr_t)lp,
                16, 0, 0);
        }
    };

    stage(0, 0);
    for (int kk = 0; kk < 16; kk++) {
        int cur = kk & 1;
        if (kk + 1 < 16) {
            stage(cur ^ 1, (kk + 1) * 32);
            PIPE_WAIT_ENTER(4)
        } else {
            PIPE_WAIT_ENTER(0)
        }
        bf16x8 a[4], b[4];
#pragma unroll
        for (int i = 0; i < 4; i++)
            a[i] = *(const bf16x8*)&As[cur][(wm * 64 + i * 16 + l16) * 32 + ((quad ^ swz) << 3)];
#pragma unroll
        for (int j = 0; j < 4; j++)
            b[j] = *(const bf16x8*)&Bs[cur][(wn * 64 + j * 16 + l16) * 32 + ((quad ^ swz) << 3)];
#pragma unroll
        for (int i = 0; i < 4; i++)
#pragma unroll
            for (int j = 0; j < 4; j++)
                acc[i][j] = __builtin_amdgcn_mfma_f32_16x16x32_bf16(a[i], b[j], acc[i][j], 0, 0, 0);
        PIPE_EXIT()
    }

#pragma unroll
    for (int i = 0; i < 4; i++) {
        int gm0 = row0 + wm * 64 + i * 16 + quad * 4;
#pragma unroll
        for (int r = 0; r < 4; r++) {
            int gm = gm0 + r;
#pragma unroll
            for (int j = 0; j < 4; j++) {
                int col = col0 + wn * 64 + l16 + j * 16;
                float v = acc[i][j][r];
                if (col < 256) {
                    v = fmaxf(v + b1[col], 0.f);
                    o1bf[(size_t)gm * H_ + col] = __float2bfloat16(v);
                } else {
                    h1[(size_t)gm * 128 + (col - 256)] = v + b2[col - 256];
                }
            }
        }
    }

    if (col0 == 256) {
        // BN partial sums over this block's 128 rows, per h1 column.
#pragma unroll
        for (int j = 0; j < 4; j++) {
            int cj = wn * 64 + j * 16 + l16;      // h1 col 0..127
            float bj = b2[cj];
            float s = 0.f, ss = 0.f;
#pragma unroll
            for (int i = 0; i < 4; i++)
#pragma unroll
                for (int r = 0; r < 4; r++) {
                    float v = acc[i][j][r] + bj;
                    s += v;
                    ss += v * v;
                }
            s  += __shfl_xor(s, 16);  s  += __shfl_xor(s, 32);   // reduce across quads
            ss += __shfl_xor(ss, 16); ss += __shfl_xor(ss, 32);
            if (quad == 0) {
                atomicAdd(&bnsum[cj], s);
                atomicAdd(&bnsum[128 + cj], ss);
            }
        }
    }
}

// msg[e,o] = (he[e,:]/64).(fp8 V[row[e],o,:]) + outb[row[e],o]; atomicAdd into agg[col[e],o]
// Edges processed in row-sorted order, XCD-chunked; 4 independent partial accumulators.
__global__ void k_msg(const int* __restrict__ ei, const int* __restrict__ eord,
                      const float* __restrict__ he,
                      const unsigned char* __restrict__ V8, const float* __restrict__ outb,
                      float* __restrict__ agg) {
    int bid = blockIdx.x;
    int e = eord[((bid & 7) << 9) | (bid >> 3)];
    int o = threadIdx.x;
    __shared__ float hs[KH_];
    if (o < KH_) hs[o] = he[e * KH_ + o] * VSCALE_INV;
    __syncthreads();
    int r = ei[e], c = ei[E_ + e];
    const unsigned char* vbase = V8 + (size_t)r * NV_ + o * 16;

    auto dot16 = [&](uint4 u, const float* hp) -> float {
        f32x2 f;
        float s;
        f = __builtin_amdgcn_cvt_pk_f32_fp8(u.x, false); s  = hp[0]  * f.x + hp[1]  * f.y;
        f = __builtin_amdgcn_cvt_pk_f32_fp8(u.x, true);  s += hp[2]  * f.x + hp[3]  * f.y;
        f = __builtin_amdgcn_cvt_pk_f32_fp8(u.y, false); s += hp[4]  * f.x + hp[5]  * f.y;
        f = __builtin_amdgcn_cvt_pk_f32_fp8(u.y, true);  s += hp[6]  * f.x + hp[7]  * f.y;
        f = __builtin_amdgcn_cvt_pk_f32_fp8(u.z, false); s += hp[8]  * f.x + hp[9]  * f.y;
        f = __builtin_amdgcn_cvt_pk_f32_fp8(u.z, true);  s += hp[10] * f.x + hp[11] * f.y;
        f = __builtin_amdgcn_cvt_pk_f32_fp8(u.w, false); s += hp[12] * f.x + hp[13] * f.y;
        f = __builtin_amdgcn_cvt_pk_f32_fp8(u.w, true);  s += hp[14] * f.x + hp[15] * f.y;
        return s;
    };

    float p0, p1, p2, p3;
    {
        uint4 u0 = *(const uint4*)(vbase);
        uint4 u1 = *(const uint4*)(vbase + 4096);
        uint4 u2 = *(const uint4*)(vbase + 2 * 4096);
        uint4 u3 = *(const uint4*)(vbase + 3 * 4096);
        p0 = dot16(u0, hs);
        p1 = dot16(u1, hs + 16);
        p2 = dot16(u2, hs + 32);
        p3 = dot16(u3, hs + 48);
    }
    {
        uint4 u0 = *(const uint4*)(vbase + 4 * 4096);
        uint4 u1 = *(const uint4*)(vbase + 5 * 4096);
        uint4 u2 = *(const uint4*)(vbase + 6 * 4096);
        uint4 u3 = *(const uint4*)(vbase + 7 * 4096);
        p0 += dot16(u0, hs + 64);
        p1 += dot16(u1, hs + 80);
        p2 += dot16(u2, hs + 96);
        p3 += dot16(u3, hs + 112);
    }
    float acc = outb[(size_t)r * H_ + o] + ((p0 + p1) + (p2 + p3));
    atomicAdd(&agg[(size_t)c * H_ + o], acc);
}

// GRU pointwise; refreshes Abf = bf16(h); zeroes agg for the next iteration.
__global__ void k_gru_update(const float* __restrict__ gi, const float* __restrict__ gh,
                             float* __restrict__ h, __hip_bfloat16* __restrict__ Abf,
                             float* __restrict__ agg) {
    int i = blockIdx.x * blockDim.x + threadIdx.x;
    if (i >= N_ * H_) return;
    int n = i >> 8, j = i & 255;
    const float* gip = gi + (size_t)n * NG_;
    const float* ghp = gh + (size_t)n * NG_;
    float r = 1.f / (1.f + expf(-(gip[j] + ghp[j])));
    float z = 1.f / (1.f + expf(-(gip[H_ + j] + ghp[H_ + j])));
    float nn = tanhf(gip[2 * H_ + j] + r * ghp[2 * H_ + j]);
    float hv = (1.f - z) * nn + z * h[i];
    h[i] = hv;
    Abf[i] = __float2bfloat16(hv);
    agg[i] = 0.f;
}

// Fused final launch (both parts depend only on k_gemm_tail):
//   blocks [0,64):  out2 = o1bf @ lin2Wb^T + lin2_b (242 cols, depth-2 GEMM)
//   blocks [64,80): precs = relu(bn(h1)) . W2 + b   (mu/rsig from bnsum)
__global__ __launch_bounds__(256, 3) void k_gemm_lin2p(const __hip_bfloat16* __restrict__ A,
                                                       const __hip_bfloat16* __restrict__ Bt,
                                                       const float* __restrict__ bias,
                                                       const float* __restrict__ h1,
                                                       const float* __restrict__ bnsum,
                                                       const float* __restrict__ g,
                                                       const float* __restrict__ bb,
                                                       const float* __restrict__ W2,
                                                       const float* __restrict__ b2,
                                                       float* __restrict__ out) {
    int bid = blockIdx.x;
    int t = threadIdx.x;

    if (bid >= 64) {
        // ---------------- precs part ----------------
        __shared__ float smu[128], srs[128];
        if (t < 128) {
            float mu = bnsum[t] * (1.f / E_);
            float var = bnsum[128 + t] * (1.f / E_) - mu * mu;
            smu[t] = mu;
            srs[t] = rsqrtf(var + 1e-5f);
        }
        __syncthreads();
        int e = (bid - 64) * 256 + t;
        if (e >= E_) return;
        float acc = b2[0];
#pragma unroll 4
        for (int j = 0; j < 128; j++) {
            float v = (h1[(size_t)e * 128 + j] - smu[j]) * srs[j] * g[j] + bb[j];
            acc += fmaxf(v, 0.f) * W2[j];
        }
        out[(size_t)E_ * 242 + e] = acc;
        return;
    }

    // ---------------- lin2 GEMM part (KD=256, 242 valid cols) ----------------
    __shared__ __align__(16) short As[2][4096];
    __shared__ __align__(16) short Bs[2][4096];
    int lane = t & 63, wave = t >> 6;
    int wm = wave >> 1, wn = wave & 1;
    int quad = lane >> 4, l16 = lane & 15;
    int row0 = (bid >> 1) * 128, col0 = (bid & 1) * 128;

    f32x4 acc[4][4] = {};
    int r_ld = (lane >> 2);
    int koff = (((lane & 3) ^ ((lane >> 3) & 3)) * 8);
    int swz = (l16 >> 1) & 3;

    auto stage = [&](int buf, int k0) {
#pragma unroll
        for (int c = 0; c < 4; c++) {
            int q = wave * 4 + c;
            int ch = q & 7;
            int r = ch * 16 + r_ld;
            const __hip_bfloat16* gp;
            short* lp;
            if (q < 8) { gp = A  + (size_t)(row0 + r) * 256 + k0 + koff; lp = &As[buf][ch * 512]; }
            else       { gp = Bt + (size_t)(col0 + r) * 256 + k0 + koff; lp = &Bs[buf][ch * 512]; }
            __builtin_amdgcn_global_load_lds(
                (const __attribute__((address_space(1))) unsigned int*)(uintptr_t)gp,
                (__attribute__((address_space(3))) unsigned int*)(uintptr_t)lp,
                16, 0, 0);
        }
    };

    stage(0, 0);
    for (int kk = 0; kk < 8; kk++) {
        int cur = kk & 1;
        if (kk + 1 < 8) {
            stage(cur ^ 1, (kk + 1) * 32);
            PIPE_WAIT_ENTER(4)
        } else {
            PIPE_WAIT_ENTER(0)
        }
        bf16x8 a[4], b[4];
#pragma unroll
        for (int i = 0; i < 4; i++)
            a[i] = *(const bf16x8*)&As[cur][(wm * 64 + i * 16 + l16) * 32 + ((quad ^ swz) << 3)];
#pragma unroll
        for (int j = 0; j < 4; j++)
            b[j] = *(const bf16x8*)&Bs[cur][(wn * 64 + j * 16 + l16) * 32 + ((quad ^ swz) << 3)];
#pragma unroll
        for (int i = 0; i < 4; i++)
#pragma unroll
            for (int j = 0; j < 4; j++)
                acc[i][j] = __builtin_amdgcn_mfma_f32_16x16x32_bf16(a[i], b[j], acc[i][j], 0, 0, 0);
        PIPE_EXIT()
    }

#pragma unroll
    for (int i = 0; i < 4; i++) {
        int gm0 = row0 + wm * 64 + i * 16 + quad * 4;
#pragma unroll
        for (int r = 0; r < 4; r++) {
            int gm = gm0 + r;
#pragma unroll
            for (int j = 0; j < 4; j++) {
                int col = col0 + wn * 64 + l16 + j * 16;
                if (col < 242) {
                    out[(size_t)gm * 242 + col] = acc[i][j][r] + bias[col];
                }
            }
        }
    }
}

extern "C" void kernel_launch(void* const* d_in, const int* in_sizes, int n_in,
                              void* d_out, int out_size, void* d_ws, size_t ws_size,
                              hipStream_t stream) {
    const int*   x        = (const int*)  d_in[0];
    const float* pos      = (const float*)d_in[1];
    const int*   ei       = (const int*)  d_in[2];
    const float* edge_atr = (const float*)d_in[3];
    const float* emb      = (const float*)d_in[4];
    const float* lin0_W   = (const float*)d_in[5];
    const float* lin0_b   = (const float*)d_in[6];
    const float* mlp1_W   = (const float*)d_in[7];
    const float* mlp1_b   = (const float*)d_in[8];
    const float* mlp2_W   = (const float*)d_in[9];
    const float* mlp2_b   = (const float*)d_in[10];
    const float* conv_b   = (const float*)d_in[11];
    const float* gru_Wih  = (const float*)d_in[12];
    const float* gru_Whh  = (const float*)d_in[13];
    const float* gru_bih  = (const float*)d_in[14];
    const float* gru_bhh  = (const float*)d_in[15];
    const float* lin1_W   = (const float*)d_in[16];
    const float* lin1_b   = (const float*)d_in[17];
    const float* lin2_W   = (const float*)d_in[18];
    const float* lin2_b   = (const float*)d_in[19];
    const float* l6_W1    = (const float*)d_in[20];
    const float* l6_b1    = (const float*)d_in[21];
    const float* bn_g     = (const float*)d_in[22];
    const float* bn_b     = (const float*)d_in[23];
    const float* l6_W2    = (const float*)d_in[24];
    const float* l6_b2    = (const float*)d_in[25];
    float* out = (float*)d_out;

    // workspace layout
    char* w = (char*)d_ws;
    size_t off = 0;
    auto alloc = [&](size_t bytes) -> void* {
        void* p = w + off;
        off = (off + bytes + 255) & ~(size_t)255;
        return p;
    };
    float* hbuf   = (float*)alloc((size_t)N_ * H_ * 4);
    float* aggm   = (float*)alloc((size_t)N_ * H_ * 4);
    float* outb   = (float*)alloc((size_t)N_ * H_ * 4);
    float* he     = (float*)alloc((size_t)E_ * KH_ * 4);
    float* gi     = (float*)alloc((size_t)N_ * NG_ * 4);
    float* gh     = (float*)alloc((size_t)N_ * NG_ * 4);
    float* h1     = (float*)alloc((size_t)E_ * 128 * 4);
    float* counts = (float*)alloc((size_t)N_ * 4);
    float* bnsum  = (float*)alloc(256 * 4);
    int*   deg    = (int*)  alloc((size_t)N_ * 4);
    int*   eord   = (int*)  alloc((size_t)E_ * 4);
    unsigned char* V8      = (unsigned char*)alloc((size_t)N_ * NV_);          // 65.5 MB fp8
    __hip_bfloat16* Abf    = (__hip_bfloat16*)alloc((size_t)MPAD_ * H_ * 2);
    __hip_bfloat16* Bt     = (__hip_bfloat16*)alloc((size_t)NV_ * H_ * 2);     // 16.8 MB
    __hip_bfloat16* WihB   = (__hip_bfloat16*)alloc((size_t)NG_ * H_ * 2);
    __hip_bfloat16* WhhB   = (__hip_bfloat16*)alloc((size_t)NG_ * H_ * 2);
    __hip_bfloat16* Bpk    = (__hip_bfloat16*)alloc((size_t)384 * 512 * 2);
    __hip_bfloat16* lin2Wb = (__hip_bfloat16*)alloc((size_t)H_ * H_ * 2);
    __hip_bfloat16* BtB    = (__hip_bfloat16*)alloc((size_t)H_ * H_ * 2);
    __hip_bfloat16* Cbf    = (__hip_bfloat16*)alloc((size_t)E_ * 2 * H_ * 2);
    __hip_bfloat16* o1bf   = (__hip_bfloat16*)alloc((size_t)E_ * H_ * 2);

    k_lin0<<<MPAD_, 256, 0, stream>>>(x, pos, emb, lin0_W, lin0_b, hbuf, Abf,
                                      counts, aggm, deg);
    k_he<<<E_, 128, 0, stream>>>(edge_atr, mlp1_W, mlp1_b, he, ei, counts, deg);
    k_scanfill<<<1, 256, 0, stream>>>(ei, deg, eord);
    k_trans_bt<<<dim3(NV_ / 64, H_ / 32), 256, 0, stream>>>(mlp2_W, Bt);
    k_prep_w<<<768, 256, 0, stream>>>(gru_Wih, gru_Whh, lin1_W, l6_W1, lin2_W, mlp2_b,
                                      WihB, WhhB, Bpk, lin2Wb, BtB);

    for (int it = 0; it < 3; it++) {
        // fused: gh = Abf@Whh^T + bhh, outb = Abf@BtB^T, V8 = fp8(Abf@Bt^T)
        k_gemm_VP<<<128 + (NV_ / 128) * (MPAD_ / 128), 256, 0, stream>>>(
            Abf, Bt, WhhB, BtB, gru_bhh, gh, outb, V8);
        k_msg<<<E_, 256, 0, stream>>>(ei, eord, he, V8, outb, aggm);
        // gi = relu(agg/c + conv_b) @ Wih^T + bih   (m-transform fused, balanced waves)
        k_gemm_gi<<<dim3(6, MPAD_ / 128), 256, 0, stream>>>(
            aggm, counts, conv_b, WihB, gru_bih, gi);
        k_gru_update<<<(N_ * H_ + 255) / 256, 256, 0, stream>>>(gi, gh, hbuf, Abf, aggm);
    }

    k_concat<<<E_, 256, 0, stream>>>(ei, hbuf, Cbf, bnsum);
    k_gemm_tail<<<dim3(3, E_ / 128), 256, 0, stream>>>(Cbf, Bpk, lin1_b, l6_b1,
                                                       o1bf, h1, bnsum);
    k_gemm_lin2p<<<80, 256, 0, stream>>>(o1bf, lin2Wb, lin2_b,
                                         h1, bnsum, bn_g, bn_b, l6_W2, l6_b2, out);
}

// Round 11
// 397.636 us; speedup vs baseline: 1.2431x; 1.0182x over previous
//
#include <hip/hip_runtime.h>
#include <hip/hip_bf16.h>

// Problem constants (fixed by the reference)
constexpr int N_ = 2000;   // nodes
constexpr int E_ = 4096;   // edges
constexpr int H_ = 256;    // hidden
constexpr int KH_ = 128;   // he dim (mlp1 out)
constexpr int NV_ = H_ * KH_; // 32768, V row length — fp8 bytes
constexpr int MPAD_ = 2048;   // padded M for node-side MFMA GEMMs
constexpr int NG_ = 768;      // GRU gate width (3*H)
constexpr float VSCALE = 64.f;     // fp8 scale for V (avoids e4m3 subnormals)
constexpr float VSCALE_INV = 1.f / 64.f;

typedef short bf16x8 __attribute__((ext_vector_type(8)));
typedef float f32x4  __attribute__((ext_vector_type(4)));
typedef float f32x2  __attribute__((ext_vector_type(2)));

__device__ __forceinline__ float bf_lo(unsigned u) { return __uint_as_float(u << 16); }
__device__ __forceinline__ float bf_hi(unsigned u) { return __uint_as_float(u & 0xffff0000u); }
__device__ __forceinline__ short bfbits(float f) {
    __hip_bfloat16 b = __float2bfloat16(f);
    return *(short*)&b;
}

// ---- pipeline sync helpers (T4: counted vmcnt across raw barrier), depth-2 ----
#define PIPE_WAIT_ENTER(N_OUTST)                                   \
    asm volatile("s_waitcnt vmcnt(" #N_OUTST ")" ::: "memory");    \
    __builtin_amdgcn_s_barrier();                                  \
    asm volatile("" ::: "memory");                                 \
    __builtin_amdgcn_sched_barrier(0);

#define PIPE_EXIT()                                                \
    __builtin_amdgcn_sched_barrier(0);                             \
    asm volatile("" ::: "memory");                                 \
    __builtin_amdgcn_s_barrier();

// out = relu([emb[x], pos] @ lin0_W.T + b); emits Abf (bf16, zero-padded rows).
// Also zero-inits counts/deg/aggm (replaces memsets).
__global__ void k_lin0(const int* __restrict__ x, const float* __restrict__ pos,
                       const float* __restrict__ emb, const float* __restrict__ W,
                       const float* __restrict__ b, float* __restrict__ out,
                       __hip_bfloat16* __restrict__ Abf,
                       float* __restrict__ counts, float* __restrict__ aggm,
                       int* __restrict__ deg) {
    int n = blockIdx.x, t = threadIdx.x;
    if (n >= N_) { Abf[(size_t)n * H_ + t] = __float2bfloat16(0.f); return; }
    if (t == 0) counts[n] = 0.f;
    if (t == 1) deg[n] = 0;
    aggm[(size_t)n * H_ + t] = 0.f;
    __shared__ float in_p[8];
    if (t < 5) in_p[t] = emb[x[n] * 5 + t];
    else if (t < 8) in_p[t] = pos[n * 3 + (t - 5)];
    __syncthreads();
    float acc = b[t];
#pragma unroll
    for (int i = 0; i < 8; i++) acc += in_p[i] * W[t * 8 + i];
    float v = fmaxf(acc, 0.f);
    out[n * H_ + t] = v;
    Abf[(size_t)n * H_ + t] = __float2bfloat16(v);
}

// he = relu(edge_atr @ mlp1_W.T + b); also tallies col in-degree + row out-degree.
// grid E, block 128
__global__ void k_he(const float* __restrict__ ea, const float* __restrict__ W,
                     const float* __restrict__ b, float* __restrict__ he,
                     const int* __restrict__ ei, float* __restrict__ counts,
                     int* __restrict__ deg) {
    int e = blockIdx.x, t = threadIdx.x;
    __shared__ float a[5];
    if (t < 5) a[t] = ea[e * 5 + t];
    if (t == 8) atomicAdd(&counts[ei[E_ + e]], 1.0f);
    if (t == 9) atomicAdd(&deg[ei[e]], 1);
    __syncthreads();
    float acc = b[t];
#pragma unroll
    for (int i = 0; i < 5; i++) acc += a[i] * W[t * 5 + i];
    he[e * KH_ + t] = fmaxf(acc, 0.f);
}

// Fused scan+fill: exclusive prefix over deg -> LDS rowptr, then scatter edge ids
// into row-sorted eord (LDS write-cursors).  1 block, 256 threads.
__global__ void k_scanfill(const int* __restrict__ ei, const int* __restrict__ deg,
                           int* __restrict__ eord) {
    __shared__ int rp[N_];
    __shared__ int wc[N_];
    __shared__ int ws[256];
    int t = threadIdx.x;
    int base = t * 8;
    int loc[8];
    int s = 0;
#pragma unroll
    for (int j = 0; j < 8; j++) {
        int idx = base + j;
        int d = (idx < N_) ? deg[idx] : 0;
        loc[j] = s;
        s += d;
    }
    ws[t] = s;
    __syncthreads();
    for (int off2 = 1; off2 < 256; off2 <<= 1) {
        int v = (t >= off2) ? ws[t - off2] : 0;
        __syncthreads();
        ws[t] += v;
        __syncthreads();
    }
    int excl = ws[t] - s;
#pragma unroll
    for (int j = 0; j < 8; j++) {
        int idx = base + j;
        if (idx < N_) { rp[idx] = excl + loc[j]; wc[idx] = 0; }
    }
    __syncthreads();
    for (int e = t; e < E_; e += 256) {
        int r = ei[e];
        int p = atomicAdd(&wc[r], 1);
        eord[rp[r] + p] = e;
    }
}

// Bt[nv][h] = mlp2_W[h*32768 + nv] as bf16 (transpose+convert), once per launch.
__global__ void k_trans_bt(const float* __restrict__ W, __hip_bfloat16* __restrict__ Bt) {
    __shared__ float tile[32][68];   // 68: 16B-aligned rows, bank-shifted
    int t = threadIdx.x;
    int n0 = blockIdx.x * 64, k0 = blockIdx.y * 32;
#pragma unroll
    for (int i = 0; i < 2; i++) {
        int idx = t + i * 256;                 // 0..511
        int kk = idx >> 4, nn = (idx & 15) * 4;
        float4 f = *(const float4*)&W[(size_t)(k0 + kk) * NV_ + n0 + nn];
        *(float4*)&tile[kk][nn] = f;
    }
    __syncthreads();
#pragma unroll
    for (int i = 0; i < 2; i++) {
        int idx = t + i * 256;                 // 0..511
        int nn = idx >> 3, k4 = (idx & 7) * 4;
        short4 s;
        s.x = bfbits(tile[k4 + 0][nn]);
        s.y = bfbits(tile[k4 + 1][nn]);
        s.z = bfbits(tile[k4 + 2][nn]);
        s.w = bfbits(tile[k4 + 3][nn]);
        *(short4*)&Bt[(size_t)(n0 + nn) * H_ + k0 + k4] = s;
    }
}

// One-time weight preps (bf16 converts + packed tail B + lin2 pad + mlp2_b transpose).
__global__ void k_prep_w(const float* __restrict__ Wih, const float* __restrict__ Whh,
                         const float* __restrict__ lin1W, const float* __restrict__ l6W1,
                         const float* __restrict__ lin2W, const float* __restrict__ b2,
                         __hip_bfloat16* __restrict__ WihB, __hip_bfloat16* __restrict__ WhhB,
                         __hip_bfloat16* __restrict__ Bpk,
                         __hip_bfloat16* __restrict__ lin2Wb, __hip_bfloat16* __restrict__ BtB) {
    int i = blockIdx.x * 256 + threadIdx.x;     // i < 196608
    if (i < NG_ * H_) {
        WihB[i] = __float2bfloat16(Wih[i]);
        WhhB[i] = __float2bfloat16(Whh[i]);
    }
    Bpk[i] = __float2bfloat16(i < 256 * 512 ? lin1W[i] : l6W1[i - 256 * 512]);
    if (i < 128 * 2 * H_) {
        int r = i >> 8, k = i & 255;
        lin2Wb[i] = __float2bfloat16(r < 242 ? lin2W[r * H_ + k] : 0.f);
        int o = i >> 8, h = i & 255;
        BtB[o * H_ + h] = __float2bfloat16(b2[h * H_ + o]);
    }
}

// Cbf[e] = bf16([h[row[e]], h[col[e]]]); block 0 zero-inits bnsum.  grid E, block 256
__global__ void k_concat(const int* __restrict__ ei, const float* __restrict__ h,
                         __hip_bfloat16* __restrict__ Cbf, float* __restrict__ bnsum) {
    int e = blockIdx.x, t = threadIdx.x;
    if (e == 0) bnsum[t] = 0.f;
    int r = ei[e], c = ei[E_ + e];
    Cbf[(size_t)e * 512 + t]       = __float2bfloat16(h[(size_t)r * H_ + t]);
    Cbf[(size_t)e * 512 + 256 + t] = __float2bfloat16(h[(size_t)c * H_ + t]);
}

// Fused per-iteration GEMM launch (one grid, block-uniform branch):
//   blocks [0,128):    pair part — gh / outb from Abf
//   blocks [128,4224): V part — V8 = fp8(Abf @ Bt^T), permuted layout
// Depth-2 everywhere; __launch_bounds__(256,4) caps regs at 128/wave so 4
// blocks/CU co-reside (R10 showed depth-3's 3-block occupancy is a net loss).
__global__ __launch_bounds__(256, 4) void k_gemm_VP(const __hip_bfloat16* __restrict__ Abf,
                                                    const __hip_bfloat16* __restrict__ Bt,
                                                    const __hip_bfloat16* __restrict__ WhhB,
                                                    const __hip_bfloat16* __restrict__ BtB,
                                                    const float* __restrict__ bhh,
                                                    float* __restrict__ gh,
                                                    float* __restrict__ outb,
                                                    unsigned char* __restrict__ V8) {
    __shared__ __align__(16) short As[2][4096];
    __shared__ __align__(16) short Bs[2][4096];
    int bid = blockIdx.x;
    int t = threadIdx.x;
    int lane = t & 63, wave = t >> 6;
    int wm = wave >> 1, wn = wave & 1;
    int quad = lane >> 4, l16 = lane & 15;
    int r_ld = (lane >> 2);
    int koff = (((lane & 3) ^ ((lane >> 3) & 3)) * 8);
    int swz = (l16 >> 1) & 3;

    if (bid < 128) {
        // ---------------- pair part ----------------
        int pbx = bid & 7, pby = bid >> 3;
        bool ob = (pbx >= 6);
        const __hip_bfloat16* Bp = ob ? BtB : WhhB;
        int col0 = ob ? (pbx - 6) * 128 : pbx * 128;
        int ldc = ob ? H_ : NG_;
        float* C = ob ? outb : gh;
        int row0 = pby * 128;

        f32x4 acc[4][4] = {};
        auto stage = [&](int buf, int k0) {
#pragma unroll
            for (int c = 0; c < 4; c++) {
                int q = wave * 4 + c;
                int ch = q & 7;
                int r = ch * 16 + r_ld;
                const __hip_bfloat16* gp;
                short* lp;
                if (q < 8) { gp = Abf + ((size_t)(row0 + r) << 8) + k0 + koff; lp = &As[buf][ch * 512]; }
                else       { gp = Bp  + ((size_t)(col0 + r) << 8) + k0 + koff; lp = &Bs[buf][ch * 512]; }
                __builtin_amdgcn_global_load_lds(
                    (const __attribute__((address_space(1))) unsigned int*)(uintptr_t)gp,
                    (__attribute__((address_space(3))) unsigned int*)(uintptr_t)lp,
                    16, 0, 0);
            }
        };
        stage(0, 0);
        for (int kk = 0; kk < 8; kk++) {
            int cur = kk & 1;
            if (kk + 1 < 8) {
                stage(cur ^ 1, (kk + 1) * 32);
                PIPE_WAIT_ENTER(4)
            } else {
                PIPE_WAIT_ENTER(0)
            }
            bf16x8 a[4], b[4];
#pragma unroll
            for (int i = 0; i < 4; i++)
                a[i] = *(const bf16x8*)&As[cur][(wm * 64 + i * 16 + l16) * 32 + ((quad ^ swz) << 3)];
#pragma unroll
            for (int j = 0; j < 4; j++)
                b[j] = *(const bf16x8*)&Bs[cur][(wn * 64 + j * 16 + l16) * 32 + ((quad ^ swz) << 3)];
#pragma unroll
            for (int i = 0; i < 4; i++)
#pragma unroll
                for (int j = 0; j < 4; j++)
                    acc[i][j] = __builtin_amdgcn_mfma_f32_16x16x32_bf16(a[i], b[j], acc[i][j], 0, 0, 0);
            PIPE_EXIT()
        }
#pragma unroll
        for (int i = 0; i < 4; i++) {
            int gm0 = row0 + wm * 64 + i * 16 + quad * 4;
#pragma unroll
            for (int r = 0; r < 4; r++) {
                int gm = gm0 + r;
                if (gm < N_) {
#pragma unroll
                    for (int j = 0; j < 4; j++) {
                        int col = col0 + wn * 64 + l16 + j * 16;
                        float v = acc[i][j][r] + (ob ? 0.f : bhh[col]);
                        C[(size_t)gm * ldc + col] = v;
                    }
                }
            }
        }
        return;
    }

    // ---------------- V part ----------------
    int vb = bid - 128;
    int bx = vb & 255, by = vb >> 8;
    int row0 = by * 128, col0 = bx * 128;
    int obase = bx * 8;                    // o = (obase+ch)&255
    int kb = (bx >> 5) * 16;               // k16*16
    short* Ps = &As[0][0];                 // epilogue alias: 32 x 136 shorts

    f32x4 acc[4][4] = {};
    auto stage = [&](int buf, int k0) {
#pragma unroll
        for (int c = 0; c < 4; c++) {
            int q = wave * 4 + c;
            int ch = q & 7;
            const __hip_bfloat16* gp;
            short* lp;
            if (q < 8) {
                gp = Abf + ((size_t)(row0 + ch * 16 + r_ld) << 8) + k0 + koff;
                lp = &As[buf][ch * 512];
            } else {
                int nv = ((obase + ch) & 255) * 128 + kb + r_ld;   // f -> nv remap
                gp = Bt + ((size_t)nv << 8) + k0 + koff;
                lp = &Bs[buf][ch * 512];
            }
            __builtin_amdgcn_global_load_lds(
                (const __attribute__((address_space(1))) unsigned int*)(uintptr_t)gp,
                (__attribute__((address_space(3))) unsigned int*)(uintptr_t)lp,
                16, 0, 0);
        }
    };
    stage(0, 0);
    for (int kk = 0; kk < 8; kk++) {
        int cur = kk & 1;
        if (kk + 1 < 8) {
            stage(cur ^ 1, (kk + 1) * 32);
            PIPE_WAIT_ENTER(4)
        } else {
            PIPE_WAIT_ENTER(0)
        }
        bf16x8 a[4], b[4];
#pragma unroll
        for (int i = 0; i < 4; i++)
            a[i] = *(const bf16x8*)&As[cur][(wm * 64 + i * 16 + l16) * 32 + ((quad ^ swz) << 3)];
#pragma unroll
        for (int j = 0; j < 4; j++)
            b[j] = *(const bf16x8*)&Bs[cur][(wn * 64 + j * 16 + l16) * 32 + ((quad ^ swz) << 3)];
#pragma unroll
        for (int i = 0; i < 4; i++)
#pragma unroll
            for (int j = 0; j < 4; j++)
                acc[i][j] = __builtin_amdgcn_mfma_f32_16x16x32_bf16(a[i], b[j], acc[i][j], 0, 0, 0);
        PIPE_EXIT()
    }

    // 4-pass epilogue: stage 32 scaled-bf16 rows in Ps, convert+store coalesced uint4.
#pragma unroll
    for (int pp = 0; pp < 4; pp++) {
        if (wm == (pp >> 1)) {
#pragma unroll
            for (int ii = 0; ii < 2; ii++) {
                const int i = (pp & 1) * 2 + ii;       // compile-time acc index
                int lr = ii * 16 + quad * 4;           // local row in [0,32)
#pragma unroll
                for (int r = 0; r < 4; r++) {
#pragma unroll
                    for (int j = 0; j < 4; j++) {
                        int col = wn * 64 + j * 16 + l16;
                        Ps[(lr + r) * 136 + col] = bfbits(acc[i][j][r] * VSCALE);
                    }
                }
            }
        }
        __syncthreads();
        {
            int row = t >> 3;            // 0..31
            int col = (t & 7) * 16;      // 0..112 step 16
            int gm = row0 + pp * 32 + row;
            if (gm < N_) {
                uint4 ua = *(const uint4*)&Ps[row * 136 + col];
                uint4 ub = *(const uint4*)&Ps[row * 136 + col + 8];
                unsigned p0 = __builtin_amdgcn_cvt_pk_fp8_f32(bf_lo(ua.x), bf_hi(ua.x), 0, false);
                p0 = __builtin_amdgcn_cvt_pk_fp8_f32(bf_lo(ua.y), bf_hi(ua.y), p0, true);
                unsigned p1 = __builtin_amdgcn_cvt_pk_fp8_f32(bf_lo(ua.z), bf_hi(ua.z), 0, false);
                p1 = __builtin_amdgcn_cvt_pk_fp8_f32(bf_lo(ua.w), bf_hi(ua.w), p1, true);
                unsigned p2 = __builtin_amdgcn_cvt_pk_fp8_f32(bf_lo(ub.x), bf_hi(ub.x), 0, false);
                p2 = __builtin_amdgcn_cvt_pk_fp8_f32(bf_lo(ub.y), bf_hi(ub.y), p2, true);
                unsigned p3 = __builtin_amdgcn_cvt_pk_fp8_f32(bf_lo(ub.z), bf_hi(ub.z), 0, false);
                p3 = __builtin_amdgcn_cvt_pk_fp8_f32(bf_lo(ub.w), bf_hi(ub.w), p3, true);
                uint4 o4;
                o4.x = p0; o4.y = p1; o4.z = p2; o4.w = p3;
                *(uint4*)(V8 + (size_t)gm * NV_ + col0 + col) = o4;
            }
        }
        __syncthreads();
    }
}

// gi = relu(agg/c + conv_b) @ Wih^T + bih, m-transform fused into A-staging.
// BALANCED roles: every wave stages 2 A-channels and 2 B-channels.
__global__ __launch_bounds__(256, 3) void k_gemm_gi(const float* __restrict__ agg,
                                                    const float* __restrict__ counts,
                                                    const float* __restrict__ conv_b,
                                                    const __hip_bfloat16* __restrict__ WihB,
                                                    const float* __restrict__ bih,
                                                    float* __restrict__ gi) {
    __shared__ __align__(16) short As[2][4096];
    __shared__ __align__(16) short Bs[2][4096];
    __shared__ __align__(16) float conv_lds[256];
    int t = threadIdx.x;
    int lane = t & 63, wave = t >> 6;
    int wm = wave >> 1, wn = wave & 1;
    int quad = lane >> 4, l16 = lane & 15;
    int row0 = blockIdx.y * 128, col0 = blockIdx.x * 128;
    int r_ld = (lane >> 2);
    int koff = (((lane & 3) ^ ((lane >> 3) & 3)) * 8);
    int swz = (l16 >> 1) & 3;

    conv_lds[t] = conv_b[t];
    __syncthreads();

    f32x4 acc[4][4] = {};
    float rcv[2];
    const float* asrc[2];
#pragma unroll
    for (int c = 0; c < 2; c++) {
        int ch = wave * 2 + c;
        int row = row0 + ch * 16 + r_ld;
        int rowc = row < N_ ? row : N_ - 1;   // clamp padded rows (results discarded)
        rcv[c] = 1.f / fmaxf(counts[rowc], 1.f);
        asrc[c] = agg + (size_t)rowc * 256;
    }
    float4 R[2][2][2];

    auto loadA = [&](int buf, int k0) {
#pragma unroll
        for (int c = 0; c < 2; c++) {
            R[buf][c][0] = *(const float4*)(asrc[c] + k0 + koff);
            R[buf][c][1] = *(const float4*)(asrc[c] + k0 + koff + 4);
        }
    };
    auto stageB = [&](int buf, int k0) {
#pragma unroll
        for (int c = 0; c < 2; c++) {
            int ch = wave * 2 + c;
            const __hip_bfloat16* gp = WihB + (size_t)(col0 + ch * 16 + r_ld) * 256 + k0 + koff;
            short* lp = &Bs[buf][ch * 512];
            __builtin_amdgcn_global_load_lds(
                (const __attribute__((address_space(1))) unsigned int*)(uintptr_t)gp,
                (__attribute__((address_space(3))) unsigned int*)(uintptr_t)lp,
                16, 0, 0);
        }
    };
    auto writeA = [&](int buf, int k0) {
        float4 cb0 = *(const float4*)&conv_lds[k0 + koff];
        float4 cb1 = *(const float4*)&conv_lds[k0 + koff + 4];
#pragma unroll
        for (int c = 0; c < 2; c++) {
            int ch = wave * 2 + c;
            float rc = rcv[c];
            float4 a0 = R[buf][c][0], a1 = R[buf][c][1];
            bf16x8 v;
            v[0] = bfbits(fmaxf(a0.x * rc + cb0.x, 0.f));
            v[1] = bfbits(fmaxf(a0.y * rc + cb0.y, 0.f));
            v[2] = bfbits(fmaxf(a0.z * rc + cb0.z, 0.f));
            v[3] = bfbits(fmaxf(a0.w * rc + cb0.w, 0.f));
            v[4] = bfbits(fmaxf(a1.x * rc + cb1.x, 0.f));
            v[5] = bfbits(fmaxf(a1.y * rc + cb1.y, 0.f));
            v[6] = bfbits(fmaxf(a1.z * rc + cb1.z, 0.f));
            v[7] = bfbits(fmaxf(a1.w * rc + cb1.w, 0.f));
            *(bf16x8*)&As[buf][ch * 512 + lane * 8] = v;   // same slotting as gload_lds
        }
    };

    loadA(0, 0);
    stageB(0, 0);
#pragma unroll
    for (int kk = 0; kk < 8; kk++) {
        const int cur = kk & 1;
        if (kk + 1 < 8) {
            loadA(cur ^ 1, (kk + 1) * 32);
            stageB(cur ^ 1, (kk + 1) * 32);
        }
        writeA(cur, kk * 32);   // compiler auto-waits on R[cur]'s loads
        if (kk + 1 < 8) { asm volatile("s_waitcnt vmcnt(6)" ::: "memory"); }
        else            { asm volatile("s_waitcnt vmcnt(0)" ::: "memory"); }
        asm volatile("s_waitcnt lgkmcnt(0)" ::: "memory");
        __builtin_amdgcn_s_barrier();
        asm volatile("" ::: "memory");
        __builtin_amdgcn_sched_barrier(0);
        bf16x8 a[4], b[4];
#pragma unroll
        for (int i = 0; i < 4; i++)
            a[i] = *(const bf16x8*)&As[cur][(wm * 64 + i * 16 + l16) * 32 + ((quad ^ swz) << 3)];
#pragma unroll
        for (int j = 0; j < 4; j++)
            b[j] = *(const bf16x8*)&Bs[cur][(wn * 64 + j * 16 + l16) * 32 + ((quad ^ swz) << 3)];
#pragma unroll
        for (int i = 0; i < 4; i++)
#pragma unroll
            for (int j = 0; j < 4; j++)
                acc[i][j] = __builtin_amdgcn_mfma_f32_16x16x32_bf16(a[i], b[j], acc[i][j], 0, 0, 0);
        PIPE_EXIT()
    }

#pragma unroll
    for (int i = 0; i < 4; i++) {
        int gm0 = row0 + wm * 64 + i * 16 + quad * 4;
#pragma unroll
        for (int r = 0; r < 4; r++) {
            int gm = gm0 + r;
            if (gm < N_) {
#pragma unroll
                for (int j = 0; j < 4; j++) {
                    int col = col0 + wn * 64 + l16 + j * 16;
                    gi[(size_t)gm * NG_ + col] = acc[i][j][r] + bih[col];
                }
            }
        }
    }
}

// Tail GEMM with packed B (384x512): cols 0..255 -> relu->o1bf; cols 256..383 -> h1.
// Block x==2 additionally emits BN column partial sums (shfl-reduced, 2 atomics/col/wave).
__global__ __launch_bounds__(256, 3) void k_gemm_tail(const __hip_bfloat16* __restrict__ A,
                                                      const __hip_bfloat16* __restrict__ Bpk,
                                                      const float* __restrict__ b1,
                                                      const float* __restrict__ b2,
                                                      __hip_bfloat16* __restrict__ o1bf,
                                                      float* __restrict__ h1,
                                                      float* __restrict__ bnsum) {
    __shared__ __align__(16) short As[2][4096];
    __shared__ __align__(16) short Bs[2][4096];
    int t = threadIdx.x;
    int lane = t & 63, wave = t >> 6;
    int wm = wave >> 1, wn = wave & 1;
    int quad = lane >> 4, l16 = lane & 15;
    int row0 = blockIdx.y * 128, col0 = blockIdx.x * 128;

    f32x4 acc[4][4] = {};
    int r_ld = (lane >> 2);
    int koff = (((lane & 3) ^ ((lane >> 3) & 3)) * 8);
    int swz = (l16 >> 1) & 3;

    auto stage = [&](int buf, int k0) {
#pragma unroll
        for (int c = 0; c < 4; c++) {
            int q = wave * 4 + c;
            int ch = q & 7;
            int r = ch * 16 + r_ld;
            const __hip_bfloat16* gp;
            short* lp;
            if (q < 8) { gp = A   + (size_t)(row0 + r) * 512 + k0 + koff; lp = &As[buf][ch * 512]; }
            else       { gp = Bpk + (size_t)(col0 + r) * 512 + k0 + koff; lp = &Bs[buf][ch * 512]; }
            __builtin_amdgcn_global_load_lds(
                (const __attribute__((address_space(1))) unsigned int*)(uintptr_t)gp,
                (__attribute__((address_space(3))) unsigned int*)(uintptr_t)lp,
                16, 0, 0);
        }
    };

    stage(0, 0);
    for (int kk = 0; kk < 16; kk++) {
        int cur = kk & 1;
        if (kk + 1 < 16) {
            stage(cur ^ 1, (kk + 1) * 32);
            PIPE_WAIT_ENTER(4)
        } else {
            PIPE_WAIT_ENTER(0)
        }
        bf16x8 a[4], b[4];
#pragma unroll
        for (int i = 0; i < 4; i++)
            a[i] = *(const bf16x8*)&As[cur][(wm * 64 + i * 16 + l16) * 32 + ((quad ^ swz) << 3)];
#pragma unroll
        for (int j = 0; j < 4; j++)
            b[j] = *(const bf16x8*)&Bs[cur][(wn * 64 + j * 16 + l16) * 32 + ((quad ^ swz) << 3)];
#pragma unroll
        for (int i = 0; i < 4; i++)
#pragma unroll
            for (int j = 0; j < 4; j++)
                acc[i][j] = __builtin_amdgcn_mfma_f32_16x16x32_bf16(a[i], b[j], acc[i][j], 0, 0, 0);
        PIPE_EXIT()
    }

#pragma unroll
    for (int i = 0; i < 4; i++) {
        int gm0 = row0 + wm * 64 + i * 16 + quad * 4;
#pragma unroll
        for (int r = 0; r < 4; r++) {
            int gm = gm0 + r;
#pragma unroll
            for (int j = 0; j < 4; j++) {
                int col = col0 + wn * 64 + l16 + j * 16;
                float v = acc[i][j][r];
                if (col < 256) {
                    v = fmaxf(v + b1[col], 0.f);
                    o1bf[(size_t)gm * H_ + col] = __float2bfloat16(v);
                } else {
                    h1[(size_t)gm * 128 + (col - 256)] = v + b2[col - 256];
                }
            }
        }
    }

    if (col0 == 256) {
        // BN partial sums over this block's 128 rows, per h1 column.
#pragma unroll
        for (int j = 0; j < 4; j++) {
            int cj = wn * 64 + j * 16 + l16;      // h1 col 0..127
            float bj = b2[cj];
            float s = 0.f, ss = 0.f;
#pragma unroll
            for (int i = 0; i < 4; i++)
#pragma unroll
                for (int r = 0; r < 4; r++) {
                    float v = acc[i][j][r] + bj;
                    s += v;
                    ss += v * v;
                }
            s  += __shfl_xor(s, 16);  s  += __shfl_xor(s, 32);   // reduce across quads
            ss += __shfl_xor(ss, 16); ss += __shfl_xor(ss, 32);
            if (quad == 0) {
                atomicAdd(&bnsum[cj], s);
                atomicAdd(&bnsum[128 + cj], ss);
            }
        }
    }
}

// msg[e,o] = (he[e,:]/64).(fp8 V[row[e],o,:]) + outb[row[e],o]; atomicAdd into agg[col[e],o]
// Edges processed in row-sorted order, XCD-chunked; 4 independent partial accumulators.
__global__ void k_msg(const int* __restrict__ ei, const int* __restrict__ eord,
                      const float* __restrict__ he,
                      const unsigned char* __restrict__ V8, const float* __restrict__ outb,
                      float* __restrict__ agg) {
    int bid = blockIdx.x;
    int e = eord[((bid & 7) << 9) | (bid >> 3)];
    int o = threadIdx.x;
    __shared__ float hs[KH_];
    if (o < KH_) hs[o] = he[e * KH_ + o] * VSCALE_INV;
    __syncthreads();
    int r = ei[e], c = ei[E_ + e];
    const unsigned char* vbase = V8 + (size_t)r * NV_ + o * 16;

    auto dot16 = [&](uint4 u, const float* hp) -> float {
        f32x2 f;
        float s;
        f = __builtin_amdgcn_cvt_pk_f32_fp8(u.x, false); s  = hp[0]  * f.x + hp[1]  * f.y;
        f = __builtin_amdgcn_cvt_pk_f32_fp8(u.x, true);  s += hp[2]  * f.x + hp[3]  * f.y;
        f = __builtin_amdgcn_cvt_pk_f32_fp8(u.y, false); s += hp[4]  * f.x + hp[5]  * f.y;
        f = __builtin_amdgcn_cvt_pk_f32_fp8(u.y, true);  s += hp[6]  * f.x + hp[7]  * f.y;
        f = __builtin_amdgcn_cvt_pk_f32_fp8(u.z, false); s += hp[8]  * f.x + hp[9]  * f.y;
        f = __builtin_amdgcn_cvt_pk_f32_fp8(u.z, true);  s += hp[10] * f.x + hp[11] * f.y;
        f = __builtin_amdgcn_cvt_pk_f32_fp8(u.w, false); s += hp[12] * f.x + hp[13] * f.y;
        f = __builtin_amdgcn_cvt_pk_f32_fp8(u.w, true);  s += hp[14] * f.x + hp[15] * f.y;
        return s;
    };

    float p0, p1, p2, p3;
    {
        uint4 u0 = *(const uint4*)(vbase);
        uint4 u1 = *(const uint4*)(vbase + 4096);
        uint4 u2 = *(const uint4*)(vbase + 2 * 4096);
        uint4 u3 = *(const uint4*)(vbase + 3 * 4096);
        p0 = dot16(u0, hs);
        p1 = dot16(u1, hs + 16);
        p2 = dot16(u2, hs + 32);
        p3 = dot16(u3, hs + 48);
    }
    {
        uint4 u0 = *(const uint4*)(vbase + 4 * 4096);
        uint4 u1 = *(const uint4*)(vbase + 5 * 4096);
        uint4 u2 = *(const uint4*)(vbase + 6 * 4096);
        uint4 u3 = *(const uint4*)(vbase + 7 * 4096);
        p0 += dot16(u0, hs + 64);
        p1 += dot16(u1, hs + 80);
        p2 += dot16(u2, hs + 96);
        p3 += dot16(u3, hs + 112);
    }
    float acc = outb[(size_t)r * H_ + o] + ((p0 + p1) + (p2 + p3));
    atomicAdd(&agg[(size_t)c * H_ + o], acc);
}

// GRU pointwise; refreshes Abf = bf16(h); zeroes agg for the next iteration.
__global__ void k_gru_update(const float* __restrict__ gi, const float* __restrict__ gh,
                             float* __restrict__ h, __hip_bfloat16* __restrict__ Abf,
                             float* __restrict__ agg) {
    int i = blockIdx.x * blockDim.x + threadIdx.x;
    if (i >= N_ * H_) return;
    int n = i >> 8, j = i & 255;
    const float* gip = gi + (size_t)n * NG_;
    const float* ghp = gh + (size_t)n * NG_;
    float r = 1.f / (1.f + expf(-(gip[j] + ghp[j])));
    float z = 1.f / (1.f + expf(-(gip[H_ + j] + ghp[H_ + j])));
    float nn = tanhf(gip[2 * H_ + j] + r * ghp[2 * H_ + j]);
    float hv = (1.f - z) * nn + z * h[i];
    h[i] = hv;
    Abf[i] = __float2bfloat16(hv);
    agg[i] = 0.f;
}

// Fused final launch (both parts depend only on k_gemm_tail):
//   blocks [0,64):  out2 = o1bf @ lin2Wb^T + lin2_b (242 cols, depth-2 GEMM)
//   blocks [64,80): precs = relu(bn(h1)) . W2 + b   (mu/rsig from bnsum)
__global__ __launch_bounds__(256, 3) void k_gemm_lin2p(const __hip_bfloat16* __restrict__ A,
                                                       const __hip_bfloat16* __restrict__ Bt,
                                                       const float* __restrict__ bias,
                                                       const float* __restrict__ h1,
                                                       const float* __restrict__ bnsum,
                                                       const float* __restrict__ g,
                                                       const float* __restrict__ bb,
                                                       const float* __restrict__ W2,
                                                       const float* __restrict__ b2,
                                                       float* __restrict__ out) {
    int bid = blockIdx.x;
    int t = threadIdx.x;

    if (bid >= 64) {
        // ---------------- precs part ----------------
        __shared__ float smu[128], srs[128];
        if (t < 128) {
            float mu = bnsum[t] * (1.f / E_);
            float var = bnsum[128 + t] * (1.f / E_) - mu * mu;
            smu[t] = mu;
            srs[t] = rsqrtf(var + 1e-5f);
        }
        __syncthreads();
        int e = (bid - 64) * 256 + t;
        if (e >= E_) return;
        float acc = b2[0];
#pragma unroll 4
        for (int j = 0; j < 128; j++) {
            float v = (h1[(size_t)e * 128 + j] - smu[j]) * srs[j] * g[j] + bb[j];
            acc += fmaxf(v, 0.f) * W2[j];
        }
        out[(size_t)E_ * 242 + e] = acc;
        return;
    }

    // ---------------- lin2 GEMM part (KD=256, 242 valid cols) ----------------
    __shared__ __align__(16) short As[2][4096];
    __shared__ __align__(16) short Bs[2][4096];
    int lane = t & 63, wave = t >> 6;
    int wm = wave >> 1, wn = wave & 1;
    int quad = lane >> 4, l16 = lane & 15;
    int row0 = (bid >> 1) * 128, col0 = (bid & 1) * 128;

    f32x4 acc[4][4] = {};
    int r_ld = (lane >> 2);
    int koff = (((lane & 3) ^ ((lane >> 3) & 3)) * 8);
    int swz = (l16 >> 1) & 3;

    auto stage = [&](int buf, int k0) {
#pragma unroll
        for (int c = 0; c < 4; c++) {
            int q = wave * 4 + c;
            int ch = q & 7;
            int r = ch * 16 + r_ld;
            const __hip_bfloat16* gp;
            short* lp;
            if (q < 8) { gp = A  + (size_t)(row0 + r) * 256 + k0 + koff; lp = &As[buf][ch * 512]; }
            else       { gp = Bt + (size_t)(col0 + r) * 256 + k0 + koff; lp = &Bs[buf][ch * 512]; }
            __builtin_amdgcn_global_load_lds(
                (const __attribute__((address_space(1))) unsigned int*)(uintptr_t)gp,
                (__attribute__((address_space(3))) unsigned int*)(uintptr_t)lp,
                16, 0, 0);
        }
    };

    stage(0, 0);
    for (int kk = 0; kk < 8; kk++) {
        int cur = kk & 1;
        if (kk + 1 < 8) {
            stage(cur ^ 1, (kk + 1) * 32);
            PIPE_WAIT_ENTER(4)
        } else {
            PIPE_WAIT_ENTER(0)
        }
        bf16x8 a[4], b[4];
#pragma unroll
        for (int i = 0; i < 4; i++)
            a[i] = *(const bf16x8*)&As[cur][(wm * 64 + i * 16 + l16) * 32 + ((quad ^ swz) << 3)];
#pragma unroll
        for (int j = 0; j < 4; j++)
            b[j] = *(const bf16x8*)&Bs[cur][(wn * 64 + j * 16 + l16) * 32 + ((quad ^ swz) << 3)];
#pragma unroll
        for (int i = 0; i < 4; i++)
#pragma unroll
            for (int j = 0; j < 4; j++)
                acc[i][j] = __builtin_amdgcn_mfma_f32_16x16x32_bf16(a[i], b[j], acc[i][j], 0, 0, 0);
        PIPE_EXIT()
    }

#pragma unroll
    for (int i = 0; i < 4; i++) {
        int gm0 = row0 + wm * 64 + i * 16 + quad * 4;
#pragma unroll
        for (int r = 0; r < 4; r++) {
            int gm = gm0 + r;
#pragma unroll
            for (int j = 0; j < 4; j++) {
                int col = col0 + wn * 64 + l16 + j * 16;
                if (col < 242) {
                    out[(size_t)gm * 242 + col] = acc[i][j][r] + bias[col];
                }
            }
        }
    }
}

extern "C" void kernel_launch(void* const* d_in, const int* in_sizes, int n_in,
                              void* d_out, int out_size, void* d_ws, size_t ws_size,
                              hipStream_t stream) {
    const int*   x        = (const int*)  d_in[0];
    const float* pos      = (const float*)d_in[1];
    const int*   ei       = (const int*)  d_in[2];
    const float* edge_atr = (const float*)d_in[3];
    const float* emb      = (const float*)d_in[4];
    const float* lin0_W   = (const float*)d_in[5];
    const float* lin0_b   = (const float*)d_in[6];
    const float* mlp1_W   = (const float*)d_in[7];
    const float* mlp1_b   = (const float*)d_in[8];
    const float* mlp2_W   = (const float*)d_in[9];
    const float* mlp2_b   = (const float*)d_in[10];
    const float* conv_b   = (const float*)d_in[11];
    const float* gru_Wih  = (const float*)d_in[12];
    const float* gru_Whh  = (const float*)d_in[13];
    const float* gru_bih  = (const float*)d_in[14];
    const float* gru_bhh  = (const float*)d_in[15];
    const float* lin1_W   = (const float*)d_in[16];
    const float* lin1_b   = (const float*)d_in[17];
    const float* lin2_W   = (const float*)d_in[18];
    const float* lin2_b   = (const float*)d_in[19];
    const float* l6_W1    = (const float*)d_in[20];
    const float* l6_b1    = (const float*)d_in[21];
    const float* bn_g     = (const float*)d_in[22];
    const float* bn_b     = (const float*)d_in[23];
    const float* l6_W2    = (const float*)d_in[24];
    const float* l6_b2    = (const float*)d_in[25];
    float* out = (float*)d_out;

    // workspace layout
    char* w = (char*)d_ws;
    size_t off = 0;
    auto alloc = [&](size_t bytes) -> void* {
        void* p = w + off;
        off = (off + bytes + 255) & ~(size_t)255;
        return p;
    };
    float* hbuf   = (float*)alloc((size_t)N_ * H_ * 4);
    float* aggm   = (float*)alloc((size_t)N_ * H_ * 4);
    float* outb   = (float*)alloc((size_t)N_ * H_ * 4);
    float* he     = (float*)alloc((size_t)E_ * KH_ * 4);
    float* gi     = (float*)alloc((size_t)N_ * NG_ * 4);
    float* gh     = (float*)alloc((size_t)N_ * NG_ * 4);
    float* h1     = (float*)alloc((size_t)E_ * 128 * 4);
    float* counts = (float*)alloc((size_t)N_ * 4);
    float* bnsum  = (float*)alloc(256 * 4);
    int*   deg    = (int*)  alloc((size_t)N_ * 4);
    int*   eord   = (int*)  alloc((size_t)E_ * 4);
    unsigned char* V8      = (unsigned char*)alloc((size_t)N_ * NV_);          // 65.5 MB fp8
    __hip_bfloat16* Abf    = (__hip_bfloat16*)alloc((size_t)MPAD_ * H_ * 2);
    __hip_bfloat16* Bt     = (__hip_bfloat16*)alloc((size_t)NV_ * H_ * 2);     // 16.8 MB
    __hip_bfloat16* WihB   = (__hip_bfloat16*)alloc((size_t)NG_ * H_ * 2);
    __hip_bfloat16* WhhB   = (__hip_bfloat16*)alloc((size_t)NG_ * H_ * 2);
    __hip_bfloat16* Bpk    = (__hip_bfloat16*)alloc((size_t)384 * 512 * 2);
    __hip_bfloat16* lin2Wb = (__hip_bfloat16*)alloc((size_t)H_ * H_ * 2);
    __hip_bfloat16* BtB    = (__hip_bfloat16*)alloc((size_t)H_ * H_ * 2);
    __hip_bfloat16* Cbf    = (__hip_bfloat16*)alloc((size_t)E_ * 2 * H_ * 2);
    __hip_bfloat16* o1bf   = (__hip_bfloat16*)alloc((size_t)E_ * H_ * 2);

    k_lin0<<<MPAD_, 256, 0, stream>>>(x, pos, emb, lin0_W, lin0_b, hbuf, Abf,
                                      counts, aggm, deg);
    k_he<<<E_, 128, 0, stream>>>(edge_atr, mlp1_W, mlp1_b, he, ei, counts, deg);
    k_scanfill<<<1, 256, 0, stream>>>(ei, deg, eord);
    k_trans_bt<<<dim3(NV_ / 64, H_ / 32), 256, 0, stream>>>(mlp2_W, Bt);
    k_prep_w<<<768, 256, 0, stream>>>(gru_Wih, gru_Whh, lin1_W, l6_W1, lin2_W, mlp2_b,
                                      WihB, WhhB, Bpk, lin2Wb, BtB);

    for (int it = 0; it < 3; it++) {
        // fused: gh = Abf@Whh^T + bhh, outb = Abf@BtB^T, V8 = fp8(Abf@Bt^T)
        k_gemm_VP<<<128 + (NV_ / 128) * (MPAD_ / 128), 256, 0, stream>>>(
            Abf, Bt, WhhB, BtB, gru_bhh, gh, outb, V8);
        k_msg<<<E_, 256, 0, stream>>>(ei, eord, he, V8, outb, aggm);
        // gi = relu(agg/c + conv_b) @ Wih^T + bih   (m-transform fused, balanced waves)
        k_gemm_gi<<<dim3(6, MPAD_ / 128), 256, 0, stream>>>(
            aggm, counts, conv_b, WihB, gru_bih, gi);
        k_gru_update<<<(N_ * H_ + 255) / 256, 256, 0, stream>>>(gi, gh, hbuf, Abf, aggm);
    }

    k_concat<<<E_, 256, 0, stream>>>(ei, hbuf, Cbf, bnsum);
    k_gemm_tail<<<dim3(3, E_ / 128), 256, 0, stream>>>(Cbf, Bpk, lin1_b, l6_b1,
                                                       o1bf, h1, bnsum);
    k_gemm_lin2p<<<80, 256, 0, stream>>>(o1bf, lin2Wb, lin2_b,
                                         h1, bnsum, bn_g, bn_b, l6_W2, l6_b2, out);
}